// Round 12
// baseline (148.812 us; speedup 1.0000x reference)
//
#include <hip/hip_runtime.h>
#include <math.h>

#define B_    2
#define TU_   1024
#define D_    80
#define H_    8
#define DH_   10
#define FFN_  2048
#define SEG_  32
#define RC_   8
#define LC_   50
#define NSEG_ 32
#define RCT_  256
#define L_    1280
#define NLAYERS_ 4
#define OUTD_ 768
#define EPS_  1e-5f
#define SCALE_ 0.31622776601683794f
#define NR_   (B_*L_)                 // 2560
#define KP_   96                      // K pad 80->96

typedef __attribute__((ext_vector_type(8))) short bf16x8;
typedef __attribute__((ext_vector_type(4))) float f32x4;
typedef unsigned short ushort_t;
typedef unsigned char uchar_t;
typedef long i64_t;

__device__ inline ushort_t f2bf(float f) {
  union { float f; unsigned u; } x; x.f = f;
  unsigned r = x.u + 0x7fffu + ((x.u >> 16) & 1u);   // RNE
  return (ushort_t)(r >> 16);
}
__device__ inline float bf2f(ushort_t u) {
  union { unsigned u; float f; } x; x.u = ((unsigned)u) << 16; return x.f;
}
// HW fp8 e4m3 convert (gfx950: v_cvt_pk_fp8_f32, RNE, saturating)
__device__ inline uchar_t f2fp8(float f) {
  return (uchar_t)(__builtin_amdgcn_cvt_pk_fp8_f32(f, f, 0, false) & 0xff);
}

// ============ one-shot weight prep ============
#define S1_ (NLAYERS_*FFN_*KP_)        // w18 fp8 [l][n2048][k96], x16
#define S2_ (NLAYERS_*D_*FFN_)         // w28 fp8 [l][n80][k2048], x16
#define S3_ (NLAYERS_*256*KP_)         // wqkvT bf16 [l][n256][k96] (scale folded in q cols)
#define S4_ (NLAYERS_*D_*KP_)          // woT bf16 [l][n80][k96]
#define S5_ (OUTD_*KP_)                // pwT bf16 [n768][k96]
#define S6_ (NLAYERS_*240)             // bqkv fp32 [l][240]
#define WPREP_N_ (S1_+S2_+S3_+S4_+S5_+S6_)

__global__ void k_wprep(const float* __restrict__ w1, const float* __restrict__ w2,
    const float* __restrict__ wq, const float* __restrict__ wkv,
    const float* __restrict__ wo, const float* __restrict__ pw,
    const float* __restrict__ bq, const float* __restrict__ bkv,
    uchar_t* __restrict__ w18, uchar_t* __restrict__ w28,
    ushort_t* __restrict__ wqkvT, ushort_t* __restrict__ woT,
    ushort_t* __restrict__ pwT, float* __restrict__ bqkv) {
  int idx = blockIdx.x * blockDim.x + threadIdx.x;
  if (idx < S1_) {
    int k = idx % KP_, n = (idx / KP_) % FFN_, l = idx / (KP_*FFN_);
    w18[idx] = (k < D_) ? f2fp8(w1[(l*D_ + k)*FFN_ + n] * 16.f) : 0;
    return;
  }
  idx -= S1_;
  if (idx < S2_) {
    int k = idx % FFN_, n = (idx / FFN_) % D_, l = idx / (FFN_*D_);
    w28[idx] = f2fp8(w2[(l*FFN_ + k)*D_ + n] * 16.f);
    return;
  }
  idx -= S2_;
  if (idx < S3_) {
    int k = idx % KP_, n = (idx / KP_) % 256, l = idx / (KP_*256);
    float v = 0.f;
    if (k < D_ && n < 240) {
      if (n < D_) v = wq[(l*D_ + k)*D_ + n] * SCALE_;
      else        v = wkv[(l*D_ + k)*2*D_ + (n - D_)];
    }
    wqkvT[idx] = f2bf(v);
    return;
  }
  idx -= S3_;
  if (idx < S4_) {
    int k = idx % KP_, n = (idx / KP_) % D_, l = idx / (KP_*D_);
    woT[idx] = (k < D_) ? f2bf(wo[(l*D_ + k)*D_ + n]) : 0;
    return;
  }
  idx -= S4_;
  if (idx < S5_) {
    int k = idx % KP_, n = idx / KP_;
    pwT[idx] = (k < D_) ? f2bf(pw[k*OUTD_ + n]) : 0;
    return;
  }
  idx -= S5_;
  if (idx < S6_) {
    int c = idx % 240, l = idx / 240;
    bqkv[idx] = (c < D_) ? bq[l*D_ + c] * SCALE_ : bkv[l*2*D_ + (c - D_)];
  }
}

// ============ merged: gather mel -> x + layer-0 LN_in + QKV MFMA -> q/kv ============
__global__ __launch_bounds__(512) void k_build_qkv(const float* __restrict__ mel,
    const float* __restrict__ lw, const float* __restrict__ lb,
    const ushort_t* __restrict__ wqkvT, const float* __restrict__ bqkv,
    float* __restrict__ x, float* __restrict__ q, float* __restrict__ kv) {
  int tid = threadIdx.x;
  int wv = tid >> 6, lane = tid & 63;
  int r = lane & 15, g = lane >> 4;
  int bm = blockIdx.x * 16;
  __shared__ ushort_t hnsh[16][KP_];

  if (tid < 256) {
    int row = tid >> 4, j = tid & 15;
    int grow = bm + row;
    int b = grow / L_, i = grow % L_;
    int srow = (i < RCT_) ? ((i >> 3) + 1)*SEG_ + (i & 7) : i - RCT_;
    float v[5], s = 0.f, ss = 0.f;
    #pragma unroll
    for (int c = 0; c < 5; ++c) {
      int col = j + c*16;
      v[c] = mel[((size_t)b*(TU_+RC_) + srow)*D_ + col];
      x[(size_t)grow*D_ + col] = v[c];
      s += v[c]; ss += v[c]*v[c];
    }
    s  += __shfl_xor(s, 1, 16);  ss += __shfl_xor(ss, 1, 16);
    s  += __shfl_xor(s, 2, 16);  ss += __shfl_xor(ss, 2, 16);
    s  += __shfl_xor(s, 4, 16);  ss += __shfl_xor(ss, 4, 16);
    s  += __shfl_xor(s, 8, 16);  ss += __shfl_xor(ss, 8, 16);
    float mean = s * (1.f/D_);
    float var  = ss * (1.f/D_) - mean*mean;
    float inv  = rsqrtf(var + EPS_);
    #pragma unroll
    for (int c = 0; c < 5; ++c) {
      int col = j + c*16;
      hnsh[row][col] = f2bf((v[c] - mean) * inv * lw[col] + lb[col]);
    }
    hnsh[row][D_ + j] = 0;
  }
  __syncthreads();

  for (int t = wv; t < 15; t += 8) {
    f32x4 acc = {};
    #pragma unroll
    for (int ks = 0; ks < KP_; ks += 32) {
      bf16x8 a  = *(const bf16x8*)(&hnsh[r][ks + g*8]);
      bf16x8 bb = *(const bf16x8*)(wqkvT + (size_t)(t*16 + r)*KP_ + ks + g*8);
      acc = __builtin_amdgcn_mfma_f32_16x16x32_bf16(a, bb, acc, 0, 0, 0);
    }
    int col = t*16 + r;
    float bc = bqkv[col];
    #pragma unroll
    for (int rr = 0; rr < 4; ++rr) {
      int row = bm + g*4 + rr;
      float v = acc[rr] + bc;
      if (col < D_) q[(size_t)row*D_ + col] = v;
      else          kv[(size_t)row*2*D_ + (col - D_)] = v;
    }
  }
}

// ============ block-sparse attention -> attbf bf16 [2560][96] ============
// ILP fix: all fp32 reduction chains broken into independent partials
// (no -ffast-math => compiler cannot reassociate; serial chains were the cost).
__global__ __launch_bounds__(256) void k_attn(const float* __restrict__ q,
    const float* __restrict__ kv, ushort_t* __restrict__ att) {
  int seg = blockIdx.x, b = blockIdx.y, h = blockIdx.z;
  int tid = threadIdx.x;
  int seg_start = seg*SEG_ - LC_; if (seg_start < 0) seg_start = 0;
  int kc = RC_ + (seg+1)*SEG_ - seg_start;       // <= 90
  __shared__ float Ksh[90][DH_];
  __shared__ float Vsh[90][DH_];
  __shared__ float Qsh[40][DH_];
  __shared__ float Ssh[40][90];
  __shared__ float inv_sh[40];
  for (int idx = tid; idx < kc*DH_; idx += 256) {
    int kk = idx / DH_, d = idx % DH_;
    int krow = (kk < RC_) ? seg*RC_ + kk : RCT_ + seg_start + (kk - RC_);
    const float* base = kv + (b*L_ + krow)*2*D_ + h*DH_ + d;
    Ksh[kk][d] = base[0];
    Vsh[kk][d] = base[D_];
  }
  for (int idx = tid; idx < 40*DH_; idx += 256) {
    int qi = idx / DH_, d = idx % DH_;
    int qrow = (qi < RC_) ? seg*RC_ + qi : RCT_ + seg*SEG_ + (qi - RC_);
    Qsh[qi][d] = q[(b*L_ + qrow)*D_ + h*DH_ + d];
  }
  __syncthreads();
  // scores (independent per output; dot-10 unrolled by compiler)
  for (int p = tid; p < 40*kc; p += 256) {
    int qi = p / kc, kk = p - qi*kc;
    float s0 = 0.f, s1 = 0.f;
    #pragma unroll
    for (int d = 0; d < DH_; d += 2) {
      s0 += Qsh[qi][d]   * Ksh[kk][d];
      s1 += Qsh[qi][d+1] * Ksh[kk][d+1];
    }
    Ssh[qi][kk] = s0 + s1;
  }
  __syncthreads();
  // softmax: 40 rows x 4 lanes; 2-way partials break the serial chains
  if (tid < 160) {
    int row = tid >> 2, j = tid & 3;
    float pm0 = -INFINITY, pm1 = -INFINITY;
    int kk = j;
    for (; kk + 8 <= kc + j; kk += 8) {          // pairs at stride 4
      pm0 = fmaxf(pm0, Ssh[row][kk]);
      if (kk + 4 < kc) pm1 = fmaxf(pm1, Ssh[row][kk+4]);
    }
    if (kk < kc) pm0 = fmaxf(pm0, Ssh[row][kk]);
    float pm = fmaxf(pm0, pm1);
    pm = fmaxf(pm, __shfl_xor(pm, 1, 4));
    pm = fmaxf(pm, __shfl_xor(pm, 2, 4));
    float ps0 = 0.f, ps1 = 0.f;
    for (kk = j; kk + 8 <= kc + j; kk += 8) {
      float e0 = __expf(Ssh[row][kk] - pm);
      Ssh[row][kk] = e0; ps0 += e0;
      if (kk + 4 < kc) {
        float e1 = __expf(Ssh[row][kk+4] - pm);
        Ssh[row][kk+4] = e1; ps1 += e1;
      }
    }
    if (kk < kc) { float e0 = __expf(Ssh[row][kk] - pm); Ssh[row][kk] = e0; ps0 += e0; }
    float ps = ps0 + ps1;
    ps += __shfl_xor(ps, 1, 4);
    ps += __shfl_xor(ps, 2, 4);
    if (j == 0) inv_sh[row] = 1.f / ps;
  }
  __syncthreads();
  // PV: 4 independent partial accumulators (was: 90-long dependent FMA chain)
  for (int o = tid; o < 40*DH_; o += 256) {
    int qi = o / DH_, d = o - qi*DH_;
    float a0 = 0.f, a1 = 0.f, a2 = 0.f, a3 = 0.f;
    int kk = 0;
    for (; kk + 4 <= kc; kk += 4) {
      a0 += Ssh[qi][kk+0] * Vsh[kk+0][d];
      a1 += Ssh[qi][kk+1] * Vsh[kk+1][d];
      a2 += Ssh[qi][kk+2] * Vsh[kk+2][d];
      a3 += Ssh[qi][kk+3] * Vsh[kk+3][d];
    }
    for (; kk < kc; ++kk) a0 += Ssh[qi][kk] * Vsh[kk][d];
    float acc = (a0 + a1) + (a2 + a3);
    int qrow = (qi < RC_) ? seg*RC_ + qi : RCT_ + seg*SEG_ + (qi - RC_);
    att[(b*L_ + qrow)*KP_ + h*DH_ + d] = f2bf(acc * inv_sh[qi]);
  }
  if (h == 0) {  // zero K-pad cols 80..95
    for (int idx = tid; idx < 40*16; idx += 256) {
      int qi = idx >> 4, c = D_ + (idx & 15);
      int qrow = (qi < RC_) ? seg*RC_ + qi : RCT_ + seg*SEG_ + (qi - RC_);
      att[(b*L_ + qrow)*KP_ + c] = 0;
    }
  }
}

// ============ fused per-layer tail (16 waves): WO(bf16) + res + LN_ff +
//              FFN1(fp8) + FFN2(fp8) + reduce + res + LN_out -> x,
//              LN_in(next) -> QKV(next, bf16) ============
__global__ __launch_bounds__(1024) void k_ffn_fused(const ushort_t* __restrict__ attbf,
    const ushort_t* __restrict__ woT, const float* __restrict__ bo,
    const uchar_t* __restrict__ w18, const float* __restrict__ b1,
    const uchar_t* __restrict__ w28, const float* __restrict__ b2,
    const float* __restrict__ lfw, const float* __restrict__ lfb,
    const float* __restrict__ low, const float* __restrict__ lob,
    const float* __restrict__ liw, const float* __restrict__ lib, int mode,
    float* __restrict__ x, ushort_t* __restrict__ xnbf,
    const ushort_t* __restrict__ wqkvT_n, const float* __restrict__ bqkv_n,
    float* __restrict__ q, float* __restrict__ kv) {
  int tid = threadIdx.x;
  int wv = tid >> 6, lane = tid & 63;
  int r = lane & 15, g = lane >> 4;
  int bm = blockIdx.x * 16;
  __shared__ ushort_t attsh[16][KP_];
  __shared__ ushort_t hnsh[16][KP_];         // LN_in(next) out, QKV A-operand
  __shared__ uchar_t  hn8[16][104];          // fp8 LN_ff out (FFN1 A)
  __shared__ uchar_t  ff18[16][16][136];     // fp8 relu(ff1)*8, per-wave slice
  __shared__ ushort_t redb[16][16][D_];      // bf16 FFN2 partials
  __shared__ float    vsh[16][D_];           // WO out -> residual -> FFN2 sum

  if (tid < 192) {
    int row = tid / 12, c = (tid % 12) * 8;
    *(bf16x8*)&attsh[row][c] = *(const bf16x8*)(attbf + (size_t)(bm+row)*KP_ + c);
  }
  __syncthreads();

  // ---- WO: waves 0..4 each compute one 16-col fragment (K=96, bf16) ----
  if (wv < 5) {
    f32x4 acc = {};
    #pragma unroll
    for (int ks = 0; ks < KP_; ks += 32) {
      bf16x8 a  = *(const bf16x8*)(&attsh[r][ks + g*8]);
      bf16x8 bb = *(const bf16x8*)(woT + (size_t)(wv*16 + r)*KP_ + ks + g*8);
      acc = __builtin_amdgcn_mfma_f32_16x16x32_bf16(a, bb, acc, 0, 0, 0);
    }
    #pragma unroll
    for (int rr = 0; rr < 4; ++rr)
      vsh[g*4 + rr][wv*16 + r] = acc[rr];
  }
  __syncthreads();

  // ---- bias + residual + LN_ff -> hn8 (res kept in vsh) ----
  if (tid < 256) {
    int row = tid >> 4, j = tid & 15;
    int grow = bm + row;
    float v[5], s = 0.f, ss = 0.f;
    #pragma unroll
    for (int c = 0; c < 5; ++c) {
      int col = j + c*16;
      v[c] = vsh[row][col] + bo[col] + x[(size_t)grow*D_ + col];
      vsh[row][col] = v[c];
      s += v[c]; ss += v[c]*v[c];
    }
    s  += __shfl_xor(s, 1, 16);  ss += __shfl_xor(ss, 1, 16);
    s  += __shfl_xor(s, 2, 16);  ss += __shfl_xor(ss, 2, 16);
    s  += __shfl_xor(s, 4, 16);  ss += __shfl_xor(ss, 4, 16);
    s  += __shfl_xor(s, 8, 16);  ss += __shfl_xor(ss, 8, 16);
    float mean = s * (1.f/D_);
    float var  = ss * (1.f/D_) - mean*mean;
    float inv  = rsqrtf(var + EPS_);
    #pragma unroll
    for (int c = 0; c < 5; ++c) {
      int col = j + c*16;
      hn8[row][col] = f2fp8((v[c] - mean) * inv * lfw[col] + lfb[col]);
    }
    hn8[row][D_ + j] = 0;
  }
  __syncthreads();

  // ---- FFN1 fp8: M=16 x N=128(per wave) x K=96; out = acc/16 + b1, relu, x8 -> fp8 ----
  f32x4 acc1[8];
  #pragma unroll
  for (int ni = 0; ni < 8; ++ni) acc1[ni] = (f32x4){0.f,0.f,0.f,0.f};
  int nbase = wv*128;
  #pragma unroll
  for (int ks = 0; ks < KP_; ks += 32) {
    i64_t a = *(const i64_t*)(&hn8[r][ks + g*8]);
    #pragma unroll
    for (int ni = 0; ni < 8; ++ni) {
      i64_t bb = *(const i64_t*)(w18 + (size_t)(nbase + ni*16 + r)*KP_ + ks + g*8);
      acc1[ni] = __builtin_amdgcn_mfma_f32_16x16x32_fp8_fp8(a, bb, acc1[ni], 0, 0, 0);
    }
  }
  #pragma unroll
  for (int ni = 0; ni < 8; ++ni) {
    int col = nbase + ni*16 + r;
    float bc = b1[col];
    #pragma unroll
    for (int rr = 0; rr < 4; ++rr) {
      float v = acc1[ni][rr] * 0.0625f + bc;          // /16 (weight scale)
      ff18[wv][g*4 + rr][ni*16 + r] = f2fp8(fmaxf(v, 0.f) * 8.f);
    }
  }
  // same-wave write->read of ff18[wv]: compiler-ordered, no block barrier needed

  // ---- FFN2 fp8: M=16 x N=80 x K=128 (this wave's chunk) ----
  f32x4 acc2[5] = {};
  #pragma unroll
  for (int ks = 0; ks < 128; ks += 32) {
    i64_t a = *(const i64_t*)(&ff18[wv][r][ks + g*8]);
    #pragma unroll
    for (int nf = 0; nf < 5; ++nf) {
      i64_t bb = *(const i64_t*)(w28 + (size_t)(nf*16 + r)*FFN_ + wv*128 + ks + g*8);
      acc2[nf] = __builtin_amdgcn_mfma_f32_16x16x32_fp8_fp8(a, bb, acc2[nf], 0, 0, 0);
    }
  }
  #pragma unroll
  for (int nf = 0; nf < 5; ++nf)
    #pragma unroll
    for (int rr = 0; rr < 4; ++rr)
      redb[wv][g*4 + rr][nf*16 + r] = f2bf(acc2[nf][rr]);
  __syncthreads();

  // ---- 16-way partial reduce /128 + bias + residual -> vsh (4-way ILP) ----
  for (int e = tid; e < 16*D_; e += 1024) {
    int row = e / D_, col = e % D_;
    float s0 = 0.f, s1 = 0.f, s2 = 0.f, s3 = 0.f;
    #pragma unroll
    for (int w = 0; w < 16; w += 4) {
      s0 += bf2f(redb[w+0][row][col]);
      s1 += bf2f(redb[w+1][row][col]);
      s2 += bf2f(redb[w+2][row][col]);
      s3 += bf2f(redb[w+3][row][col]);
    }
    vsh[row][col] = ((s0+s1)+(s2+s3)) * (1.f/128.f) + b2[col] + vsh[row][col];
  }
  __syncthreads();
  if (tid < 256) {
    int row = tid >> 4, j = tid & 15;
    float v[5], s = 0.f, ss = 0.f;
    #pragma unroll
    for (int c = 0; c < 5; ++c) {
      v[c] = vsh[row][j + c*16];
      s += v[c]; ss += v[c]*v[c];
    }
    s  += __shfl_xor(s, 1, 16);  ss += __shfl_xor(ss, 1, 16);
    s  += __shfl_xor(s, 2, 16);  ss += __shfl_xor(ss, 2, 16);
    s  += __shfl_xor(s, 4, 16);  ss += __shfl_xor(ss, 4, 16);
    s  += __shfl_xor(s, 8, 16);  ss += __shfl_xor(ss, 8, 16);
    float mean = s * (1.f/D_);
    float var  = ss * (1.f/D_) - mean*mean;
    float inv  = rsqrtf(var + EPS_);
    int grow = bm + row;
    float xs[5];
    float s2 = 0.f, ss2 = 0.f;
    #pragma unroll
    for (int c = 0; c < 5; ++c) {
      int col = j + c*16;
      xs[c] = (v[c] - mean) * inv * low[col] + lob[col];
      x[(size_t)grow*D_ + col] = xs[c];
      s2 += xs[c]; ss2 += xs[c]*xs[c];
    }
    if (mode == 0) {
      s2  += __shfl_xor(s2, 1, 16);  ss2 += __shfl_xor(ss2, 1, 16);
      s2  += __shfl_xor(s2, 2, 16);  ss2 += __shfl_xor(ss2, 2, 16);
      s2  += __shfl_xor(s2, 4, 16);  ss2 += __shfl_xor(ss2, 4, 16);
      s2  += __shfl_xor(s2, 8, 16);  ss2 += __shfl_xor(ss2, 8, 16);
      float m2 = s2 * (1.f/D_);
      float v2 = ss2 * (1.f/D_) - m2*m2;
      float i2 = rsqrtf(v2 + EPS_);
      #pragma unroll
      for (int c = 0; c < 5; ++c) {
        int col = j + c*16;
        hnsh[row][col] = f2bf((xs[c] - m2) * i2 * liw[col] + lib[col]);
      }
      hnsh[row][D_ + j] = 0;
    } else {
      #pragma unroll
      for (int c = 0; c < 5; ++c)
        xnbf[(size_t)grow*KP_ + j + c*16] = f2bf(xs[c]);
      xnbf[(size_t)grow*KP_ + D_ + j] = 0;
    }
  }

  // ---- fused next-layer QKV: [16x96] @ [96x240] (15 N-tiles over 16 waves) ----
  if (mode == 0) {
    __syncthreads();
    if (wv < 15) {
      int t = wv;
      f32x4 acc = {};
      #pragma unroll
      for (int ks = 0; ks < KP_; ks += 32) {
        bf16x8 a  = *(const bf16x8*)(&hnsh[r][ks + g*8]);
        bf16x8 bb = *(const bf16x8*)(wqkvT_n + (size_t)(t*16 + r)*KP_ + ks + g*8);
        acc = __builtin_amdgcn_mfma_f32_16x16x32_bf16(a, bb, acc, 0, 0, 0);
      }
      int col = t*16 + r;
      float bc = bqkv_n[col];
      #pragma unroll
      for (int rr = 0; rr < 4; ++rr) {
        int row = bm + g*4 + rr;
        float v = acc[rr] + bc;
        if (col < D_) q[(size_t)row*D_ + col] = v;
        else          kv[(size_t)row*2*D_ + (col - D_)] = v;
      }
    }
  }
}

// ============ final proj MFMA (+ lengths tail) ============
__global__ __launch_bounds__(256) void k_proj_mfma(const ushort_t* __restrict__ xbf,
    const ushort_t* __restrict__ pwT, const float* __restrict__ pb,
    const int* __restrict__ len, float* __restrict__ out) {
  int wv = threadIdx.x >> 6, lane = threadIdx.x & 63;
  int bm = blockIdx.x * 64;
  int bn = blockIdx.y * 128 + wv*32;
  int b  = blockIdx.z;
  int r = lane & 15, g = lane >> 4;
  f32x4 acc[4][2] = {};
  const ushort_t* Ab = xbf + ((size_t)(b*L_ + RCT_ + bm) + r)*KP_ + g*8;
  const ushort_t* Bb = pwT + (size_t)(bn + r)*KP_ + g*8;
  #pragma unroll
  for (int ks = 0; ks < KP_; ks += 32) {
    bf16x8 a[4], bfr[2];
    #pragma unroll
    for (int mf = 0; mf < 4; ++mf) a[mf]   = *(const bf16x8*)(Ab + mf*16*KP_ + ks);
    #pragma unroll
    for (int nf = 0; nf < 2; ++nf) bfr[nf] = *(const bf16x8*)(Bb + nf*16*KP_ + ks);
    #pragma unroll
    for (int mf = 0; mf < 4; ++mf)
      #pragma unroll
      for (int nf = 0; nf < 2; ++nf)
        acc[mf][nf] = __builtin_amdgcn_mfma_f32_16x16x32_bf16(a[mf], bfr[nf], acc[mf][nf], 0, 0, 0);
  }
  #pragma unroll
  for (int mf = 0; mf < 4; ++mf)
    #pragma unroll
    for (int nf = 0; nf < 2; ++nf) {
      int col = bn + nf*16 + r;
      float bc = pb[col];
      #pragma unroll
      for (int rr = 0; rr < 4; ++rr) {
        int row = bm + mf*16 + g*4 + rr;
        out[((size_t)b*TU_ + row)*OUTD_ + col] = acc[mf][nf][rr] + bc;
      }
    }
  if (blockIdx.x == 0 && blockIdx.y == 0 && blockIdx.z == 0 && threadIdx.x < B_)
    out[(size_t)B_*TU_*OUTD_ + threadIdx.x] = (float)len[threadIdx.x];
}

extern "C" void kernel_launch(void* const* d_in, const int* in_sizes, int n_in,
                              void* d_out, int out_size, void* d_ws, size_t ws_size,
                              hipStream_t stream) {
  const float* mel     = (const float*)d_in[0];
  const int*   lengths = (const int*)  d_in[1];
  const float* ln_in_w = (const float*)d_in[2];
  const float* ln_in_b = (const float*)d_in[3];
  const float* wq      = (const float*)d_in[4];
  const float* bq      = (const float*)d_in[5];
  const float* wkv     = (const float*)d_in[6];
  const float* bkv     = (const float*)d_in[7];
  const float* wo      = (const float*)d_in[8];
  const float* bo      = (const float*)d_in[9];
  const float* ln_ff_w = (const float*)d_in[10];
  const float* ln_ff_b = (const float*)d_in[11];
  const float* w1      = (const float*)d_in[12];
  const float* b1      = (const float*)d_in[13];
  const float* w2      = (const float*)d_in[14];
  const float* b2      = (const float*)d_in[15];
  const float* ln_o_w  = (const float*)d_in[16];
  const float* ln_o_b  = (const float*)d_in[17];
  const float* pw      = (const float*)d_in[18];
  const float* pb      = (const float*)d_in[19];
  float* out = (float*)d_out;

  float* ws = (float*)d_ws;
  float* x     = ws; ws += NR_*D_;
  float* qb    = ws; ws += NR_*D_;
  float* kvb   = ws; ws += NR_*2*D_;
  float* bqkv  = ws; ws += NLAYERS_*240;
  ushort_t* us = (ushort_t*)ws;
  ushort_t* xnbf  = us; us += NR_*KP_;
  ushort_t* attbf = us; us += NR_*KP_;
  ushort_t* wqkvT = us; us += S3_;
  ushort_t* woT   = us; us += S4_;
  ushort_t* pwT   = us; us += S5_;
  uchar_t* ub = (uchar_t*)us;
  uchar_t* w18 = ub; ub += S1_;
  uchar_t* w28 = ub; ub += S2_;

  k_wprep<<<(WPREP_N_ + 255)/256, 256, 0, stream>>>(w1, w2, wq, wkv, wo, pw, bq, bkv,
                                                    w18, w28, wqkvT, woT, pwT, bqkv);
  k_build_qkv<<<NR_/16, 512, 0, stream>>>(mel, ln_in_w, ln_in_b, wqkvT, bqkv, x, qb, kvb);

  for (int l = 0; l < NLAYERS_; ++l) {
    int last = (l == NLAYERS_-1);
    k_attn<<<dim3(NSEG_, B_, H_), 256, 0, stream>>>(qb, kvb, attbf);
    k_ffn_fused<<<NR_/16, 1024, 0, stream>>>(attbf,
        woT + l*D_*KP_, bo + l*D_,
        w18 + (size_t)l*FFN_*KP_, b1 + l*FFN_,
        w28 + (size_t)l*D_*FFN_, b2 + l*D_,
        ln_ff_w + l*D_, ln_ff_b + l*D_,
        ln_o_w + l*D_, ln_o_b + l*D_,
        ln_in_w + (last ? 0 : (l+1)*D_), ln_in_b + (last ? 0 : (l+1)*D_),
        last, x, xnbf,
        wqkvT + (last ? 0 : (l+1)*256*KP_), bqkv + (last ? 0 : (l+1)*240),
        qb, kvb);
  }

  k_proj_mfma<<<dim3(TU_/64, OUTD_/128, B_), 256, 0, stream>>>(xnbf, pwT, pb, lengths, out);
}

// Round 13
// 147.159 us; speedup vs baseline: 1.0112x; 1.0112x over previous
//
#include <hip/hip_runtime.h>
#include <math.h>

#define B_    2
#define TU_   1024
#define D_    80
#define H_    8
#define DH_   10
#define FFN_  2048
#define SEG_  32
#define RC_   8
#define LC_   50
#define NSEG_ 32
#define RCT_  256
#define L_    1280
#define NLAYERS_ 4
#define OUTD_ 768
#define EPS_  1e-5f
#define SCALE_ 0.31622776601683794f
#define NR_   (B_*L_)                 // 2560
#define KP_   96                      // K pad 80->96

typedef __attribute__((ext_vector_type(8))) short bf16x8;
typedef __attribute__((ext_vector_type(4))) float f32x4;
typedef unsigned short ushort_t;
typedef unsigned char uchar_t;
typedef long i64_t;

__device__ inline ushort_t f2bf(float f) {
  union { float f; unsigned u; } x; x.f = f;
  unsigned r = x.u + 0x7fffu + ((x.u >> 16) & 1u);   // RNE
  return (ushort_t)(r >> 16);
}
__device__ inline float bf2f(ushort_t u) {
  union { unsigned u; float f; } x; x.u = ((unsigned)u) << 16; return x.f;
}
// HW fp8 e4m3 convert (gfx950: v_cvt_pk_fp8_f32, RNE, saturating)
__device__ inline uchar_t f2fp8(float f) {
  return (uchar_t)(__builtin_amdgcn_cvt_pk_fp8_f32(f, f, 0, false) & 0xff);
}
// pack 4 floats -> 4 fp8 bytes in one u32 (two HW pack ops)
__device__ inline unsigned pk4fp8(float f0, float f1, float f2, float f3) {
  unsigned w = (unsigned)__builtin_amdgcn_cvt_pk_fp8_f32(f0, f1, 0, false);
  w = (unsigned)__builtin_amdgcn_cvt_pk_fp8_f32(f2, f3, (int)w, true);
  return w;
}

#define S1_ (NLAYERS_*FFN_*KP_)        // w18 fp8 [l][n2048][k96], x16
#define S2_ (NLAYERS_*D_*FFN_)         // w28 fp8 [l][n80][k2048], x16
#define S3_ (NLAYERS_*256*KP_)         // wqkvT bf16 [l][n256][k96] (scale folded in q cols)
#define S4_ (NLAYERS_*D_*KP_)          // woT bf16 [l][n80][k96]
#define S5_ (OUTD_*KP_)                // pwT bf16 [n768][k96]
#define S6_ (NLAYERS_*240)             // bqkv fp32 [l][240]
#define WSM_N_ (S3_+S4_+S5_+S6_)

// ============ small weight prep (qkv/wo/proj transposes + bias fold) ============
__global__ void k_wprep_small(const float* __restrict__ wq, const float* __restrict__ wkv,
    const float* __restrict__ wo, const float* __restrict__ pw,
    const float* __restrict__ bq, const float* __restrict__ bkv,
    ushort_t* __restrict__ wqkvT, ushort_t* __restrict__ woT,
    ushort_t* __restrict__ pwT, float* __restrict__ bqkv) {
  int idx = blockIdx.x * blockDim.x + threadIdx.x;
  if (idx < S3_) {
    int k = idx % KP_, n = (idx / KP_) % 256, l = idx / (KP_*256);
    float v = 0.f;
    if (k < D_ && n < 240) {
      if (n < D_) v = wq[(l*D_ + k)*D_ + n] * SCALE_;
      else        v = wkv[(l*D_ + k)*2*D_ + (n - D_)];
    }
    wqkvT[idx] = f2bf(v);
    return;
  }
  idx -= S3_;
  if (idx < S4_) {
    int k = idx % KP_, n = (idx / KP_) % D_, l = idx / (KP_*D_);
    woT[idx] = (k < D_) ? f2bf(wo[(l*D_ + k)*D_ + n]) : 0;
    return;
  }
  idx -= S4_;
  if (idx < S5_) {
    int k = idx % KP_, n = idx / KP_;
    pwT[idx] = (k < D_) ? f2bf(pw[k*OUTD_ + n]) : 0;
    return;
  }
  idx -= S5_;
  if (idx < S6_) {
    int c = idx % 240, l = idx / 240;
    bqkv[idx] = (c < D_) ? bq[l*D_ + c] * SCALE_ : bkv[l*2*D_ + (c - D_)];
  }
}

// ============ w1 -> w18 fp8 [l][n2048][k96], LDS-tiled transpose (coalesced both sides) ============
// grid (32, NLAYERS), 256 thr. Tile: all k (80), 64 n.
__global__ __launch_bounds__(256) void k_w1t8(const float* __restrict__ w1,
    uchar_t* __restrict__ w18) {
  int n0 = blockIdx.x * 64, l = blockIdx.y;
  int tid = threadIdx.x;
  __shared__ float t[D_][64];
  for (int idx = tid; idx < D_*64; idx += 256) {
    int k = idx >> 6, n = idx & 63;
    t[k][n] = w1[((size_t)(l*D_ + k))*FFN_ + n0 + n];      // coalesced 256B
  }
  __syncthreads();
  unsigned* out = (unsigned*)(w18 + ((size_t)l*FFN_ + n0)*KP_);
  for (int idx = tid; idx < 64*24; idx += 256) {            // 24 u32 per row
    int wq = idx % 24, n = idx / 24;
    int k = wq * 4;
    float f0 = (k+0 < D_) ? t[k+0][n]*16.f : 0.f;
    float f1 = (k+1 < D_) ? t[k+1][n]*16.f : 0.f;
    float f2 = (k+2 < D_) ? t[k+2][n]*16.f : 0.f;
    float f3 = (k+3 < D_) ? t[k+3][n]*16.f : 0.f;
    out[n*24 + wq] = pk4fp8(f0, f1, f2, f3);                // coalesced u32
  }
}

// ============ w2 -> w28 fp8 [l][n80][k2048], LDS-tiled transpose ============
// grid (32, NLAYERS), 256 thr. Tile: 64 k, all n (80).
__global__ __launch_bounds__(256) void k_w2t8(const float* __restrict__ w2,
    uchar_t* __restrict__ w28) {
  int k0 = blockIdx.x * 64, l = blockIdx.y;
  int tid = threadIdx.x;
  __shared__ float t[64][D_];
  for (int idx = tid; idx < 64*D_; idx += 256) {
    int k = idx / D_, n = idx % D_;
    t[k][n] = w2[((size_t)(l*FFN_ + k0 + k))*D_ + n];       // fully coalesced (contiguous)
  }
  __syncthreads();
  for (int idx = tid; idx < D_*16; idx += 256) {            // 16 u32 per n-row
    int u = idx % 16, n = idx / 16;
    int k = u * 4;
    unsigned w = pk4fp8(t[k+0][n]*16.f, t[k+1][n]*16.f, t[k+2][n]*16.f, t[k+3][n]*16.f);
    *(unsigned*)(w28 + ((size_t)(l*D_ + n))*FFN_ + k0 + k) = w;   // 64B-dense per row
  }
}

// ============ merged: gather mel -> x + layer-0 LN_in + QKV MFMA -> q/kv ============
__global__ __launch_bounds__(512) void k_build_qkv(const float* __restrict__ mel,
    const float* __restrict__ lw, const float* __restrict__ lb,
    const ushort_t* __restrict__ wqkvT, const float* __restrict__ bqkv,
    float* __restrict__ x, float* __restrict__ q, float* __restrict__ kv) {
  int tid = threadIdx.x;
  int wv = tid >> 6, lane = tid & 63;
  int r = lane & 15, g = lane >> 4;
  int bm = blockIdx.x * 16;
  __shared__ ushort_t hnsh[16][KP_];

  if (tid < 256) {
    int row = tid >> 4, j = tid & 15;
    int grow = bm + row;
    int b = grow / L_, i = grow % L_;
    int srow = (i < RCT_) ? ((i >> 3) + 1)*SEG_ + (i & 7) : i - RCT_;
    float v[5], s = 0.f, ss = 0.f;
    #pragma unroll
    for (int c = 0; c < 5; ++c) {
      int col = j + c*16;
      v[c] = mel[((size_t)b*(TU_+RC_) + srow)*D_ + col];
      x[(size_t)grow*D_ + col] = v[c];
      s += v[c]; ss += v[c]*v[c];
    }
    s  += __shfl_xor(s, 1, 16);  ss += __shfl_xor(ss, 1, 16);
    s  += __shfl_xor(s, 2, 16);  ss += __shfl_xor(ss, 2, 16);
    s  += __shfl_xor(s, 4, 16);  ss += __shfl_xor(ss, 4, 16);
    s  += __shfl_xor(s, 8, 16);  ss += __shfl_xor(ss, 8, 16);
    float mean = s * (1.f/D_);
    float var  = ss * (1.f/D_) - mean*mean;
    float inv  = rsqrtf(var + EPS_);
    #pragma unroll
    for (int c = 0; c < 5; ++c) {
      int col = j + c*16;
      hnsh[row][col] = f2bf((v[c] - mean) * inv * lw[col] + lb[col]);
    }
    hnsh[row][D_ + j] = 0;
  }
  __syncthreads();

  for (int t = wv; t < 15; t += 8) {
    f32x4 acc = {};
    #pragma unroll
    for (int ks = 0; ks < KP_; ks += 32) {
      bf16x8 a  = *(const bf16x8*)(&hnsh[r][ks + g*8]);
      bf16x8 bb = *(const bf16x8*)(wqkvT + (size_t)(t*16 + r)*KP_ + ks + g*8);
      acc = __builtin_amdgcn_mfma_f32_16x16x32_bf16(a, bb, acc, 0, 0, 0);
    }
    int col = t*16 + r;
    float bc = bqkv[col];
    #pragma unroll
    for (int rr = 0; rr < 4; ++rr) {
      int row = bm + g*4 + rr;
      float v = acc[rr] + bc;
      if (col < D_) q[(size_t)row*D_ + col] = v;
      else          kv[(size_t)row*2*D_ + (col - D_)] = v;
    }
  }
}

// ============ block-sparse attention -> attbf bf16 [2560][96] ============
__global__ __launch_bounds__(256) void k_attn(const float* __restrict__ q,
    const float* __restrict__ kv, ushort_t* __restrict__ att) {
  int seg = blockIdx.x, b = blockIdx.y, h = blockIdx.z;
  int tid = threadIdx.x;
  int seg_start = seg*SEG_ - LC_; if (seg_start < 0) seg_start = 0;
  int kc = RC_ + (seg+1)*SEG_ - seg_start;       // <= 90
  __shared__ float Ksh[90][DH_];
  __shared__ float Vsh[90][DH_];
  __shared__ float Qsh[40][DH_];
  __shared__ float Ssh[40][90];
  __shared__ float inv_sh[40];
  // float2 staging: one iteration covers K and V for a (kk, d-pair)
  for (int idx = tid; idx < kc*5; idx += 256) {
    int kk = idx / 5, dd = (idx % 5) * 2;
    int krow = (kk < RC_) ? seg*RC_ + kk : RCT_ + seg_start + (kk - RC_);
    const float* base = kv + ((size_t)b*L_ + krow)*2*D_ + h*DH_ + dd;
    float2 kf = *(const float2*)base;
    float2 vf = *(const float2*)(base + D_);
    Ksh[kk][dd] = kf.x; Ksh[kk][dd+1] = kf.y;
    Vsh[kk][dd] = vf.x; Vsh[kk][dd+1] = vf.y;
  }
  if (tid < 200) {
    int qi = tid / 5, dd = (tid % 5) * 2;
    int qrow = (qi < RC_) ? seg*RC_ + qi : RCT_ + seg*SEG_ + (qi - RC_);
    float2 qf = *(const float2*)(q + ((size_t)b*L_ + qrow)*D_ + h*DH_ + dd);
    Qsh[qi][dd] = qf.x; Qsh[qi][dd+1] = qf.y;
  }
  __syncthreads();
  for (int p = tid; p < 40*kc; p += 256) {
    int qi = p / kc, kk = p - qi*kc;
    float s = 0.f;
    #pragma unroll
    for (int d = 0; d < DH_; ++d) s += Qsh[qi][d] * Ksh[kk][d];
    Ssh[qi][kk] = s;
  }
  __syncthreads();
  if (tid < 160) {
    int row = tid >> 2, j = tid & 3;
    float pm = -INFINITY;
    for (int kk = j; kk < kc; kk += 4) pm = fmaxf(pm, Ssh[row][kk]);
    pm = fmaxf(pm, __shfl_xor(pm, 1, 4));
    pm = fmaxf(pm, __shfl_xor(pm, 2, 4));
    float ps = 0.f;
    for (int kk = j; kk < kc; kk += 4) {
      float e = __expf(Ssh[row][kk] - pm);
      Ssh[row][kk] = e;
      ps += e;
    }
    ps += __shfl_xor(ps, 1, 4);
    ps += __shfl_xor(ps, 2, 4);
    if (j == 0) inv_sh[row] = 1.f / ps;
  }
  __syncthreads();
  for (int o = tid; o < 40*DH_; o += 256) {
    int qi = o / DH_, d = o - qi*DH_;
    float acc = 0.f;
    for (int kk = 0; kk < kc; ++kk) acc += Ssh[qi][kk] * Vsh[kk][d];
    int qrow = (qi < RC_) ? seg*RC_ + qi : RCT_ + seg*SEG_ + (qi - RC_);
    att[((size_t)b*L_ + qrow)*KP_ + h*DH_ + d] = f2bf(acc * inv_sh[qi]);
  }
  if (h == 0) {  // zero K-pad cols 80..95
    for (int idx = tid; idx < 40*16; idx += 256) {
      int qi = idx >> 4, c = D_ + (idx & 15);
      int qrow = (qi < RC_) ? seg*RC_ + qi : RCT_ + seg*SEG_ + (qi - RC_);
      att[((size_t)b*L_ + qrow)*KP_ + c] = 0;
    }
  }
}

// ============ fused per-layer tail (16 waves): WO(bf16) + res + LN_ff +
//              FFN1(fp8) + FFN2(fp8) + reduce + res + LN_out -> x,
//              LN_in(next) -> QKV(next, bf16) ============
__global__ __launch_bounds__(1024) void k_ffn_fused(const ushort_t* __restrict__ attbf,
    const ushort_t* __restrict__ woT, const float* __restrict__ bo,
    const uchar_t* __restrict__ w18, const float* __restrict__ b1,
    const uchar_t* __restrict__ w28, const float* __restrict__ b2,
    const float* __restrict__ lfw, const float* __restrict__ lfb,
    const float* __restrict__ low, const float* __restrict__ lob,
    const float* __restrict__ liw, const float* __restrict__ lib, int mode,
    float* __restrict__ x, ushort_t* __restrict__ xnbf,
    const ushort_t* __restrict__ wqkvT_n, const float* __restrict__ bqkv_n,
    float* __restrict__ q, float* __restrict__ kv) {
  int tid = threadIdx.x;
  int wv = tid >> 6, lane = tid & 63;
  int r = lane & 15, g = lane >> 4;
  int bm = blockIdx.x * 16;
  __shared__ ushort_t attsh[16][KP_];
  __shared__ ushort_t hnsh[16][KP_];
  __shared__ uchar_t  hn8[16][104];
  __shared__ uchar_t  ff18[16][16][136];
  __shared__ ushort_t redb[16][16][D_];
  __shared__ float    vsh[16][D_];

  if (tid < 192) {
    int row = tid / 12, c = (tid % 12) * 8;
    *(bf16x8*)&attsh[row][c] = *(const bf16x8*)(attbf + (size_t)(bm+row)*KP_ + c);
  }
  __syncthreads();

  if (wv < 5) {
    f32x4 acc = {};
    #pragma unroll
    for (int ks = 0; ks < KP_; ks += 32) {
      bf16x8 a  = *(const bf16x8*)(&attsh[r][ks + g*8]);
      bf16x8 bb = *(const bf16x8*)(woT + (size_t)(wv*16 + r)*KP_ + ks + g*8);
      acc = __builtin_amdgcn_mfma_f32_16x16x32_bf16(a, bb, acc, 0, 0, 0);
    }
    #pragma unroll
    for (int rr = 0; rr < 4; ++rr)
      vsh[g*4 + rr][wv*16 + r] = acc[rr];
  }
  __syncthreads();

  if (tid < 256) {
    int row = tid >> 4, j = tid & 15;
    int grow = bm + row;
    float v[5], s = 0.f, ss = 0.f;
    #pragma unroll
    for (int c = 0; c < 5; ++c) {
      int col = j + c*16;
      v[c] = vsh[row][col] + bo[col] + x[(size_t)grow*D_ + col];
      vsh[row][col] = v[c];
      s += v[c]; ss += v[c]*v[c];
    }
    s  += __shfl_xor(s, 1, 16);  ss += __shfl_xor(ss, 1, 16);
    s  += __shfl_xor(s, 2, 16);  ss += __shfl_xor(ss, 2, 16);
    s  += __shfl_xor(s, 4, 16);  ss += __shfl_xor(ss, 4, 16);
    s  += __shfl_xor(s, 8, 16);  ss += __shfl_xor(ss, 8, 16);
    float mean = s * (1.f/D_);
    float var  = ss * (1.f/D_) - mean*mean;
    float inv  = rsqrtf(var + EPS_);
    #pragma unroll
    for (int c = 0; c < 5; ++c) {
      int col = j + c*16;
      hn8[row][col] = f2fp8((v[c] - mean) * inv * lfw[col] + lfb[col]);
    }
    hn8[row][D_ + j] = 0;
  }
  __syncthreads();

  // FFN1 fp8: M=16 x N=128(per wave) x K=96
  f32x4 acc1[8];
  #pragma unroll
  for (int ni = 0; ni < 8; ++ni) acc1[ni] = (f32x4){0.f,0.f,0.f,0.f};
  int nbase = wv*128;
  #pragma unroll
  for (int ks = 0; ks < KP_; ks += 32) {
    i64_t a = *(const i64_t*)(&hn8[r][ks + g*8]);
    #pragma unroll
    for (int ni = 0; ni < 8; ++ni) {
      i64_t bb = *(const i64_t*)(w18 + (size_t)(nbase + ni*16 + r)*KP_ + ks + g*8);
      acc1[ni] = __builtin_amdgcn_mfma_f32_16x16x32_fp8_fp8(a, bb, acc1[ni], 0, 0, 0);
    }
  }
  #pragma unroll
  for (int ni = 0; ni < 8; ++ni) {
    int col = nbase + ni*16 + r;
    float bc = b1[col];
    #pragma unroll
    for (int rr = 0; rr < 4; ++rr) {
      float v = acc1[ni][rr] * 0.0625f + bc;
      ff18[wv][g*4 + rr][ni*16 + r] = f2fp8(fmaxf(v, 0.f) * 8.f);
    }
  }

  // FFN2 fp8: M=16 x N=80 x K=128 (this wave's chunk)
  f32x4 acc2[5] = {};
  #pragma unroll
  for (int ks = 0; ks < 128; ks += 32) {
    i64_t a = *(const i64_t*)(&ff18[wv][r][ks + g*8]);
    #pragma unroll
    for (int nf = 0; nf < 5; ++nf) {
      i64_t bb = *(const i64_t*)(w28 + (size_t)(nf*16 + r)*FFN_ + wv*128 + ks + g*8);
      acc2[nf] = __builtin_amdgcn_mfma_f32_16x16x32_fp8_fp8(a, bb, acc2[nf], 0, 0, 0);
    }
  }
  #pragma unroll
  for (int nf = 0; nf < 5; ++nf)
    #pragma unroll
    for (int rr = 0; rr < 4; ++rr)
      redb[wv][g*4 + rr][nf*16 + r] = f2bf(acc2[nf][rr]);
  __syncthreads();

  for (int e = tid; e < 16*D_; e += 1024) {
    int row = e / D_, col = e % D_;
    float s0 = 0.f, s1 = 0.f, s2 = 0.f, s3 = 0.f;
    #pragma unroll
    for (int w = 0; w < 16; w += 4) {
      s0 += bf2f(redb[w+0][row][col]);
      s1 += bf2f(redb[w+1][row][col]);
      s2 += bf2f(redb[w+2][row][col]);
      s3 += bf2f(redb[w+3][row][col]);
    }
    vsh[row][col] = ((s0+s1)+(s2+s3)) * (1.f/128.f) + b2[col] + vsh[row][col];
  }
  __syncthreads();
  if (tid < 256) {
    int row = tid >> 4, j = tid & 15;
    float v[5], s = 0.f, ss = 0.f;
    #pragma unroll
    for (int c = 0; c < 5; ++c) {
      v[c] = vsh[row][j + c*16];
      s += v[c]; ss += v[c]*v[c];
    }
    s  += __shfl_xor(s, 1, 16);  ss += __shfl_xor(ss, 1, 16);
    s  += __shfl_xor(s, 2, 16);  ss += __shfl_xor(ss, 2, 16);
    s  += __shfl_xor(s, 4, 16);  ss += __shfl_xor(ss, 4, 16);
    s  += __shfl_xor(s, 8, 16);  ss += __shfl_xor(ss, 8, 16);
    float mean = s * (1.f/D_);
    float var  = ss * (1.f/D_) - mean*mean;
    float inv  = rsqrtf(var + EPS_);
    int grow = bm + row;
    float xs[5];
    float s2 = 0.f, ss2 = 0.f;
    #pragma unroll
    for (int c = 0; c < 5; ++c) {
      int col = j + c*16;
      xs[c] = (v[c] - mean) * inv * low[col] + lob[col];
      x[(size_t)grow*D_ + col] = xs[c];
      s2 += xs[c]; ss2 += xs[c]*xs[c];
    }
    if (mode == 0) {
      s2  += __shfl_xor(s2, 1, 16);  ss2 += __shfl_xor(ss2, 1, 16);
      s2  += __shfl_xor(s2, 2, 16);  ss2 += __shfl_xor(ss2, 2, 16);
      s2  += __shfl_xor(s2, 4, 16);  ss2 += __shfl_xor(ss2, 4, 16);
      s2  += __shfl_xor(s2, 8, 16);  ss2 += __shfl_xor(ss2, 8, 16);
      float m2 = s2 * (1.f/D_);
      float v2 = ss2 * (1.f/D_) - m2*m2;
      float i2 = rsqrtf(v2 + EPS_);
      #pragma unroll
      for (int c = 0; c < 5; ++c) {
        int col = j + c*16;
        hnsh[row][col] = f2bf((xs[c] - m2) * i2 * liw[col] + lib[col]);
      }
      hnsh[row][D_ + j] = 0;
    } else {
      #pragma unroll
      for (int c = 0; c < 5; ++c)
        xnbf[(size_t)grow*KP_ + j + c*16] = f2bf(xs[c]);
      xnbf[(size_t)grow*KP_ + D_ + j] = 0;
    }
  }

  if (mode == 0) {
    __syncthreads();
    if (wv < 15) {
      int t = wv;
      f32x4 acc = {};
      #pragma unroll
      for (int ks = 0; ks < KP_; ks += 32) {
        bf16x8 a  = *(const bf16x8*)(&hnsh[r][ks + g*8]);
        bf16x8 bb = *(const bf16x8*)(wqkvT_n + (size_t)(t*16 + r)*KP_ + ks + g*8);
        acc = __builtin_amdgcn_mfma_f32_16x16x32_bf16(a, bb, acc, 0, 0, 0);
      }
      int col = t*16 + r;
      float bc = bqkv_n[col];
      #pragma unroll
      for (int rr = 0; rr < 4; ++rr) {
        int row = bm + g*4 + rr;
        float v = acc[rr] + bc;
        if (col < D_) q[(size_t)row*D_ + col] = v;
        else          kv[(size_t)row*2*D_ + (col - D_)] = v;
      }
    }
  }
}

// ============ final proj MFMA, 64x64 tiles (384 blocks) + lengths tail ============
__global__ __launch_bounds__(256) void k_proj_mfma(const ushort_t* __restrict__ xbf,
    const ushort_t* __restrict__ pwT, const float* __restrict__ pb,
    const int* __restrict__ len, float* __restrict__ out) {
  int wv = threadIdx.x >> 6, lane = threadIdx.x & 63;
  int bm = blockIdx.x * 64;
  int bn = blockIdx.y * 64 + wv*16;
  int b  = blockIdx.z;
  int r = lane & 15, g = lane >> 4;
  f32x4 acc[4] = {};
  const ushort_t* Ab = xbf + ((size_t)(b*L_ + RCT_ + bm) + r)*KP_ + g*8;
  const ushort_t* Bb = pwT + (size_t)(bn + r)*KP_ + g*8;
  #pragma unroll
  for (int ks = 0; ks < KP_; ks += 32) {
    bf16x8 bb = *(const bf16x8*)(Bb + ks);
    #pragma unroll
    for (int mf = 0; mf < 4; ++mf) {
      bf16x8 a = *(const bf16x8*)(Ab + mf*16*KP_ + ks);
      acc[mf] = __builtin_amdgcn_mfma_f32_16x16x32_bf16(a, bb, acc[mf], 0, 0, 0);
    }
  }
  int col = bn + r;
  float bc = pb[col];
  #pragma unroll
  for (int mf = 0; mf < 4; ++mf)
    #pragma unroll
    for (int rr = 0; rr < 4; ++rr) {
      int row = bm + mf*16 + g*4 + rr;
      out[((size_t)b*TU_ + row)*OUTD_ + col] = acc[mf][rr] + bc;
    }
  if (blockIdx.x == 0 && blockIdx.y == 0 && blockIdx.z == 0 && threadIdx.x < B_)
    out[(size_t)B_*TU_*OUTD_ + threadIdx.x] = (float)len[threadIdx.x];
}

extern "C" void kernel_launch(void* const* d_in, const int* in_sizes, int n_in,
                              void* d_out, int out_size, void* d_ws, size_t ws_size,
                              hipStream_t stream) {
  const float* mel     = (const float*)d_in[0];
  const int*   lengths = (const int*)  d_in[1];
  const float* ln_in_w = (const float*)d_in[2];
  const float* ln_in_b = (const float*)d_in[3];
  const float* wq      = (const float*)d_in[4];
  const float* bq      = (const float*)d_in[5];
  const float* wkv     = (const float*)d_in[6];
  const float* bkv     = (const float*)d_in[7];
  const float* wo      = (const float*)d_in[8];
  const float* bo      = (const float*)d_in[9];
  const float* ln_ff_w = (const float*)d_in[10];
  const float* ln_ff_b = (const float*)d_in[11];
  const float* w1      = (const float*)d_in[12];
  const float* b1      = (const float*)d_in[13];
  const float* w2      = (const float*)d_in[14];
  const float* b2      = (const float*)d_in[15];
  const float* ln_o_w  = (const float*)d_in[16];
  const float* ln_o_b  = (const float*)d_in[17];
  const float* pw      = (const float*)d_in[18];
  const float* pb      = (const float*)d_in[19];
  float* out = (float*)d_out;

  float* ws = (float*)d_ws;
  float* x     = ws; ws += NR_*D_;
  float* qb    = ws; ws += NR_*D_;
  float* kvb   = ws; ws += NR_*2*D_;
  float* bqkv  = ws; ws += NLAYERS_*240;
  ushort_t* us = (ushort_t*)ws;
  ushort_t* xnbf  = us; us += NR_*KP_;
  ushort_t* attbf = us; us += NR_*KP_;
  ushort_t* wqkvT = us; us += S3_;
  ushort_t* woT   = us; us += S4_;
  ushort_t* pwT   = us; us += S5_;
  uchar_t* ub = (uchar_t*)us;
  uchar_t* w18 = ub; ub += S1_;
  uchar_t* w28 = ub; ub += S2_;

  k_wprep_small<<<(WSM_N_ + 255)/256, 256, 0, stream>>>(wq, wkv, wo, pw, bq, bkv,
                                                        wqkvT, woT, pwT, bqkv);
  k_w1t8<<<dim3(FFN_/64, NLAYERS_), 256, 0, stream>>>(w1, w18);
  k_w2t8<<<dim3(FFN_/64, NLAYERS_), 256, 0, stream>>>(w2, w28);
  k_build_qkv<<<NR_/16, 512, 0, stream>>>(mel, ln_in_w, ln_in_b, wqkvT, bqkv, x, qb, kvb);

  for (int l = 0; l < NLAYERS_; ++l) {
    int last = (l == NLAYERS_-1);
    k_attn<<<dim3(NSEG_, B_, H_), 256, 0, stream>>>(qb, kvb, attbf);
    k_ffn_fused<<<NR_/16, 1024, 0, stream>>>(attbf,
        woT + l*D_*KP_, bo + l*D_,
        w18 + (size_t)l*FFN_*KP_, b1 + l*FFN_,
        w28 + (size_t)l*D_*FFN_, b2 + l*D_,
        ln_ff_w + l*D_, ln_ff_b + l*D_,
        ln_o_w + l*D_, ln_o_b + l*D_,
        ln_in_w + (last ? 0 : (l+1)*D_), ln_in_b + (last ? 0 : (l+1)*D_),
        last, x, xnbf,
        wqkvT + (last ? 0 : (l+1)*256*KP_), bqkv + (last ? 0 : (l+1)*240),
        qb, kvb);
  }

  k_proj_mfma<<<dim3(TU_/64, OUTD_/64, B_), 256, 0, stream>>>(xnbf, pwT, pb, lengths, out);
}

// Round 14
// 117.194 us; speedup vs baseline: 1.2698x; 1.2557x over previous
//
#include <hip/hip_runtime.h>
#include <math.h>

#define B_    2
#define TU_   1024
#define D_    80
#define H_    8
#define DH_   10
#define FFN_  2048
#define SEG_  32
#define RC_   8
#define LC_   50
#define NSEG_ 32
#define RCT_  256
#define L_    1280
#define NLAYERS_ 4
#define OUTD_ 768
#define EPS_  1e-5f
#define SCALE_ 0.31622776601683794f
#define NR_   (B_*L_)                 // 2560
#define KP_   96                      // K pad 80->96

typedef __attribute__((ext_vector_type(8))) short bf16x8;
typedef __attribute__((ext_vector_type(4))) float f32x4;
typedef unsigned short ushort_t;
typedef unsigned char uchar_t;
typedef long i64_t;

__device__ inline ushort_t f2bf(float f) {
  union { float f; unsigned u; } x; x.f = f;
  unsigned r = x.u + 0x7fffu + ((x.u >> 16) & 1u);   // RNE
  return (ushort_t)(r >> 16);
}
__device__ inline float bf2f(ushort_t u) {
  union { unsigned u; float f; } x; x.u = ((unsigned)u) << 16; return x.f;
}
__device__ inline uchar_t f2fp8(float f) {
  return (uchar_t)(__builtin_amdgcn_cvt_pk_fp8_f32(f, f, 0, false) & 0xff);
}
__device__ inline unsigned pk4fp8(float f0, float f1, float f2, float f3) {
  unsigned w = (unsigned)__builtin_amdgcn_cvt_pk_fp8_f32(f0, f1, 0, false);
  w = (unsigned)__builtin_amdgcn_cvt_pk_fp8_f32(f2, f3, (int)w, true);
  return w;
}

// ---- fragment-tiled sizes (tile = 512 elements = 64 lanes x 8) ----
#define S1_  (NLAYERS_*FFN_*KP_)       // w18 fp8 tiled [l][128 ntile][3 ktile][512]
#define S2_  (NLAYERS_*D_*FFN_)        // w28 fp8 tiled [l][5 ntile][64 ktile][512]
#define S3_  (NLAYERS_*45*512)         // wqkvT bf16 tiled [l][15][3][512]
#define S4_  (NLAYERS_*15*512)         // woT bf16 tiled [l][5][3][512]
#define S5_  (144*512)                 // pwT bf16 tiled [48][3][512]
#define S6_  (NLAYERS_*240)            // bqkv fp32
#define WSM_N_ (S3_+S4_+S5_+S6_)

// ============ small weight prep: fragment-tiled bf16 (qkv/wo/proj) + bias fold ============
__global__ void k_wprep_small(const float* __restrict__ wq, const float* __restrict__ wkv,
    const float* __restrict__ wo, const float* __restrict__ pw,
    const float* __restrict__ bq, const float* __restrict__ bkv,
    ushort_t* __restrict__ wqkvT, ushort_t* __restrict__ woT,
    ushort_t* __restrict__ pwT, float* __restrict__ bqkv) {
  int idx = blockIdx.x * blockDim.x + threadIdx.x;
  if (idx < S3_) {
    int l = idx / (45*512); int rem = idx % (45*512);
    int tile = rem / 512, off = rem % 512;
    int t = tile / 3, kt = tile % 3;
    int lane = off >> 3, j = off & 7;
    int n = t*16 + (lane & 15);
    int k = kt*32 + (lane >> 4)*8 + j;
    float v = 0.f;
    if (k < D_) {
      if (n < D_)       v = wq[(l*D_ + k)*D_ + n] * SCALE_;
      else if (n < 240) v = wkv[(l*D_ + k)*2*D_ + (n - D_)];
    }
    wqkvT[idx] = f2bf(v);
    return;
  }
  idx -= S3_;
  if (idx < S4_) {
    int l = idx / (15*512); int rem = idx % (15*512);
    int tile = rem / 512, off = rem % 512;
    int nf = tile / 3, kt = tile % 3;
    int lane = off >> 3, j = off & 7;
    int n = nf*16 + (lane & 15);
    int k = kt*32 + (lane >> 4)*8 + j;
    woT[idx] = (k < D_) ? f2bf(wo[(l*D_ + k)*D_ + n]) : 0;
    return;
  }
  idx -= S4_;
  if (idx < S5_) {
    int tile = idx / 512, off = idx % 512;
    int t = tile / 3, kt = tile % 3;
    int lane = off >> 3, j = off & 7;
    int n = t*16 + (lane & 15);
    int k = kt*32 + (lane >> 4)*8 + j;
    pwT[idx] = (k < D_) ? f2bf(pw[k*OUTD_ + n]) : 0;
    return;
  }
  idx -= S5_;
  if (idx < S6_) {
    int c = idx % 240, l = idx / 240;
    bqkv[idx] = (c < D_) ? bq[l*D_ + c] * SCALE_ : bkv[l*2*D_ + (c - D_)];
  }
}

// ============ w1 -> w18 fp8 fragment-tiled, LDS transpose (coalesced both sides) ============
// grid (32, NLAYERS), 256 thr. Block covers 64 n (4 n-tiles), all k.
__global__ __launch_bounds__(256) void k_w1t8(const float* __restrict__ w1,
    uchar_t* __restrict__ w18) {
  int n0 = blockIdx.x * 64, l = blockIdx.y;
  int tid = threadIdx.x;
  __shared__ float t[D_][64];
  for (int idx = tid; idx < D_*64; idx += 256) {
    int k = idx >> 6, n = idx & 63;
    t[k][n] = w1[((size_t)(l*D_ + k))*FFN_ + n0 + n];      // coalesced 256B rows
  }
  __syncthreads();
  for (int idx = tid; idx < 4*3*64; idx += 256) {          // (nis, kt, lane)
    int nis = idx / 192, rem = idx % 192;
    int kt = rem / 64, lane = rem % 64;
    int r = lane & 15, g = lane >> 4;
    int nl = nis*16 + r;
    int kb = kt*32 + g*8;
    float v[8];
    #pragma unroll
    for (int j = 0; j < 8; ++j) {
      int k = kb + j;
      v[j] = (k < D_) ? t[k][nl]*16.f : 0.f;
    }
    uint2 o;
    o.x = pk4fp8(v[0], v[1], v[2], v[3]);
    o.y = pk4fp8(v[4], v[5], v[6], v[7]);
    size_t ni = (size_t)(n0 >> 4) + nis;
    *(uint2*)(w18 + (((size_t)l*128 + ni)*3 + kt)*512 + lane*8) = o;   // contiguous 512B tile
  }
}

// ============ w2 -> w28 fp8 fragment-tiled ============
// grid (32, NLAYERS), 256 thr. Block covers 64 k (2 k-tiles), all n.
__global__ __launch_bounds__(256) void k_w2t8(const float* __restrict__ w2,
    uchar_t* __restrict__ w28) {
  int k0 = blockIdx.x * 64, l = blockIdx.y;
  int tid = threadIdx.x;
  __shared__ float t[64][D_];
  for (int idx = tid; idx < 64*D_; idx += 256) {
    int k = idx / D_, n = idx % D_;
    t[k][n] = w2[((size_t)(l*FFN_ + k0 + k))*D_ + n];      // contiguous
  }
  __syncthreads();
  for (int idx = tid; idx < 5*2*64; idx += 256) {          // (nf, ktl, lane)
    int nf = idx / 128, rem = idx % 128;
    int ktl = rem / 64, lane = rem % 64;
    int r = lane & 15, g = lane >> 4;
    int n = nf*16 + r;
    int kb = ktl*32 + g*8;
    uint2 o;
    o.x = pk4fp8(t[kb+0][n]*16.f, t[kb+1][n]*16.f, t[kb+2][n]*16.f, t[kb+3][n]*16.f);
    o.y = pk4fp8(t[kb+4][n]*16.f, t[kb+5][n]*16.f, t[kb+6][n]*16.f, t[kb+7][n]*16.f);
    size_t kt = (size_t)(k0 >> 5) + ktl;
    *(uint2*)(w28 + (((size_t)l*5 + nf)*64 + kt)*512 + lane*8) = o;
  }
}

// ============ merged: gather mel -> x + layer-0 LN_in + QKV MFMA -> q/kv ============
__global__ __launch_bounds__(512) void k_build_qkv(const float* __restrict__ mel,
    const float* __restrict__ lw, const float* __restrict__ lb,
    const ushort_t* __restrict__ wqkvT, const float* __restrict__ bqkv,
    float* __restrict__ x, float* __restrict__ q, float* __restrict__ kv) {
  int tid = threadIdx.x;
  int wv = tid >> 6, lane = tid & 63;
  int r = lane & 15, g = lane >> 4;
  int bm = blockIdx.x * 16;
  __shared__ ushort_t hnsh[16][KP_];

  if (tid < 256) {
    int row = tid >> 4, j = tid & 15;
    int grow = bm + row;
    int b = grow / L_, i = grow % L_;
    int srow = (i < RCT_) ? ((i >> 3) + 1)*SEG_ + (i & 7) : i - RCT_;
    float v[5], s = 0.f, ss = 0.f;
    #pragma unroll
    for (int c = 0; c < 5; ++c) {
      int col = j + c*16;
      v[c] = mel[((size_t)b*(TU_+RC_) + srow)*D_ + col];
      x[(size_t)grow*D_ + col] = v[c];
      s += v[c]; ss += v[c]*v[c];
    }
    s  += __shfl_xor(s, 1, 16);  ss += __shfl_xor(ss, 1, 16);
    s  += __shfl_xor(s, 2, 16);  ss += __shfl_xor(ss, 2, 16);
    s  += __shfl_xor(s, 4, 16);  ss += __shfl_xor(ss, 4, 16);
    s  += __shfl_xor(s, 8, 16);  ss += __shfl_xor(ss, 8, 16);
    float mean = s * (1.f/D_);
    float var  = ss * (1.f/D_) - mean*mean;
    float inv  = rsqrtf(var + EPS_);
    #pragma unroll
    for (int c = 0; c < 5; ++c) {
      int col = j + c*16;
      hnsh[row][col] = f2bf((v[c] - mean) * inv * lw[col] + lb[col]);
    }
    hnsh[row][D_ + j] = 0;
  }
  __syncthreads();

  for (int t = wv; t < 15; t += 8) {
    f32x4 acc = {};
    #pragma unroll
    for (int kt = 0; kt < 3; ++kt) {
      bf16x8 a  = *(const bf16x8*)(&hnsh[r][kt*32 + g*8]);
      bf16x8 bb = *(const bf16x8*)(wqkvT + ((size_t)t*3 + kt)*512 + lane*8);
      acc = __builtin_amdgcn_mfma_f32_16x16x32_bf16(a, bb, acc, 0, 0, 0);
    }
    int col = t*16 + r;
    float bc = bqkv[col];
    #pragma unroll
    for (int rr = 0; rr < 4; ++rr) {
      int row = bm + g*4 + rr;
      float v = acc[rr] + bc;
      if (col < D_) q[(size_t)row*D_ + col] = v;
      else          kv[(size_t)row*2*D_ + (col - D_)] = v;
    }
  }
}

// ============ block-sparse attention -> attbf bf16 [2560][96] ============
__global__ __launch_bounds__(256) void k_attn(const float* __restrict__ q,
    const float* __restrict__ kv, ushort_t* __restrict__ att) {
  int seg = blockIdx.x, b = blockIdx.y, h = blockIdx.z;
  int tid = threadIdx.x;
  int seg_start = seg*SEG_ - LC_; if (seg_start < 0) seg_start = 0;
  int kc = RC_ + (seg+1)*SEG_ - seg_start;       // <= 90
  __shared__ float Ksh[90][DH_];
  __shared__ float Vsh[90][DH_];
  __shared__ float Qsh[40][DH_];
  __shared__ float Ssh[40][90];
  __shared__ float inv_sh[40];
  for (int idx = tid; idx < kc*5; idx += 256) {
    int kk = idx / 5, dd = (idx % 5) * 2;
    int krow = (kk < RC_) ? seg*RC_ + kk : RCT_ + seg_start + (kk - RC_);
    const float* base = kv + ((size_t)b*L_ + krow)*2*D_ + h*DH_ + dd;
    float2 kf = *(const float2*)base;
    float2 vf = *(const float2*)(base + D_);
    Ksh[kk][dd] = kf.x; Ksh[kk][dd+1] = kf.y;
    Vsh[kk][dd] = vf.x; Vsh[kk][dd+1] = vf.y;
  }
  if (tid < 200) {
    int qi = tid / 5, dd = (tid % 5) * 2;
    int qrow = (qi < RC_) ? seg*RC_ + qi : RCT_ + seg*SEG_ + (qi - RC_);
    float2 qf = *(const float2*)(q + ((size_t)b*L_ + qrow)*D_ + h*DH_ + dd);
    Qsh[qi][dd] = qf.x; Qsh[qi][dd+1] = qf.y;
  }
  __syncthreads();
  for (int p = tid; p < 40*kc; p += 256) {
    int qi = p / kc, kk = p - qi*kc;
    float s = 0.f;
    #pragma unroll
    for (int d = 0; d < DH_; ++d) s += Qsh[qi][d] * Ksh[kk][d];
    Ssh[qi][kk] = s;
  }
  __syncthreads();
  if (tid < 160) {
    int row = tid >> 2, j = tid & 3;
    float pm = -INFINITY;
    for (int kk = j; kk < kc; kk += 4) pm = fmaxf(pm, Ssh[row][kk]);
    pm = fmaxf(pm, __shfl_xor(pm, 1, 4));
    pm = fmaxf(pm, __shfl_xor(pm, 2, 4));
    float ps = 0.f;
    for (int kk = j; kk < kc; kk += 4) {
      float e = __expf(Ssh[row][kk] - pm);
      Ssh[row][kk] = e;
      ps += e;
    }
    ps += __shfl_xor(ps, 1, 4);
    ps += __shfl_xor(ps, 2, 4);
    if (j == 0) inv_sh[row] = 1.f / ps;
  }
  __syncthreads();
  for (int o = tid; o < 40*DH_; o += 256) {
    int qi = o / DH_, d = o - qi*DH_;
    float acc = 0.f;
    for (int kk = 0; kk < kc; ++kk) acc += Ssh[qi][kk] * Vsh[kk][d];
    int qrow = (qi < RC_) ? seg*RC_ + qi : RCT_ + seg*SEG_ + (qi - RC_);
    att[((size_t)b*L_ + qrow)*KP_ + h*DH_ + d] = f2bf(acc * inv_sh[qi]);
  }
  if (h == 0) {
    for (int idx = tid; idx < 40*16; idx += 256) {
      int qi = idx >> 4, c = D_ + (idx & 15);
      int qrow = (qi < RC_) ? seg*RC_ + qi : RCT_ + seg*SEG_ + (qi - RC_);
      att[((size_t)b*L_ + qrow)*KP_ + c] = 0;
    }
  }
}

// ============ fused per-layer tail (16 waves), fragment-tiled weights ============
__global__ __launch_bounds__(1024) void k_ffn_fused(const ushort_t* __restrict__ attbf,
    const ushort_t* __restrict__ woT, const float* __restrict__ bo,
    const uchar_t* __restrict__ w18, const float* __restrict__ b1,
    const uchar_t* __restrict__ w28, const float* __restrict__ b2,
    const float* __restrict__ lfw, const float* __restrict__ lfb,
    const float* __restrict__ low, const float* __restrict__ lob,
    const float* __restrict__ liw, const float* __restrict__ lib, int mode,
    float* __restrict__ x, ushort_t* __restrict__ xnbf,
    const ushort_t* __restrict__ wqkvT_n, const float* __restrict__ bqkv_n,
    float* __restrict__ q, float* __restrict__ kv) {
  int tid = threadIdx.x;
  int wv = tid >> 6, lane = tid & 63;
  int r = lane & 15, g = lane >> 4;
  int bm = blockIdx.x * 16;
  __shared__ ushort_t attsh[16][KP_];
  __shared__ ushort_t hnsh[16][KP_];
  __shared__ uchar_t  hn8[16][104];
  __shared__ uchar_t  ff18[16][16][136];
  __shared__ ushort_t redb[16][16][D_];
  __shared__ float    vsh[16][D_];

  if (tid < 192) {
    int row = tid / 12, c = (tid % 12) * 8;
    *(bf16x8*)&attsh[row][c] = *(const bf16x8*)(attbf + (size_t)(bm+row)*KP_ + c);
  }
  __syncthreads();

  // WO: waves 0..4, fragment-tiled woT (one 1KB contiguous load per kt)
  if (wv < 5) {
    f32x4 acc = {};
    #pragma unroll
    for (int kt = 0; kt < 3; ++kt) {
      bf16x8 a  = *(const bf16x8*)(&attsh[r][kt*32 + g*8]);
      bf16x8 bb = *(const bf16x8*)(woT + ((size_t)wv*3 + kt)*512 + lane*8);
      acc = __builtin_amdgcn_mfma_f32_16x16x32_bf16(a, bb, acc, 0, 0, 0);
    }
    #pragma unroll
    for (int rr = 0; rr < 4; ++rr)
      vsh[g*4 + rr][wv*16 + r] = acc[rr];
  }
  __syncthreads();

  if (tid < 256) {
    int row = tid >> 4, j = tid & 15;
    int grow = bm + row;
    float v[5], s = 0.f, ss = 0.f;
    #pragma unroll
    for (int c = 0; c < 5; ++c) {
      int col = j + c*16;
      v[c] = vsh[row][col] + bo[col] + x[(size_t)grow*D_ + col];
      vsh[row][col] = v[c];
      s += v[c]; ss += v[c]*v[c];
    }
    s  += __shfl_xor(s, 1, 16);  ss += __shfl_xor(ss, 1, 16);
    s  += __shfl_xor(s, 2, 16);  ss += __shfl_xor(ss, 2, 16);
    s  += __shfl_xor(s, 4, 16);  ss += __shfl_xor(ss, 4, 16);
    s  += __shfl_xor(s, 8, 16);  ss += __shfl_xor(ss, 8, 16);
    float mean = s * (1.f/D_);
    float var  = ss * (1.f/D_) - mean*mean;
    float inv  = rsqrtf(var + EPS_);
    #pragma unroll
    for (int c = 0; c < 5; ++c) {
      int col = j + c*16;
      hn8[row][col] = f2fp8((v[c] - mean) * inv * lfw[col] + lfb[col]);
    }
    hn8[row][D_ + j] = 0;
  }
  __syncthreads();

  // FFN1 fp8: fragment-tiled w18 (512B contiguous per load)
  f32x4 acc1[8];
  #pragma unroll
  for (int ni = 0; ni < 8; ++ni) acc1[ni] = (f32x4){0.f,0.f,0.f,0.f};
  #pragma unroll
  for (int kt = 0; kt < 3; ++kt) {
    i64_t a = *(const i64_t*)(&hn8[r][kt*32 + g*8]);
    #pragma unroll
    for (int ni = 0; ni < 8; ++ni) {
      i64_t bb = *(const i64_t*)(w18 + (((size_t)(wv*8 + ni))*3 + kt)*512 + lane*8);
      acc1[ni] = __builtin_amdgcn_mfma_f32_16x16x32_fp8_fp8(a, bb, acc1[ni], 0, 0, 0);
    }
  }
  int nbase = wv*128;
  #pragma unroll
  for (int ni = 0; ni < 8; ++ni) {
    int col = nbase + ni*16 + r;
    float bc = b1[col];
    #pragma unroll
    for (int rr = 0; rr < 4; ++rr) {
      float v = acc1[ni][rr] * 0.0625f + bc;
      ff18[wv][g*4 + rr][ni*16 + r] = f2fp8(fmaxf(v, 0.f) * 8.f);
    }
  }
  // same-wave write->read of ff18[wv]: compiler-ordered

  // FFN2 fp8: fragment-tiled w28; wave wv owns k-tiles wv*4..wv*4+3
  f32x4 acc2[5] = {};
  #pragma unroll
  for (int ks = 0; ks < 4; ++ks) {
    i64_t a = *(const i64_t*)(&ff18[wv][r][ks*32 + g*8]);
    #pragma unroll
    for (int nf = 0; nf < 5; ++nf) {
      i64_t bb = *(const i64_t*)(w28 + (((size_t)nf*64) + wv*4 + ks)*512 + lane*8);
      acc2[nf] = __builtin_amdgcn_mfma_f32_16x16x32_fp8_fp8(a, bb, acc2[nf], 0, 0, 0);
    }
  }
  #pragma unroll
  for (int nf = 0; nf < 5; ++nf)
    #pragma unroll
    for (int rr = 0; rr < 4; ++rr)
      redb[wv][g*4 + rr][nf*16 + r] = f2bf(acc2[nf][rr]);
  __syncthreads();

  for (int e = tid; e < 16*D_; e += 1024) {
    int row = e / D_, col = e % D_;
    float s0 = 0.f, s1 = 0.f, s2 = 0.f, s3 = 0.f;
    #pragma unroll
    for (int w = 0; w < 16; w += 4) {
      s0 += bf2f(redb[w+0][row][col]);
      s1 += bf2f(redb[w+1][row][col]);
      s2 += bf2f(redb[w+2][row][col]);
      s3 += bf2f(redb[w+3][row][col]);
    }
    vsh[row][col] = ((s0+s1)+(s2+s3)) * (1.f/128.f) + b2[col] + vsh[row][col];
  }
  __syncthreads();
  if (tid < 256) {
    int row = tid >> 4, j = tid & 15;
    float v[5], s = 0.f, ss = 0.f;
    #pragma unroll
    for (int c = 0; c < 5; ++c) {
      v[c] = vsh[row][j + c*16];
      s += v[c]; ss += v[c]*v[c];
    }
    s  += __shfl_xor(s, 1, 16);  ss += __shfl_xor(ss, 1, 16);
    s  += __shfl_xor(s, 2, 16);  ss += __shfl_xor(ss, 2, 16);
    s  += __shfl_xor(s, 4, 16);  ss += __shfl_xor(ss, 4, 16);
    s  += __shfl_xor(s, 8, 16);  ss += __shfl_xor(ss, 8, 16);
    float mean = s * (1.f/D_);
    float var  = ss * (1.f/D_) - mean*mean;
    float inv  = rsqrtf(var + EPS_);
    int grow = bm + row;
    float xs[5];
    float s2 = 0.f, ss2 = 0.f;
    #pragma unroll
    for (int c = 0; c < 5; ++c) {
      int col = j + c*16;
      xs[c] = (v[c] - mean) * inv * low[col] + lob[col];
      x[(size_t)grow*D_ + col] = xs[c];
      s2 += xs[c]; ss2 += xs[c]*xs[c];
    }
    if (mode == 0) {
      s2  += __shfl_xor(s2, 1, 16);  ss2 += __shfl_xor(ss2, 1, 16);
      s2  += __shfl_xor(s2, 2, 16);  ss2 += __shfl_xor(ss2, 2, 16);
      s2  += __shfl_xor(s2, 4, 16);  ss2 += __shfl_xor(ss2, 4, 16);
      s2  += __shfl_xor(s2, 8, 16);  ss2 += __shfl_xor(ss2, 8, 16);
      float m2 = s2 * (1.f/D_);
      float v2 = ss2 * (1.f/D_) - m2*m2;
      float i2 = rsqrtf(v2 + EPS_);
      #pragma unroll
      for (int c = 0; c < 5; ++c) {
        int col = j + c*16;
        hnsh[row][col] = f2bf((xs[c] - m2) * i2 * liw[col] + lib[col]);
      }
      hnsh[row][D_ + j] = 0;
    } else {
      #pragma unroll
      for (int c = 0; c < 5; ++c)
        xnbf[(size_t)grow*KP_ + j + c*16] = f2bf(xs[c]);
      xnbf[(size_t)grow*KP_ + D_ + j] = 0;
    }
  }

  // fused next-layer QKV: fragment-tiled wqkvT
  if (mode == 0) {
    __syncthreads();
    if (wv < 15) {
      int t = wv;
      f32x4 acc = {};
      #pragma unroll
      for (int kt = 0; kt < 3; ++kt) {
        bf16x8 a  = *(const bf16x8*)(&hnsh[r][kt*32 + g*8]);
        bf16x8 bb = *(const bf16x8*)(wqkvT_n + ((size_t)t*3 + kt)*512 + lane*8);
        acc = __builtin_amdgcn_mfma_f32_16x16x32_bf16(a, bb, acc, 0, 0, 0);
      }
      int col = t*16 + r;
      float bc = bqkv_n[col];
      #pragma unroll
      for (int rr = 0; rr < 4; ++rr) {
        int row = bm + g*4 + rr;
        float v = acc[rr] + bc;
        if (col < D_) q[(size_t)row*D_ + col] = v;
        else          kv[(size_t)row*2*D_ + (col - D_)] = v;
      }
    }
  }
}

// ============ final proj MFMA, 64x64 tiles, fragment-tiled pwT ============
__global__ __launch_bounds__(256) void k_proj_mfma(const ushort_t* __restrict__ xbf,
    const ushort_t* __restrict__ pwT, const float* __restrict__ pb,
    const int* __restrict__ len, float* __restrict__ out) {
  int wv = threadIdx.x >> 6, lane = threadIdx.x & 63;
  int bm = blockIdx.x * 64;
  int bn = blockIdx.y * 64 + wv*16;
  int b  = blockIdx.z;
  int r = lane & 15, g = lane >> 4;
  f32x4 acc[4] = {};
  const ushort_t* Ab = xbf + ((size_t)(b*L_ + RCT_ + bm) + r)*KP_ + g*8;
  #pragma unroll
  for (int kt = 0; kt < 3; ++kt) {
    bf16x8 bb = *(const bf16x8*)(pwT + ((size_t)(bn >> 4)*3 + kt)*512 + lane*8);
    #pragma unroll
    for (int mf = 0; mf < 4; ++mf) {
      bf16x8 a = *(const bf16x8*)(Ab + mf*16*KP_ + kt*32);
      acc[mf] = __builtin_amdgcn_mfma_f32_16x16x32_bf16(a, bb, acc[mf], 0, 0, 0);
    }
  }
  int col = bn + r;
  float bc = pb[col];
  #pragma unroll
  for (int mf = 0; mf < 4; ++mf)
    #pragma unroll
    for (int rr = 0; rr < 4; ++rr) {
      int row = bm + mf*16 + g*4 + rr;
      out[((size_t)b*TU_ + row)*OUTD_ + col] = acc[mf][rr] + bc;
    }
  if (blockIdx.x == 0 && blockIdx.y == 0 && blockIdx.z == 0 && threadIdx.x < B_)
    out[(size_t)B_*TU_*OUTD_ + threadIdx.x] = (float)len[threadIdx.x];
}

extern "C" void kernel_launch(void* const* d_in, const int* in_sizes, int n_in,
                              void* d_out, int out_size, void* d_ws, size_t ws_size,
                              hipStream_t stream) {
  const float* mel     = (const float*)d_in[0];
  const int*   lengths = (const int*)  d_in[1];
  const float* ln_in_w = (const float*)d_in[2];
  const float* ln_in_b = (const float*)d_in[3];
  const float* wq      = (const float*)d_in[4];
  const float* bq      = (const float*)d_in[5];
  const float* wkv     = (const float*)d_in[6];
  const float* bkv     = (const float*)d_in[7];
  const float* wo      = (const float*)d_in[8];
  const float* bo      = (const float*)d_in[9];
  const float* ln_ff_w = (const float*)d_in[10];
  const float* ln_ff_b = (const float*)d_in[11];
  const float* w1      = (const float*)d_in[12];
  const float* b1      = (const float*)d_in[13];
  const float* w2      = (const float*)d_in[14];
  const float* b2      = (const float*)d_in[15];
  const float* ln_o_w  = (const float*)d_in[16];
  const float* ln_o_b  = (const float*)d_in[17];
  const float* pw      = (const float*)d_in[18];
  const float* pb      = (const float*)d_in[19];
  float* out = (float*)d_out;

  float* ws = (float*)d_ws;
  float* x     = ws; ws += NR_*D_;
  float* qb    = ws; ws += NR_*D_;
  float* kvb   = ws; ws += NR_*2*D_;
  float* bqkv  = ws; ws += NLAYERS_*240;
  ushort_t* us = (ushort_t*)ws;
  ushort_t* xnbf  = us; us += NR_*KP_;
  ushort_t* attbf = us; us += NR_*KP_;
  ushort_t* wqkvT = us; us += S3_;
  ushort_t* woT   = us; us += S4_;
  ushort_t* pwT   = us; us += S5_;
  uchar_t* ub = (uchar_t*)us;
  uchar_t* w18 = ub; ub += S1_;
  uchar_t* w28 = ub; ub += S2_;

  k_wprep_small<<<(WSM_N_ + 255)/256, 256, 0, stream>>>(wq, wkv, wo, pw, bq, bkv,
                                                        wqkvT, woT, pwT, bqkv);
  k_w1t8<<<dim3(FFN_/64, NLAYERS_), 256, 0, stream>>>(w1, w18);
  k_w2t8<<<dim3(FFN_/64, NLAYERS_), 256, 0, stream>>>(w2, w28);
  k_build_qkv<<<NR_/16, 512, 0, stream>>>(mel, ln_in_w, ln_in_b, wqkvT, bqkv, x, qb, kvb);

  for (int l = 0; l < NLAYERS_; ++l) {
    int last = (l == NLAYERS_-1);
    k_attn<<<dim3(NSEG_, B_, H_), 256, 0, stream>>>(qb, kvb, attbf);
    k_ffn_fused<<<NR_/16, 1024, 0, stream>>>(attbf,
        woT + l*15*512, bo + l*D_,
        w18 + (size_t)l*FFN_*KP_, b1 + l*FFN_,
        w28 + (size_t)l*D_*FFN_, b2 + l*D_,
        ln_ff_w + l*D_, ln_ff_b + l*D_,
        ln_o_w + l*D_, ln_o_b + l*D_,
        ln_in_w + (last ? 0 : (l+1)*D_), ln_in_b + (last ? 0 : (l+1)*D_),
        last, x, xnbf,
        wqkvT + (last ? 0 : (l+1)*45*512), bqkv + (last ? 0 : (l+1)*240),
        qb, kvb);
  }

  k_proj_mfma<<<dim3(TU_/64, OUTD_/64, B_), 256, 0, stream>>>(xnbf, pwT, pb, lengths, out);
}

// Round 15
// 101.132 us; speedup vs baseline: 1.4715x; 1.1588x over previous
//
#include <hip/hip_runtime.h>
#include <math.h>

#define B_    2
#define TU_   1024
#define D_    80
#define H_    8
#define DH_   10
#define FFN_  2048
#define SEG_  32
#define RC_   8
#define LC_   50
#define NSEG_ 32
#define RCT_  256
#define L_    1280
#define NLAYERS_ 4
#define OUTD_ 768
#define EPS_  1e-5f
#define SCALE_ 0.31622776601683794f
#define NR_   (B_*L_)                 // 2560
#define KP_   96                      // K pad 80->96

typedef __attribute__((ext_vector_type(8))) short bf16x8;
typedef __attribute__((ext_vector_type(4))) float f32x4;
typedef unsigned short ushort_t;
typedef unsigned char uchar_t;
typedef long i64_t;

__device__ inline ushort_t f2bf(float f) {
  union { float f; unsigned u; } x; x.f = f;
  unsigned r = x.u + 0x7fffu + ((x.u >> 16) & 1u);   // RNE
  return (ushort_t)(r >> 16);
}
__device__ inline float bf2f(ushort_t u) {
  union { unsigned u; float f; } x; x.u = ((unsigned)u) << 16; return x.f;
}
__device__ inline uchar_t f2fp8(float f) {
  return (uchar_t)(__builtin_amdgcn_cvt_pk_fp8_f32(f, f, 0, false) & 0xff);
}
__device__ inline unsigned pk4fp8(float f0, float f1, float f2, float f3) {
  unsigned w = (unsigned)__builtin_amdgcn_cvt_pk_fp8_f32(f0, f1, 0, false);
  w = (unsigned)__builtin_amdgcn_cvt_pk_fp8_f32(f2, f3, (int)w, true);
  return w;
}

// ---- fragment-tiled sizes (tile = 512 elements = 64 lanes x 8) ----
#define S1_  (NLAYERS_*FFN_*KP_)       // w18 fp8 tiled [l][128 ntile][3 ktile][512]
#define S2_  (NLAYERS_*D_*FFN_)        // w28 fp8 tiled [l][5 ntile][64 ktile][512]
#define S3_  (NLAYERS_*45*512)         // wqkvT bf16 tiled [l][15][3][512]
#define S4_  (NLAYERS_*15*512)         // woT bf16 tiled [l][5][3][512]
#define S5_  (144*512)                 // pwT bf16 tiled [48][3][512]
#define S6_  (NLAYERS_*240)            // bqkv fp32
#define WSM_N_ (S3_+S4_+S5_+S6_)
#define WSM_BLK_ ((WSM_N_ + 255)/256)          // 772
#define W1_BLK_  (32*NLAYERS_)                 // 128
#define W2_BLK_  (32*NLAYERS_)                 // 128

// ============ unified weight prep: 3 sections in one dispatch ============
__global__ __launch_bounds__(256) void k_wprep_all(
    const float* __restrict__ wq, const float* __restrict__ wkv,
    const float* __restrict__ wo, const float* __restrict__ pw,
    const float* __restrict__ bq, const float* __restrict__ bkv,
    const float* __restrict__ w1, const float* __restrict__ w2,
    ushort_t* __restrict__ wqkvT, ushort_t* __restrict__ woT,
    ushort_t* __restrict__ pwT, float* __restrict__ bqkv,
    uchar_t* __restrict__ w18, uchar_t* __restrict__ w28) {
  int bx = blockIdx.x;
  int tid = threadIdx.x;
  __shared__ float t[5120];   // shared by both transpose sections

  if (bx < WSM_BLK_) {
    int idx = bx * 256 + tid;
    if (idx < S3_) {
      int l = idx / (45*512); int rem = idx % (45*512);
      int tile = rem / 512, off = rem % 512;
      int tt = tile / 3, kt = tile % 3;
      int lane = off >> 3, j = off & 7;
      int n = tt*16 + (lane & 15);
      int k = kt*32 + (lane >> 4)*8 + j;
      float v = 0.f;
      if (k < D_) {
        if (n < D_)       v = wq[(l*D_ + k)*D_ + n] * SCALE_;
        else if (n < 240) v = wkv[(l*D_ + k)*2*D_ + (n - D_)];
      }
      wqkvT[idx] = f2bf(v);
      return;
    }
    idx -= S3_;
    if (idx < S4_) {
      int l = idx / (15*512); int rem = idx % (15*512);
      int tile = rem / 512, off = rem % 512;
      int nf = tile / 3, kt = tile % 3;
      int lane = off >> 3, j = off & 7;
      int n = nf*16 + (lane & 15);
      int k = kt*32 + (lane >> 4)*8 + j;
      woT[idx] = (k < D_) ? f2bf(wo[(l*D_ + k)*D_ + n]) : 0;
      return;
    }
    idx -= S4_;
    if (idx < S5_) {
      int tile = idx / 512, off = idx % 512;
      int tt = tile / 3, kt = tile % 3;
      int lane = off >> 3, j = off & 7;
      int n = tt*16 + (lane & 15);
      int k = kt*32 + (lane >> 4)*8 + j;
      pwT[idx] = (k < D_) ? f2bf(pw[k*OUTD_ + n]) : 0;
      return;
    }
    idx -= S5_;
    if (idx < S6_) {
      int c = idx % 240, l = idx / 240;
      bqkv[idx] = (c < D_) ? bq[l*D_ + c] * SCALE_ : bkv[l*2*D_ + (c - D_)];
    }
    return;
  }
  bx -= WSM_BLK_;
  if (bx < W1_BLK_) {
    // w1 -> w18 fp8 fragment-tiled. Block covers 64 n, all k.
    int n0 = (bx & 31) * 64, l = bx >> 5;
    for (int idx = tid; idx < D_*64; idx += 256) {
      int k = idx >> 6, n = idx & 63;
      t[k*64 + n] = w1[((size_t)(l*D_ + k))*FFN_ + n0 + n];
    }
    __syncthreads();
    for (int idx = tid; idx < 4*3*64; idx += 256) {
      int nis = idx / 192, rem = idx % 192;
      int kt = rem / 64, lane = rem % 64;
      int r = lane & 15, g = lane >> 4;
      int nl = nis*16 + r;
      int kb = kt*32 + g*8;
      float v[8];
      #pragma unroll
      for (int j = 0; j < 8; ++j) {
        int k = kb + j;
        v[j] = (k < D_) ? t[k*64 + nl]*16.f : 0.f;
      }
      uint2 o;
      o.x = pk4fp8(v[0], v[1], v[2], v[3]);
      o.y = pk4fp8(v[4], v[5], v[6], v[7]);
      size_t ni = (size_t)(n0 >> 4) + nis;
      *(uint2*)(w18 + (((size_t)l*128 + ni)*3 + kt)*512 + lane*8) = o;
    }
    return;
  }
  bx -= W1_BLK_;
  {
    // w2 -> w28 fp8 fragment-tiled. Block covers 64 k, all n.
    int k0 = (bx & 31) * 64, l = bx >> 5;
    for (int idx = tid; idx < 64*D_; idx += 256) {
      int k = idx / D_, n = idx % D_;
      t[k*D_ + n] = w2[((size_t)(l*FFN_ + k0 + k))*D_ + n];
    }
    __syncthreads();
    for (int idx = tid; idx < 5*2*64; idx += 256) {
      int nf = idx / 128, rem = idx % 128;
      int ktl = rem / 64, lane = rem % 64;
      int r = lane & 15, g = lane >> 4;
      int n = nf*16 + r;
      int kb = ktl*32 + g*8;
      uint2 o;
      o.x = pk4fp8(t[(kb+0)*D_+n]*16.f, t[(kb+1)*D_+n]*16.f, t[(kb+2)*D_+n]*16.f, t[(kb+3)*D_+n]*16.f);
      o.y = pk4fp8(t[(kb+4)*D_+n]*16.f, t[(kb+5)*D_+n]*16.f, t[(kb+6)*D_+n]*16.f, t[(kb+7)*D_+n]*16.f);
      size_t kt = (size_t)(k0 >> 5) + ktl;
      *(uint2*)(w28 + (((size_t)l*5 + nf)*64 + kt)*512 + lane*8) = o;
    }
  }
}

// ============ merged: gather mel -> x + layer-0 LN_in + QKV MFMA -> q/kv (bf16) ============
__global__ __launch_bounds__(512) void k_build_qkv(const float* __restrict__ mel,
    const float* __restrict__ lw, const float* __restrict__ lb,
    const ushort_t* __restrict__ wqkvT, const float* __restrict__ bqkv,
    float* __restrict__ x, ushort_t* __restrict__ q, ushort_t* __restrict__ kv) {
  int tid = threadIdx.x;
  int wv = tid >> 6, lane = tid & 63;
  int r = lane & 15, g = lane >> 4;
  int bm = blockIdx.x * 16;
  __shared__ ushort_t hnsh[16][KP_];

  if (tid < 256) {
    int row = tid >> 4, j = tid & 15;
    int grow = bm + row;
    int b = grow / L_, i = grow % L_;
    int srow = (i < RCT_) ? ((i >> 3) + 1)*SEG_ + (i & 7) : i - RCT_;
    float v[5], s = 0.f, ss = 0.f;
    #pragma unroll
    for (int c = 0; c < 5; ++c) {
      int col = j + c*16;
      v[c] = mel[((size_t)b*(TU_+RC_) + srow)*D_ + col];
      x[(size_t)grow*D_ + col] = v[c];
      s += v[c]; ss += v[c]*v[c];
    }
    s  += __shfl_xor(s, 1, 16);  ss += __shfl_xor(ss, 1, 16);
    s  += __shfl_xor(s, 2, 16);  ss += __shfl_xor(ss, 2, 16);
    s  += __shfl_xor(s, 4, 16);  ss += __shfl_xor(ss, 4, 16);
    s  += __shfl_xor(s, 8, 16);  ss += __shfl_xor(ss, 8, 16);
    float mean = s * (1.f/D_);
    float var  = ss * (1.f/D_) - mean*mean;
    float inv  = rsqrtf(var + EPS_);
    #pragma unroll
    for (int c = 0; c < 5; ++c) {
      int col = j + c*16;
      hnsh[row][col] = f2bf((v[c] - mean) * inv * lw[col] + lb[col]);
    }
    hnsh[row][D_ + j] = 0;
  }
  __syncthreads();

  for (int t = wv; t < 15; t += 8) {
    f32x4 acc = {};
    #pragma unroll
    for (int kt = 0; kt < 3; ++kt) {
      bf16x8 a  = *(const bf16x8*)(&hnsh[r][kt*32 + g*8]);
      bf16x8 bb = *(const bf16x8*)(wqkvT + ((size_t)t*3 + kt)*512 + lane*8);
      acc = __builtin_amdgcn_mfma_f32_16x16x32_bf16(a, bb, acc, 0, 0, 0);
    }
    int col = t*16 + r;
    float bc = bqkv[col];
    #pragma unroll
    for (int rr = 0; rr < 4; ++rr) {
      int row = bm + g*4 + rr;
      float v = acc[rr] + bc;
      if (col < D_) q[(size_t)row*D_ + col] = f2bf(v);
      else          kv[(size_t)row*2*D_ + (col - D_)] = f2bf(v);
    }
  }
}

// ============ block-sparse attention (bf16 q/kv in) -> attbf bf16 [2560][96] ============
__global__ __launch_bounds__(256) void k_attn(const ushort_t* __restrict__ q,
    const ushort_t* __restrict__ kv, ushort_t* __restrict__ att) {
  int seg = blockIdx.x, b = blockIdx.y, h = blockIdx.z;
  int tid = threadIdx.x;
  int seg_start = seg*SEG_ - LC_; if (seg_start < 0) seg_start = 0;
  int kc = RC_ + (seg+1)*SEG_ - seg_start;       // <= 90
  __shared__ float Ksh[90][DH_];
  __shared__ float Vsh[90][DH_];
  __shared__ float Qsh[40][DH_];
  __shared__ float Ssh[40][90];
  __shared__ float inv_sh[40];
  for (int idx = tid; idx < kc*5; idx += 256) {
    int kk = idx / 5, dd = (idx % 5) * 2;
    int krow = (kk < RC_) ? seg*RC_ + kk : RCT_ + seg_start + (kk - RC_);
    const ushort_t* base = kv + ((size_t)b*L_ + krow)*2*D_ + h*DH_ + dd;
    ushort2 kf = *(const ushort2*)base;
    ushort2 vf = *(const ushort2*)(base + D_);
    Ksh[kk][dd] = bf2f(kf.x); Ksh[kk][dd+1] = bf2f(kf.y);
    Vsh[kk][dd] = bf2f(vf.x); Vsh[kk][dd+1] = bf2f(vf.y);
  }
  if (tid < 200) {
    int qi = tid / 5, dd = (tid % 5) * 2;
    int qrow = (qi < RC_) ? seg*RC_ + qi : RCT_ + seg*SEG_ + (qi - RC_);
    ushort2 qf = *(const ushort2*)(q + ((size_t)b*L_ + qrow)*D_ + h*DH_ + dd);
    Qsh[qi][dd] = bf2f(qf.x); Qsh[qi][dd+1] = bf2f(qf.y);
  }
  __syncthreads();
  // scores: 40 rows x 6 lanes, Q row in registers
  if (tid < 240) {
    int qi = tid / 6, j = tid % 6;
    float qv[DH_];
    #pragma unroll
    for (int d = 0; d < DH_; ++d) qv[d] = Qsh[qi][d];
    for (int kk = j; kk < kc; kk += 6) {
      float s = 0.f;
      #pragma unroll
      for (int d = 0; d < DH_; ++d) s += qv[d] * Ksh[kk][d];
      Ssh[qi][kk] = s;
    }
  }
  __syncthreads();
  if (tid < 160) {
    int row = tid >> 2, j = tid & 3;
    float pm = -INFINITY;
    for (int kk = j; kk < kc; kk += 4) pm = fmaxf(pm, Ssh[row][kk]);
    pm = fmaxf(pm, __shfl_xor(pm, 1, 4));
    pm = fmaxf(pm, __shfl_xor(pm, 2, 4));
    float ps = 0.f;
    for (int kk = j; kk < kc; kk += 4) {
      float e = __expf(Ssh[row][kk] - pm);
      Ssh[row][kk] = e;
      ps += e;
    }
    ps += __shfl_xor(ps, 1, 4);
    ps += __shfl_xor(ps, 2, 4);
    if (j == 0) inv_sh[row] = 1.f / ps;
  }
  __syncthreads();
  for (int o = tid; o < 40*DH_; o += 256) {
    int qi = o / DH_, d = o - qi*DH_;
    float acc = 0.f;
    for (int kk = 0; kk < kc; ++kk) acc += Ssh[qi][kk] * Vsh[kk][d];
    int qrow = (qi < RC_) ? seg*RC_ + qi : RCT_ + seg*SEG_ + (qi - RC_);
    att[((size_t)b*L_ + qrow)*KP_ + h*DH_ + d] = f2bf(acc * inv_sh[qi]);
  }
  if (h == 0) {
    for (int idx = tid; idx < 40*16; idx += 256) {
      int qi = idx >> 4, c = D_ + (idx & 15);
      int qrow = (qi < RC_) ? seg*RC_ + qi : RCT_ + seg*SEG_ + (qi - RC_);
      att[((size_t)b*L_ + qrow)*KP_ + c] = 0;
    }
  }
}

// ============ fused per-layer tail (16 waves), fragment-tiled weights ============
__global__ __launch_bounds__(1024) void k_ffn_fused(const ushort_t* __restrict__ attbf,
    const ushort_t* __restrict__ woT, const float* __restrict__ bo,
    const uchar_t* __restrict__ w18, const float* __restrict__ b1,
    const uchar_t* __restrict__ w28, const float* __restrict__ b2,
    const float* __restrict__ lfw, const float* __restrict__ lfb,
    const float* __restrict__ low, const float* __restrict__ lob,
    const float* __restrict__ liw, const float* __restrict__ lib, int mode,
    float* __restrict__ x, ushort_t* __restrict__ xnbf,
    const ushort_t* __restrict__ wqkvT_n, const float* __restrict__ bqkv_n,
    ushort_t* __restrict__ q, ushort_t* __restrict__ kv) {
  int tid = threadIdx.x;
  int wv = tid >> 6, lane = tid & 63;
  int r = lane & 15, g = lane >> 4;
  int bm = blockIdx.x * 16;
  __shared__ ushort_t attsh[16][KP_];
  __shared__ ushort_t hnsh[16][KP_];
  __shared__ uchar_t  hn8[16][104];
  __shared__ uchar_t  ff18[16][16][136];
  __shared__ ushort_t redb[16][16][D_];
  __shared__ float    vsh[16][D_];

  if (tid < 192) {
    int row = tid / 12, c = (tid % 12) * 8;
    *(bf16x8*)&attsh[row][c] = *(const bf16x8*)(attbf + (size_t)(bm+row)*KP_ + c);
  }
  __syncthreads();

  if (wv < 5) {
    f32x4 acc = {};
    #pragma unroll
    for (int kt = 0; kt < 3; ++kt) {
      bf16x8 a  = *(const bf16x8*)(&attsh[r][kt*32 + g*8]);
      bf16x8 bb = *(const bf16x8*)(woT + ((size_t)wv*3 + kt)*512 + lane*8);
      acc = __builtin_amdgcn_mfma_f32_16x16x32_bf16(a, bb, acc, 0, 0, 0);
    }
    #pragma unroll
    for (int rr = 0; rr < 4; ++rr)
      vsh[g*4 + rr][wv*16 + r] = acc[rr];
  }
  __syncthreads();

  if (tid < 256) {
    int row = tid >> 4, j = tid & 15;
    int grow = bm + row;
    float v[5], s = 0.f, ss = 0.f;
    #pragma unroll
    for (int c = 0; c < 5; ++c) {
      int col = j + c*16;
      v[c] = vsh[row][col] + bo[col] + x[(size_t)grow*D_ + col];
      vsh[row][col] = v[c];
      s += v[c]; ss += v[c]*v[c];
    }
    s  += __shfl_xor(s, 1, 16);  ss += __shfl_xor(ss, 1, 16);
    s  += __shfl_xor(s, 2, 16);  ss += __shfl_xor(ss, 2, 16);
    s  += __shfl_xor(s, 4, 16);  ss += __shfl_xor(ss, 4, 16);
    s  += __shfl_xor(s, 8, 16);  ss += __shfl_xor(ss, 8, 16);
    float mean = s * (1.f/D_);
    float var  = ss * (1.f/D_) - mean*mean;
    float inv  = rsqrtf(var + EPS_);
    #pragma unroll
    for (int c = 0; c < 5; ++c) {
      int col = j + c*16;
      hn8[row][col] = f2fp8((v[c] - mean) * inv * lfw[col] + lfb[col]);
    }
    hn8[row][D_ + j] = 0;
  }
  __syncthreads();

  // FFN1 fp8: fragment-tiled w18
  f32x4 acc1[8];
  #pragma unroll
  for (int ni = 0; ni < 8; ++ni) acc1[ni] = (f32x4){0.f,0.f,0.f,0.f};
  #pragma unroll
  for (int kt = 0; kt < 3; ++kt) {
    i64_t a = *(const i64_t*)(&hn8[r][kt*32 + g*8]);
    #pragma unroll
    for (int ni = 0; ni < 8; ++ni) {
      i64_t bb = *(const i64_t*)(w18 + (((size_t)(wv*8 + ni))*3 + kt)*512 + lane*8);
      acc1[ni] = __builtin_amdgcn_mfma_f32_16x16x32_fp8_fp8(a, bb, acc1[ni], 0, 0, 0);
    }
  }
  int nbase = wv*128;
  #pragma unroll
  for (int ni = 0; ni < 8; ++ni) {
    int col = nbase + ni*16 + r;
    float bc = b1[col];
    #pragma unroll
    for (int rr = 0; rr < 4; ++rr) {
      float v = acc1[ni][rr] * 0.0625f + bc;
      ff18[wv][g*4 + rr][ni*16 + r] = f2fp8(fmaxf(v, 0.f) * 8.f);
    }
  }

  // FFN2 fp8: fragment-tiled w28; wave wv owns k-tiles wv*4..wv*4+3
  f32x4 acc2[5] = {};
  #pragma unroll
  for (int ks = 0; ks < 4; ++ks) {
    i64_t a = *(const i64_t*)(&ff18[wv][r][ks*32 + g*8]);
    #pragma unroll
    for (int nf = 0; nf < 5; ++nf) {
      i64_t bb = *(const i64_t*)(w28 + (((size_t)nf*64) + wv*4 + ks)*512 + lane*8);
      acc2[nf] = __builtin_amdgcn_mfma_f32_16x16x32_fp8_fp8(a, bb, acc2[nf], 0, 0, 0);
    }
  }
  #pragma unroll
  for (int nf = 0; nf < 5; ++nf)
    #pragma unroll
    for (int rr = 0; rr < 4; ++rr)
      redb[wv][g*4 + rr][nf*16 + r] = f2bf(acc2[nf][rr]);
  __syncthreads();

  for (int e = tid; e < 16*D_; e += 1024) {
    int row = e / D_, col = e % D_;
    float s0 = 0.f, s1 = 0.f, s2 = 0.f, s3 = 0.f;
    #pragma unroll
    for (int w = 0; w < 16; w += 4) {
      s0 += bf2f(redb[w+0][row][col]);
      s1 += bf2f(redb[w+1][row][col]);
      s2 += bf2f(redb[w+2][row][col]);
      s3 += bf2f(redb[w+3][row][col]);
    }
    vsh[row][col] = ((s0+s1)+(s2+s3)) * (1.f/128.f) + b2[col] + vsh[row][col];
  }
  __syncthreads();
  if (tid < 256) {
    int row = tid >> 4, j = tid & 15;
    float v[5], s = 0.f, ss = 0.f;
    #pragma unroll
    for (int c = 0; c < 5; ++c) {
      v[c] = vsh[row][j + c*16];
      s += v[c]; ss += v[c]*v[c];
    }
    s  += __shfl_xor(s, 1, 16);  ss += __shfl_xor(ss, 1, 16);
    s  += __shfl_xor(s, 2, 16);  ss += __shfl_xor(ss, 2, 16);
    s  += __shfl_xor(s, 4, 16);  ss += __shfl_xor(ss, 4, 16);
    s  += __shfl_xor(s, 8, 16);  ss += __shfl_xor(ss, 8, 16);
    float mean = s * (1.f/D_);
    float var  = ss * (1.f/D_) - mean*mean;
    float inv  = rsqrtf(var + EPS_);
    int grow = bm + row;
    float xs[5];
    float s2 = 0.f, ss2 = 0.f;
    #pragma unroll
    for (int c = 0; c < 5; ++c) {
      int col = j + c*16;
      xs[c] = (v[c] - mean) * inv * low[col] + lob[col];
      x[(size_t)grow*D_ + col] = xs[c];
      s2 += xs[c]; ss2 += xs[c]*xs[c];
    }
    if (mode == 0) {
      s2  += __shfl_xor(s2, 1, 16);  ss2 += __shfl_xor(ss2, 1, 16);
      s2  += __shfl_xor(s2, 2, 16);  ss2 += __shfl_xor(ss2, 2, 16);
      s2  += __shfl_xor(s2, 4, 16);  ss2 += __shfl_xor(ss2, 4, 16);
      s2  += __shfl_xor(s2, 8, 16);  ss2 += __shfl_xor(ss2, 8, 16);
      float m2 = s2 * (1.f/D_);
      float v2 = ss2 * (1.f/D_) - m2*m2;
      float i2 = rsqrtf(v2 + EPS_);
      #pragma unroll
      for (int c = 0; c < 5; ++c) {
        int col = j + c*16;
        hnsh[row][col] = f2bf((xs[c] - m2) * i2 * liw[col] + lib[col]);
      }
      hnsh[row][D_ + j] = 0;
    } else {
      #pragma unroll
      for (int c = 0; c < 5; ++c)
        xnbf[(size_t)grow*KP_ + j + c*16] = f2bf(xs[c]);
      xnbf[(size_t)grow*KP_ + D_ + j] = 0;
    }
  }

  // fused next-layer QKV -> bf16 q/kv
  if (mode == 0) {
    __syncthreads();
    if (wv < 15) {
      int t = wv;
      f32x4 acc = {};
      #pragma unroll
      for (int kt = 0; kt < 3; ++kt) {
        bf16x8 a  = *(const bf16x8*)(&hnsh[r][kt*32 + g*8]);
        bf16x8 bb = *(const bf16x8*)(wqkvT_n + ((size_t)t*3 + kt)*512 + lane*8);
        acc = __builtin_amdgcn_mfma_f32_16x16x32_bf16(a, bb, acc, 0, 0, 0);
      }
      int col = t*16 + r;
      float bc = bqkv_n[col];
      #pragma unroll
      for (int rr = 0; rr < 4; ++rr) {
        int row = bm + g*4 + rr;
        float v = acc[rr] + bc;
        if (col < D_) q[(size_t)row*D_ + col] = f2bf(v);
        else          kv[(size_t)row*2*D_ + (col - D_)] = f2bf(v);
      }
    }
  }
}

// ============ final proj MFMA, 64x64 tiles, fragment-tiled pwT ============
__global__ __launch_bounds__(256) void k_proj_mfma(const ushort_t* __restrict__ xbf,
    const ushort_t* __restrict__ pwT, const float* __restrict__ pb,
    const int* __restrict__ len, float* __restrict__ out) {
  int wv = threadIdx.x >> 6, lane = threadIdx.x & 63;
  int bm = blockIdx.x * 64;
  int bn = blockIdx.y * 64 + wv*16;
  int b  = blockIdx.z;
  int r = lane & 15, g = lane >> 4;
  f32x4 acc[4] = {};
  const ushort_t* Ab = xbf + ((size_t)(b*L_ + RCT_ + bm) + r)*KP_ + g*8;
  #pragma unroll
  for (int kt = 0; kt < 3; ++kt) {
    bf16x8 bb = *(const bf16x8*)(pwT + ((size_t)(bn >> 4)*3 + kt)*512 + lane*8);
    #pragma unroll
    for (int mf = 0; mf < 4; ++mf) {
      bf16x8 a = *(const bf16x8*)(Ab + mf*16*KP_ + kt*32);
      acc[mf] = __builtin_amdgcn_mfma_f32_16x16x32_bf16(a, bb, acc[mf], 0, 0, 0);
    }
  }
  int col = bn + r;
  float bc = pb[col];
  #pragma unroll
  for (int mf = 0; mf < 4; ++mf)
    #pragma unroll
    for (int rr = 0; rr < 4; ++rr) {
      int row = bm + mf*16 + g*4 + rr;
      out[((size_t)b*TU_ + row)*OUTD_ + col] = acc[mf][rr] + bc;
    }
  if (blockIdx.x == 0 && blockIdx.y == 0 && blockIdx.z == 0 && threadIdx.x < B_)
    out[(size_t)B_*TU_*OUTD_ + threadIdx.x] = (float)len[threadIdx.x];
}

extern "C" void kernel_launch(void* const* d_in, const int* in_sizes, int n_in,
                              void* d_out, int out_size, void* d_ws, size_t ws_size,
                              hipStream_t stream) {
  const float* mel     = (const float*)d_in[0];
  const int*   lengths = (const int*)  d_in[1];
  const float* ln_in_w = (const float*)d_in[2];
  const float* ln_in_b = (const float*)d_in[3];
  const float* wq      = (const float*)d_in[4];
  const float* bq      = (const float*)d_in[5];
  const float* wkv     = (const float*)d_in[6];
  const float* bkv     = (const float*)d_in[7];
  const float* wo      = (const float*)d_in[8];
  const float* bo      = (const float*)d_in[9];
  const float* ln_ff_w = (const float*)d_in[10];
  const float* ln_ff_b = (const float*)d_in[11];
  const float* w1      = (const float*)d_in[12];
  const float* b1      = (const float*)d_in[13];
  const float* w2      = (const float*)d_in[14];
  const float* b2      = (const float*)d_in[15];
  const float* ln_o_w  = (const float*)d_in[16];
  const float* ln_o_b  = (const float*)d_in[17];
  const float* pw      = (const float*)d_in[18];
  const float* pb      = (const float*)d_in[19];
  float* out = (float*)d_out;

  float* ws = (float*)d_ws;
  float* x     = ws; ws += NR_*D_;
  float* bqkv  = ws; ws += NLAYERS_*240;
  ushort_t* us = (ushort_t*)ws;
  ushort_t* qb    = us; us += NR_*D_;
  ushort_t* kvb   = us; us += NR_*2*D_;
  ushort_t* xnbf  = us; us += NR_*KP_;
  ushort_t* attbf = us; us += NR_*KP_;
  ushort_t* wqkvT = us; us += S3_;
  ushort_t* woT   = us; us += S4_;
  ushort_t* pwT   = us; us += S5_;
  uchar_t* ub = (uchar_t*)us;
  uchar_t* w18 = ub; ub += S1_;
  uchar_t* w28 = ub; ub += S2_;

  k_wprep_all<<<WSM_BLK_ + W1_BLK_ + W2_BLK_, 256, 0, stream>>>(
      wq, wkv, wo, pw, bq, bkv, w1, w2, wqkvT, woT, pwT, bqkv, w18, w28);
  k_build_qkv<<<NR_/16, 512, 0, stream>>>(mel, ln_in_w, ln_in_b, wqkvT, bqkv, x, qb, kvb);

  for (int l = 0; l < NLAYERS_; ++l) {
    int last = (l == NLAYERS_-1);
    k_attn<<<dim3(NSEG_, B_, H_), 256, 0, stream>>>(qb, kvb, attbf);
    k_ffn_fused<<<NR_/16, 1024, 0, stream>>>(attbf,
        woT + l*15*512, bo + l*D_,
        w18 + (size_t)l*FFN_*KP_, b1 + l*FFN_,
        w28 + (size_t)l*D_*FFN_, b2 + l*D_,
        ln_ff_w + l*D_, ln_ff_b + l*D_,
        ln_o_w + l*D_, ln_o_b + l*D_,
        ln_in_w + (last ? 0 : (l+1)*D_), ln_in_b + (last ? 0 : (l+1)*D_),
        last, x, xnbf,
        wqkvT + (last ? 0 : (l+1)*45*512), bqkv + (last ? 0 : (l+1)*240),
        qb, kvb);
  }

  k_proj_mfma<<<dim3(TU_/64, OUTD_/64, B_), 256, 0, stream>>>(xnbf, pwT, pb, lengths, out);
}

// Round 16
// 97.751 us; speedup vs baseline: 1.5224x; 1.0346x over previous
//
#include <hip/hip_runtime.h>
#include <math.h>

#define B_    2
#define TU_   1024
#define D_    80
#define H_    8
#define DH_   10
#define FFN_  2048
#define SEG_  32
#define RC_   8
#define LC_   50
#define NSEG_ 32
#define RCT_  256
#define L_    1280
#define NLAYERS_ 4
#define OUTD_ 768
#define EPS_  1e-5f
#define SCALE_ 0.31622776601683794f
#define NR_   (B_*L_)                 // 2560
#define KP_   96                      // K pad 80->96

typedef __attribute__((ext_vector_type(8))) short bf16x8;
typedef __attribute__((ext_vector_type(4))) float f32x4;
typedef unsigned short ushort_t;
typedef unsigned char uchar_t;
typedef long i64_t;

__device__ inline ushort_t f2bf(float f) {
  union { float f; unsigned u; } x; x.f = f;
  unsigned r = x.u + 0x7fffu + ((x.u >> 16) & 1u);   // RNE
  return (ushort_t)(r >> 16);
}
__device__ inline float bf2f(ushort_t u) {
  union { unsigned u; float f; } x; x.u = ((unsigned)u) << 16; return x.f;
}
__device__ inline uchar_t f2fp8(float f) {
  return (uchar_t)(__builtin_amdgcn_cvt_pk_fp8_f32(f, f, 0, false) & 0xff);
}
__device__ inline unsigned pk4fp8(float f0, float f1, float f2, float f3) {
  unsigned w = (unsigned)__builtin_amdgcn_cvt_pk_fp8_f32(f0, f1, 0, false);
  w = (unsigned)__builtin_amdgcn_cvt_pk_fp8_f32(f2, f3, (int)w, true);
  return w;
}

// ---- fragment-tiled sizes (tile = 512 elements = 64 lanes x 8) ----
#define S1_  (NLAYERS_*FFN_*KP_)       // w18 fp8 tiled [l][128 ntile][3 ktile][512]
#define S2_  (NLAYERS_*D_*FFN_)        // w28 fp8 tiled [l][5 ntile][64 ktile][512]
#define S3_  (NLAYERS_*45*512)         // wqkvT bf16 tiled [l][15][3][512]
#define S4_  (NLAYERS_*15*512)         // woT bf16 tiled [l][5][3][512]
#define S5_  (144*512)                 // pwT bf16 tiled [48][3][512]
#define S6_  (NLAYERS_*240)            // bqkv fp32
#define WSM_N_ (S3_+S4_+S5_+S6_)
#define WSM_BLK_ ((WSM_N_ + 255)/256)          // 772
#define W1_BLK_  (32*NLAYERS_)                 // 128
#define W2_BLK_  (32*NLAYERS_)                 // 128

// ============ unified weight prep: 3 sections in one dispatch ============
__global__ __launch_bounds__(256) void k_wprep_all(
    const float* __restrict__ wq, const float* __restrict__ wkv,
    const float* __restrict__ wo, const float* __restrict__ pw,
    const float* __restrict__ bq, const float* __restrict__ bkv,
    const float* __restrict__ w1, const float* __restrict__ w2,
    ushort_t* __restrict__ wqkvT, ushort_t* __restrict__ woT,
    ushort_t* __restrict__ pwT, float* __restrict__ bqkv,
    uchar_t* __restrict__ w18, uchar_t* __restrict__ w28) {
  int bx = blockIdx.x;
  int tid = threadIdx.x;
  __shared__ float t[5120];

  if (bx < WSM_BLK_) {
    int idx = bx * 256 + tid;
    if (idx < S3_) {
      int l = idx / (45*512); int rem = idx % (45*512);
      int tile = rem / 512, off = rem % 512;
      int tt = tile / 3, kt = tile % 3;
      int lane = off >> 3, j = off & 7;
      int n = tt*16 + (lane & 15);
      int k = kt*32 + (lane >> 4)*8 + j;
      float v = 0.f;
      if (k < D_) {
        if (n < D_)       v = wq[(l*D_ + k)*D_ + n] * SCALE_;
        else if (n < 240) v = wkv[(l*D_ + k)*2*D_ + (n - D_)];
      }
      wqkvT[idx] = f2bf(v);
      return;
    }
    idx -= S3_;
    if (idx < S4_) {
      int l = idx / (15*512); int rem = idx % (15*512);
      int tile = rem / 512, off = rem % 512;
      int nf = tile / 3, kt = tile % 3;
      int lane = off >> 3, j = off & 7;
      int n = nf*16 + (lane & 15);
      int k = kt*32 + (lane >> 4)*8 + j;
      woT[idx] = (k < D_) ? f2bf(wo[(l*D_ + k)*D_ + n]) : 0;
      return;
    }
    idx -= S4_;
    if (idx < S5_) {
      int tile = idx / 512, off = idx % 512;
      int tt = tile / 3, kt = tile % 3;
      int lane = off >> 3, j = off & 7;
      int n = tt*16 + (lane & 15);
      int k = kt*32 + (lane >> 4)*8 + j;
      pwT[idx] = (k < D_) ? f2bf(pw[k*OUTD_ + n]) : 0;
      return;
    }
    idx -= S5_;
    if (idx < S6_) {
      int c = idx % 240, l = idx / 240;
      bqkv[idx] = (c < D_) ? bq[l*D_ + c] * SCALE_ : bkv[l*2*D_ + (c - D_)];
    }
    return;
  }
  bx -= WSM_BLK_;
  if (bx < W1_BLK_) {
    int n0 = (bx & 31) * 64, l = bx >> 5;
    for (int idx = tid; idx < D_*64; idx += 256) {
      int k = idx >> 6, n = idx & 63;
      t[k*64 + n] = w1[((size_t)(l*D_ + k))*FFN_ + n0 + n];
    }
    __syncthreads();
    for (int idx = tid; idx < 4*3*64; idx += 256) {
      int nis = idx / 192, rem = idx % 192;
      int kt = rem / 64, lane = rem % 64;
      int r = lane & 15, g = lane >> 4;
      int nl = nis*16 + r;
      int kb = kt*32 + g*8;
      float v[8];
      #pragma unroll
      for (int j = 0; j < 8; ++j) {
        int k = kb + j;
        v[j] = (k < D_) ? t[k*64 + nl]*16.f : 0.f;
      }
      uint2 o;
      o.x = pk4fp8(v[0], v[1], v[2], v[3]);
      o.y = pk4fp8(v[4], v[5], v[6], v[7]);
      size_t ni = (size_t)(n0 >> 4) + nis;
      *(uint2*)(w18 + (((size_t)l*128 + ni)*3 + kt)*512 + lane*8) = o;
    }
    return;
  }
  bx -= W1_BLK_;
  {
    int k0 = (bx & 31) * 64, l = bx >> 5;
    for (int idx = tid; idx < 64*D_; idx += 256) {
      int k = idx / D_, n = idx % D_;
      t[k*D_ + n] = w2[((size_t)(l*FFN_ + k0 + k))*D_ + n];
    }
    __syncthreads();
    for (int idx = tid; idx < 5*2*64; idx += 256) {
      int nf = idx / 128, rem = idx % 128;
      int ktl = rem / 64, lane = rem % 64;
      int r = lane & 15, g = lane >> 4;
      int n = nf*16 + r;
      int kb = ktl*32 + g*8;
      uint2 o;
      o.x = pk4fp8(t[(kb+0)*D_+n]*16.f, t[(kb+1)*D_+n]*16.f, t[(kb+2)*D_+n]*16.f, t[(kb+3)*D_+n]*16.f);
      o.y = pk4fp8(t[(kb+4)*D_+n]*16.f, t[(kb+5)*D_+n]*16.f, t[(kb+6)*D_+n]*16.f, t[(kb+7)*D_+n]*16.f);
      size_t kt = (size_t)(k0 >> 5) + ktl;
      *(uint2*)(w28 + (((size_t)l*5 + nf)*64 + kt)*512 + lane*8) = o;
    }
  }
}

// ============ merged: gather mel -> x + layer-0 LN_in + QKV MFMA -> q/kv (bf16) ============
// LN phase uses contiguous-5 cols (20B/lane); also zeroes attbf pad cols once.
__global__ __launch_bounds__(512) void k_build_qkv(const float* __restrict__ mel,
    const float* __restrict__ lw, const float* __restrict__ lb,
    const ushort_t* __restrict__ wqkvT, const float* __restrict__ bqkv,
    float* __restrict__ x, ushort_t* __restrict__ q, ushort_t* __restrict__ kv,
    ushort_t* __restrict__ attbf) {
  int tid = threadIdx.x;
  int wv = tid >> 6, lane = tid & 63;
  int r = lane & 15, g = lane >> 4;
  int bm = blockIdx.x * 16;
  __shared__ ushort_t hnsh[16][KP_];

  if (tid < 256) {
    int row = tid >> 4, j = tid & 15;
    int grow = bm + row;
    int b = grow / L_, i = grow % L_;
    int srow = (i < RCT_) ? ((i >> 3) + 1)*SEG_ + (i & 7) : i - RCT_;
    float v[5], s = 0.f, ss = 0.f;
    #pragma unroll
    for (int c = 0; c < 5; ++c) {
      int col = j*5 + c;
      v[c] = mel[((size_t)b*(TU_+RC_) + srow)*D_ + col];
      x[(size_t)grow*D_ + col] = v[c];
      s += v[c]; ss += v[c]*v[c];
    }
    s  += __shfl_xor(s, 1, 16);  ss += __shfl_xor(ss, 1, 16);
    s  += __shfl_xor(s, 2, 16);  ss += __shfl_xor(ss, 2, 16);
    s  += __shfl_xor(s, 4, 16);  ss += __shfl_xor(ss, 4, 16);
    s  += __shfl_xor(s, 8, 16);  ss += __shfl_xor(ss, 8, 16);
    float mean = s * (1.f/D_);
    float var  = ss * (1.f/D_) - mean*mean;
    float inv  = rsqrtf(var + EPS_);
    #pragma unroll
    for (int c = 0; c < 5; ++c) {
      int col = j*5 + c;
      hnsh[row][col] = f2bf((v[c] - mean) * inv * lw[col] + lb[col]);
    }
    hnsh[row][D_ + j] = 0;
    attbf[(size_t)grow*KP_ + D_ + j] = 0;    // zero pad cols once for all layers
  }
  __syncthreads();

  for (int t = wv; t < 15; t += 8) {
    f32x4 acc = {};
    #pragma unroll
    for (int kt = 0; kt < 3; ++kt) {
      bf16x8 a  = *(const bf16x8*)(&hnsh[r][kt*32 + g*8]);
      bf16x8 bb = *(const bf16x8*)(wqkvT + ((size_t)t*3 + kt)*512 + lane*8);
      acc = __builtin_amdgcn_mfma_f32_16x16x32_bf16(a, bb, acc, 0, 0, 0);
    }
    int col = t*16 + r;
    float bc = bqkv[col];
    #pragma unroll
    for (int rr = 0; rr < 4; ++rr) {
      int row = bm + g*4 + rr;
      float v = acc[rr] + bc;
      if (col < D_) q[(size_t)row*D_ + col] = f2bf(v);
      else          kv[(size_t)row*2*D_ + (col - D_)] = f2bf(v);
    }
  }
}

// ============ block-sparse attention (bf16 q/kv in) -> attbf bf16 [2560][96] ============
__global__ __launch_bounds__(256) void k_attn(const ushort_t* __restrict__ q,
    const ushort_t* __restrict__ kv, ushort_t* __restrict__ att) {
  int seg = blockIdx.x, b = blockIdx.y, h = blockIdx.z;
  int tid = threadIdx.x;
  int seg_start = seg*SEG_ - LC_; if (seg_start < 0) seg_start = 0;
  int kc = RC_ + (seg+1)*SEG_ - seg_start;       // <= 90
  __shared__ float Ksh[90][DH_];
  __shared__ float Vsh[90][DH_];
  __shared__ float Qsh[40][DH_];
  __shared__ float Ssh[40][90];
  __shared__ float inv_sh[40];
  for (int idx = tid; idx < kc*5; idx += 256) {
    int kk = idx / 5, dd = (idx % 5) * 2;
    int krow = (kk < RC_) ? seg*RC_ + kk : RCT_ + seg_start + (kk - RC_);
    const ushort_t* base = kv + ((size_t)b*L_ + krow)*2*D_ + h*DH_ + dd;
    ushort2 kf = *(const ushort2*)base;
    ushort2 vf = *(const ushort2*)(base + D_);
    Ksh[kk][dd] = bf2f(kf.x); Ksh[kk][dd+1] = bf2f(kf.y);
    Vsh[kk][dd] = bf2f(vf.x); Vsh[kk][dd+1] = bf2f(vf.y);
  }
  if (tid < 200) {
    int qi = tid / 5, dd = (tid % 5) * 2;
    int qrow = (qi < RC_) ? seg*RC_ + qi : RCT_ + seg*SEG_ + (qi - RC_);
    ushort2 qf = *(const ushort2*)(q + ((size_t)b*L_ + qrow)*D_ + h*DH_ + dd);
    Qsh[qi][dd] = bf2f(qf.x); Qsh[qi][dd+1] = bf2f(qf.y);
  }
  __syncthreads();
  // scores: 40 rows x 6 lanes, Q row in registers
  if (tid < 240) {
    int qi = tid / 6, j = tid % 6;
    float qv[DH_];
    #pragma unroll
    for (int d = 0; d < DH_; ++d) qv[d] = Qsh[qi][d];
    for (int kk = j; kk < kc; kk += 6) {
      float s = 0.f;
      #pragma unroll
      for (int d = 0; d < DH_; ++d) s += qv[d] * Ksh[kk][d];
      Ssh[qi][kk] = s;
    }
  }
  __syncthreads();
  if (tid < 160) {
    int row = tid >> 2, j = tid & 3;
    float pm = -INFINITY;
    for (int kk = j; kk < kc; kk += 4) pm = fmaxf(pm, Ssh[row][kk]);
    pm = fmaxf(pm, __shfl_xor(pm, 1, 4));
    pm = fmaxf(pm, __shfl_xor(pm, 2, 4));
    float ps = 0.f;
    for (int kk = j; kk < kc; kk += 4) {
      float e = __expf(Ssh[row][kk] - pm);
      Ssh[row][kk] = e;
      ps += e;
    }
    ps += __shfl_xor(ps, 1, 4);
    ps += __shfl_xor(ps, 2, 4);
    if (j == 0) inv_sh[row] = 1.f / ps;
  }
  __syncthreads();
  // PV: 200 threads, each (row, d-pair); ushort2 output stores
  if (tid < 200) {
    int qi = tid / 5, dp = tid % 5;
    int d0 = dp*2;
    float a0 = 0.f, a1 = 0.f;
    for (int kk = 0; kk < kc; ++kk) {
      float p = Ssh[qi][kk];
      a0 += p * Vsh[kk][d0];
      a1 += p * Vsh[kk][d0+1];
    }
    float invl = inv_sh[qi];
    int qrow = (qi < RC_) ? seg*RC_ + qi : RCT_ + seg*SEG_ + (qi - RC_);
    ushort2 o;
    o.x = f2bf(a0 * invl);
    o.y = f2bf(a1 * invl);
    *(ushort2*)(att + ((size_t)b*L_ + qrow)*KP_ + h*DH_ + d0) = o;
  }
}

// ============ fused per-layer tail (16 waves), fragment-tiled weights,
//              contiguous-5 epilogue mapping ============
__global__ __launch_bounds__(1024) void k_ffn_fused(const ushort_t* __restrict__ attbf,
    const ushort_t* __restrict__ woT, const float* __restrict__ bo,
    const uchar_t* __restrict__ w18, const float* __restrict__ b1,
    const uchar_t* __restrict__ w28, const float* __restrict__ b2,
    const float* __restrict__ lfw, const float* __restrict__ lfb,
    const float* __restrict__ low, const float* __restrict__ lob,
    const float* __restrict__ liw, const float* __restrict__ lib, int mode,
    float* __restrict__ x, ushort_t* __restrict__ xnbf,
    const ushort_t* __restrict__ wqkvT_n, const float* __restrict__ bqkv_n,
    ushort_t* __restrict__ q, ushort_t* __restrict__ kv) {
  int tid = threadIdx.x;
  int wv = tid >> 6, lane = tid & 63;
  int r = lane & 15, g = lane >> 4;
  int bm = blockIdx.x * 16;
  __shared__ ushort_t attsh[16][KP_];
  __shared__ ushort_t hnsh[16][KP_];
  __shared__ uchar_t  hn8[16][104];
  __shared__ uchar_t  ff18[16][16][136];
  __shared__ ushort_t redb[16][16][D_];
  __shared__ float    vsh[16][D_];

  if (tid < 192) {
    int row = tid / 12, c = (tid % 12) * 8;
    *(bf16x8*)&attsh[row][c] = *(const bf16x8*)(attbf + (size_t)(bm+row)*KP_ + c);
  }
  __syncthreads();

  if (wv < 5) {
    f32x4 acc = {};
    #pragma unroll
    for (int kt = 0; kt < 3; ++kt) {
      bf16x8 a  = *(const bf16x8*)(&attsh[r][kt*32 + g*8]);
      bf16x8 bb = *(const bf16x8*)(woT + ((size_t)wv*3 + kt)*512 + lane*8);
      acc = __builtin_amdgcn_mfma_f32_16x16x32_bf16(a, bb, acc, 0, 0, 0);
    }
    #pragma unroll
    for (int rr = 0; rr < 4; ++rr)
      vsh[g*4 + rr][wv*16 + r] = acc[rr];
  }
  __syncthreads();

  // bias + residual (contiguous-5 x read) + LN_ff -> hn8
  if (tid < 256) {
    int row = tid >> 4, j = tid & 15;
    int grow = bm + row;
    float v[5], s = 0.f, ss = 0.f;
    #pragma unroll
    for (int c = 0; c < 5; ++c) {
      int col = j*5 + c;
      v[c] = vsh[row][col] + bo[col] + x[(size_t)grow*D_ + col];
      vsh[row][col] = v[c];
      s += v[c]; ss += v[c]*v[c];
    }
    s  += __shfl_xor(s, 1, 16);  ss += __shfl_xor(ss, 1, 16);
    s  += __shfl_xor(s, 2, 16);  ss += __shfl_xor(ss, 2, 16);
    s  += __shfl_xor(s, 4, 16);  ss += __shfl_xor(ss, 4, 16);
    s  += __shfl_xor(s, 8, 16);  ss += __shfl_xor(ss, 8, 16);
    float mean = s * (1.f/D_);
    float var  = ss * (1.f/D_) - mean*mean;
    float inv  = rsqrtf(var + EPS_);
    #pragma unroll
    for (int c = 0; c < 5; ++c) {
      int col = j*5 + c;
      hn8[row][col] = f2fp8((v[c] - mean) * inv * lfw[col] + lfb[col]);
    }
    hn8[row][D_ + j] = 0;
  }
  __syncthreads();

  // FFN1 fp8: fragment-tiled w18
  f32x4 acc1[8];
  #pragma unroll
  for (int ni = 0; ni < 8; ++ni) acc1[ni] = (f32x4){0.f,0.f,0.f,0.f};
  #pragma unroll
  for (int kt = 0; kt < 3; ++kt) {
    i64_t a = *(const i64_t*)(&hn8[r][kt*32 + g*8]);
    #pragma unroll
    for (int ni = 0; ni < 8; ++ni) {
      i64_t bb = *(const i64_t*)(w18 + (((size_t)(wv*8 + ni))*3 + kt)*512 + lane*8);
      acc1[ni] = __builtin_amdgcn_mfma_f32_16x16x32_fp8_fp8(a, bb, acc1[ni], 0, 0, 0);
    }
  }
  int nbase = wv*128;
  #pragma unroll
  for (int ni = 0; ni < 8; ++ni) {
    int col = nbase + ni*16 + r;
    float bc = b1[col];
    #pragma unroll
    for (int rr = 0; rr < 4; ++rr) {
      float v = acc1[ni][rr] * 0.0625f + bc;
      ff18[wv][g*4 + rr][ni*16 + r] = f2fp8(fmaxf(v, 0.f) * 8.f);
    }
  }

  // FFN2 fp8
  f32x4 acc2[5] = {};
  #pragma unroll
  for (int ks = 0; ks < 4; ++ks) {
    i64_t a = *(const i64_t*)(&ff18[wv][r][ks*32 + g*8]);
    #pragma unroll
    for (int nf = 0; nf < 5; ++nf) {
      i64_t bb = *(const i64_t*)(w28 + (((size_t)nf*64) + wv*4 + ks)*512 + lane*8);
      acc2[nf] = __builtin_amdgcn_mfma_f32_16x16x32_fp8_fp8(a, bb, acc2[nf], 0, 0, 0);
    }
  }
  #pragma unroll
  for (int nf = 0; nf < 5; ++nf)
    #pragma unroll
    for (int rr = 0; rr < 4; ++rr)
      redb[wv][g*4 + rr][nf*16 + r] = f2bf(acc2[nf][rr]);
  __syncthreads();

  for (int e = tid; e < 16*D_; e += 1024) {
    int row = e / D_, col = e % D_;
    float s0 = 0.f, s1 = 0.f, s2 = 0.f, s3 = 0.f;
    #pragma unroll
    for (int w = 0; w < 16; w += 4) {
      s0 += bf2f(redb[w+0][row][col]);
      s1 += bf2f(redb[w+1][row][col]);
      s2 += bf2f(redb[w+2][row][col]);
      s3 += bf2f(redb[w+3][row][col]);
    }
    vsh[row][col] = ((s0+s1)+(s2+s3)) * (1.f/128.f) + b2[col] + vsh[row][col];
  }
  __syncthreads();
  if (tid < 256) {
    int row = tid >> 4, j = tid & 15;
    float v[5], s = 0.f, ss = 0.f;
    #pragma unroll
    for (int c = 0; c < 5; ++c) {
      v[c] = vsh[row][j*5 + c];
      s += v[c]; ss += v[c]*v[c];
    }
    s  += __shfl_xor(s, 1, 16);  ss += __shfl_xor(ss, 1, 16);
    s  += __shfl_xor(s, 2, 16);  ss += __shfl_xor(ss, 2, 16);
    s  += __shfl_xor(s, 4, 16);  ss += __shfl_xor(ss, 4, 16);
    s  += __shfl_xor(s, 8, 16);  ss += __shfl_xor(ss, 8, 16);
    float mean = s * (1.f/D_);
    float var  = ss * (1.f/D_) - mean*mean;
    float inv  = rsqrtf(var + EPS_);
    int grow = bm + row;
    float xs[5];
    float s2 = 0.f, ss2 = 0.f;
    #pragma unroll
    for (int c = 0; c < 5; ++c) {
      int col = j*5 + c;
      xs[c] = (v[c] - mean) * inv * low[col] + lob[col];
      x[(size_t)grow*D_ + col] = xs[c];
      s2 += xs[c]; ss2 += xs[c]*xs[c];
    }
    if (mode == 0) {
      s2  += __shfl_xor(s2, 1, 16);  ss2 += __shfl_xor(ss2, 1, 16);
      s2  += __shfl_xor(s2, 2, 16);  ss2 += __shfl_xor(ss2, 2, 16);
      s2  += __shfl_xor(s2, 4, 16);  ss2 += __shfl_xor(ss2, 4, 16);
      s2  += __shfl_xor(s2, 8, 16);  ss2 += __shfl_xor(ss2, 8, 16);
      float m2 = s2 * (1.f/D_);
      float v2 = ss2 * (1.f/D_) - m2*m2;
      float i2 = rsqrtf(v2 + EPS_);
      #pragma unroll
      for (int c = 0; c < 5; ++c) {
        int col = j*5 + c;
        hnsh[row][col] = f2bf((xs[c] - m2) * i2 * liw[col] + lib[col]);
      }
      hnsh[row][D_ + j] = 0;
    } else {
      #pragma unroll
      for (int c = 0; c < 5; ++c)
        xnbf[(size_t)grow*KP_ + j*5 + c] = f2bf(xs[c]);
      xnbf[(size_t)grow*KP_ + D_ + j] = 0;
    }
  }

  // fused next-layer QKV -> bf16 q/kv
  if (mode == 0) {
    __syncthreads();
    if (wv < 15) {
      int t = wv;
      f32x4 acc = {};
      #pragma unroll
      for (int kt = 0; kt < 3; ++kt) {
        bf16x8 a  = *(const bf16x8*)(&hnsh[r][kt*32 + g*8]);
        bf16x8 bb = *(const bf16x8*)(wqkvT_n + ((size_t)t*3 + kt)*512 + lane*8);
        acc = __builtin_amdgcn_mfma_f32_16x16x32_bf16(a, bb, acc, 0, 0, 0);
      }
      int col = t*16 + r;
      float bc = bqkv_n[col];
      #pragma unroll
      for (int rr = 0; rr < 4; ++rr) {
        int row = bm + g*4 + rr;
        float v = acc[rr] + bc;
        if (col < D_) q[(size_t)row*D_ + col] = f2bf(v);
        else          kv[(size_t)row*2*D_ + (col - D_)] = f2bf(v);
      }
    }
  }
}

// ============ final proj MFMA, 64x64 tiles, fragment-tiled pwT ============
__global__ __launch_bounds__(256) void k_proj_mfma(const ushort_t* __restrict__ xbf,
    const ushort_t* __restrict__ pwT, const float* __restrict__ pb,
    const int* __restrict__ len, float* __restrict__ out) {
  int wv = threadIdx.x >> 6, lane = threadIdx.x & 63;
  int bm = blockIdx.x * 64;
  int bn = blockIdx.y * 64 + wv*16;
  int b  = blockIdx.z;
  int r = lane & 15, g = lane >> 4;
  f32x4 acc[4] = {};
  const ushort_t* Ab = xbf + ((size_t)(b*L_ + RCT_ + bm) + r)*KP_ + g*8;
  #pragma unroll
  for (int kt = 0; kt < 3; ++kt) {
    bf16x8 bb = *(const bf16x8*)(pwT + ((size_t)(bn >> 4)*3 + kt)*512 + lane*8);
    #pragma unroll
    for (int mf = 0; mf < 4; ++mf) {
      bf16x8 a = *(const bf16x8*)(Ab + mf*16*KP_ + kt*32);
      acc[mf] = __builtin_amdgcn_mfma_f32_16x16x32_bf16(a, bb, acc[mf], 0, 0, 0);
    }
  }
  int col = bn + r;
  float bc = pb[col];
  #pragma unroll
  for (int mf = 0; mf < 4; ++mf)
    #pragma unroll
    for (int rr = 0; rr < 4; ++rr) {
      int row = bm + mf*16 + g*4 + rr;
      out[((size_t)b*TU_ + row)*OUTD_ + col] = acc[mf][rr] + bc;
    }
  if (blockIdx.x == 0 && blockIdx.y == 0 && blockIdx.z == 0 && threadIdx.x < B_)
    out[(size_t)B_*TU_*OUTD_ + threadIdx.x] = (float)len[threadIdx.x];
}

extern "C" void kernel_launch(void* const* d_in, const int* in_sizes, int n_in,
                              void* d_out, int out_size, void* d_ws, size_t ws_size,
                              hipStream_t stream) {
  const float* mel     = (const float*)d_in[0];
  const int*   lengths = (const int*)  d_in[1];
  const float* ln_in_w = (const float*)d_in[2];
  const float* ln_in_b = (const float*)d_in[3];
  const float* wq      = (const float*)d_in[4];
  const float* bq      = (const float*)d_in[5];
  const float* wkv     = (const float*)d_in[6];
  const float* bkv     = (const float*)d_in[7];
  const float* wo      = (const float*)d_in[8];
  const float* bo      = (const float*)d_in[9];
  const float* ln_ff_w = (const float*)d_in[10];
  const float* ln_ff_b = (const float*)d_in[11];
  const float* w1      = (const float*)d_in[12];
  const float* b1      = (const float*)d_in[13];
  const float* w2      = (const float*)d_in[14];
  const float* b2      = (const float*)d_in[15];
  const float* ln_o_w  = (const float*)d_in[16];
  const float* ln_o_b  = (const float*)d_in[17];
  const float* pw      = (const float*)d_in[18];
  const float* pb      = (const float*)d_in[19];
  float* out = (float*)d_out;

  float* ws = (float*)d_ws;
  float* x     = ws; ws += NR_*D_;
  float* bqkv  = ws; ws += NLAYERS_*240;
  ushort_t* us = (ushort_t*)ws;
  ushort_t* qb    = us; us += NR_*D_;
  ushort_t* kvb   = us; us += NR_*2*D_;
  ushort_t* xnbf  = us; us += NR_*KP_;
  ushort_t* attbf = us; us += NR_*KP_;
  ushort_t* wqkvT = us; us += S3_;
  ushort_t* woT   = us; us += S4_;
  ushort_t* pwT   = us; us += S5_;
  uchar_t* ub = (uchar_t*)us;
  uchar_t* w18 = ub; ub += S1_;
  uchar_t* w28 = ub; ub += S2_;

  k_wprep_all<<<WSM_BLK_ + W1_BLK_ + W2_BLK_, 256, 0, stream>>>(
      wq, wkv, wo, pw, bq, bkv, w1, w2, wqkvT, woT, pwT, bqkv, w18, w28);
  k_build_qkv<<<NR_/16, 512, 0, stream>>>(mel, ln_in_w, ln_in_b, wqkvT, bqkv,
                                          x, qb, kvb, attbf);

  for (int l = 0; l < NLAYERS_; ++l) {
    int last = (l == NLAYERS_-1);
    k_attn<<<dim3(NSEG_, B_, H_), 256, 0, stream>>>(qb, kvb, attbf);
    k_ffn_fused<<<NR_/16, 1024, 0, stream>>>(attbf,
        woT + l*15*512, bo + l*D_,
        w18 + (size_t)l*FFN_*KP_, b1 + l*FFN_,
        w28 + (size_t)l*D_*FFN_, b2 + l*D_,
        ln_ff_w + l*D_, ln_ff_b + l*D_,
        ln_o_w + l*D_, ln_o_b + l*D_,
        ln_in_w + (last ? 0 : (l+1)*D_), ln_in_b + (last ? 0 : (l+1)*D_),
        last, x, xnbf,
        wqkvT + (last ? 0 : (l+1)*45*512), bqkv + (last ? 0 : (l+1)*240),
        qb, kvb);
  }

  k_proj_mfma<<<dim3(TU_/64, OUTD_/64, B_), 256, 0, stream>>>(xnbf, pwT, pb, lengths, out);
}

// Round 17
// 96.922 us; speedup vs baseline: 1.5354x; 1.0086x over previous
//
#include <hip/hip_runtime.h>
#include <math.h>

#define B_    2
#define TU_   1024
#define D_    80
#define H_    8
#define DH_   10
#define FFN_  2048
#define SEG_  32
#define RC_   8
#define LC_   50
#define NSEG_ 32
#define RCT_  256
#define L_    1280
#define NLAYERS_ 4
#define OUTD_ 768
#define EPS_  1e-5f
#define SCALE_ 0.31622776601683794f
#define NR_   (B_*L_)                 // 2560
#define KP_   96                      // K pad 80->96

typedef __attribute__((ext_vector_type(8))) short bf16x8;
typedef __attribute__((ext_vector_type(4))) float f32x4;
typedef unsigned short ushort_t;
typedef unsigned char uchar_t;
typedef long i64_t;

__device__ inline ushort_t f2bf(float f) {
  union { float f; unsigned u; } x; x.f = f;
  unsigned r = x.u + 0x7fffu + ((x.u >> 16) & 1u);   // RNE
  return (ushort_t)(r >> 16);
}
__device__ inline float bf2f(ushort_t u) {
  union { unsigned u; float f; } x; x.u = ((unsigned)u) << 16; return x.f;
}
__device__ inline uchar_t f2fp8(float f) {
  return (uchar_t)(__builtin_amdgcn_cvt_pk_fp8_f32(f, f, 0, false) & 0xff);
}
__device__ inline unsigned pk4fp8(float f0, float f1, float f2, float f3) {
  unsigned w = (unsigned)__builtin_amdgcn_cvt_pk_fp8_f32(f0, f1, 0, false);
  w = (unsigned)__builtin_amdgcn_cvt_pk_fp8_f32(f2, f3, (int)w, true);
  return w;
}

// ---- fragment-tiled sizes (tile = 512 elements = 64 lanes x 8) ----
#define S1_  (NLAYERS_*FFN_*KP_)       // w18 fp8 tiled [l][128 ntile][3 ktile][512]
#define S2_  (NLAYERS_*D_*FFN_)        // w28 fp8 tiled [l][5 ntile][64 ktile][512]
#define S3_  (NLAYERS_*45*512)         // wqkvT bf16 tiled [l][15][3][512]
#define S4_  (NLAYERS_*15*512)         // woT bf16 tiled [l][5][3][512]
#define S5_  (144*512)                 // pwT bf16 tiled [48][3][512]
#define S6_  (NLAYERS_*240)            // bqkv fp32
#define WSM_N_ (S3_+S4_+S5_+S6_)
#define WSM_BLK_ ((WSM_N_ + 255)/256)          // 772
#define W1_BLK_  (32*NLAYERS_)                 // 128
#define W2_BLK_  (32*NLAYERS_)                 // 128

// ============ unified weight prep (+ lengths tail) ============
__global__ __launch_bounds__(256) void k_wprep_all(
    const float* __restrict__ wq, const float* __restrict__ wkv,
    const float* __restrict__ wo, const float* __restrict__ pw,
    const float* __restrict__ bq, const float* __restrict__ bkv,
    const float* __restrict__ w1, const float* __restrict__ w2,
    ushort_t* __restrict__ wqkvT, ushort_t* __restrict__ woT,
    ushort_t* __restrict__ pwT, float* __restrict__ bqkv,
    uchar_t* __restrict__ w18, uchar_t* __restrict__ w28,
    const int* __restrict__ len, float* __restrict__ out) {
  int bx = blockIdx.x;
  int tid = threadIdx.x;
  __shared__ float t[5120];

  if (bx == 0 && tid < B_)
    out[(size_t)B_*TU_*OUTD_ + tid] = (float)len[tid];

  if (bx < WSM_BLK_) {
    int idx = bx * 256 + tid;
    if (idx < S3_) {
      int l = idx / (45*512); int rem = idx % (45*512);
      int tile = rem / 512, off = rem % 512;
      int tt = tile / 3, kt = tile % 3;
      int lane = off >> 3, j = off & 7;
      int n = tt*16 + (lane & 15);
      int k = kt*32 + (lane >> 4)*8 + j;
      float v = 0.f;
      if (k < D_) {
        if (n < D_)       v = wq[(l*D_ + k)*D_ + n] * SCALE_;
        else if (n < 240) v = wkv[(l*D_ + k)*2*D_ + (n - D_)];
      }
      wqkvT[idx] = f2bf(v);
      return;
    }
    idx -= S3_;
    if (idx < S4_) {
      int l = idx / (15*512); int rem = idx % (15*512);
      int tile = rem / 512, off = rem % 512;
      int nf = tile / 3, kt = tile % 3;
      int lane = off >> 3, j = off & 7;
      int n = nf*16 + (lane & 15);
      int k = kt*32 + (lane >> 4)*8 + j;
      woT[idx] = (k < D_) ? f2bf(wo[(l*D_ + k)*D_ + n]) : 0;
      return;
    }
    idx -= S4_;
    if (idx < S5_) {
      int tile = idx / 512, off = idx % 512;
      int tt = tile / 3, kt = tile % 3;
      int lane = off >> 3, j = off & 7;
      int n = tt*16 + (lane & 15);
      int k = kt*32 + (lane >> 4)*8 + j;
      pwT[idx] = (k < D_) ? f2bf(pw[k*OUTD_ + n]) : 0;
      return;
    }
    idx -= S5_;
    if (idx < S6_) {
      int c = idx % 240, l = idx / 240;
      bqkv[idx] = (c < D_) ? bq[l*D_ + c] * SCALE_ : bkv[l*2*D_ + (c - D_)];
    }
    return;
  }
  bx -= WSM_BLK_;
  if (bx < W1_BLK_) {
    int n0 = (bx & 31) * 64, l = bx >> 5;
    for (int idx = tid; idx < D_*64; idx += 256) {
      int k = idx >> 6, n = idx & 63;
      t[k*64 + n] = w1[((size_t)(l*D_ + k))*FFN_ + n0 + n];
    }
    __syncthreads();
    for (int idx = tid; idx < 4*3*64; idx += 256) {
      int nis = idx / 192, rem = idx % 192;
      int kt = rem / 64, lane = rem % 64;
      int r = lane & 15, g = lane >> 4;
      int nl = nis*16 + r;
      int kb = kt*32 + g*8;
      float v[8];
      #pragma unroll
      for (int j = 0; j < 8; ++j) {
        int k = kb + j;
        v[j] = (k < D_) ? t[k*64 + nl]*16.f : 0.f;
      }
      uint2 o;
      o.x = pk4fp8(v[0], v[1], v[2], v[3]);
      o.y = pk4fp8(v[4], v[5], v[6], v[7]);
      size_t ni = (size_t)(n0 >> 4) + nis;
      *(uint2*)(w18 + (((size_t)l*128 + ni)*3 + kt)*512 + lane*8) = o;
    }
    return;
  }
  bx -= W1_BLK_;
  {
    int k0 = (bx & 31) * 64, l = bx >> 5;
    for (int idx = tid; idx < 64*D_; idx += 256) {
      int k = idx / D_, n = idx % D_;
      t[k*D_ + n] = w2[((size_t)(l*FFN_ + k0 + k))*D_ + n];
    }
    __syncthreads();
    for (int idx = tid; idx < 5*2*64; idx += 256) {
      int nf = idx / 128, rem = idx % 128;
      int ktl = rem / 64, lane = rem % 64;
      int r = lane & 15, g = lane >> 4;
      int n = nf*16 + r;
      int kb = ktl*32 + g*8;
      uint2 o;
      o.x = pk4fp8(t[(kb+0)*D_+n]*16.f, t[(kb+1)*D_+n]*16.f, t[(kb+2)*D_+n]*16.f, t[(kb+3)*D_+n]*16.f);
      o.y = pk4fp8(t[(kb+4)*D_+n]*16.f, t[(kb+5)*D_+n]*16.f, t[(kb+6)*D_+n]*16.f, t[(kb+7)*D_+n]*16.f);
      size_t kt = (size_t)(k0 >> 5) + ktl;
      *(uint2*)(w28 + (((size_t)l*5 + nf)*64 + kt)*512 + lane*8) = o;
    }
  }
}

// ============ merged: gather mel -> x + layer-0 LN_in + QKV MFMA -> q/kv (bf16) ============
__global__ __launch_bounds__(512) void k_build_qkv(const float* __restrict__ mel,
    const float* __restrict__ lw, const float* __restrict__ lb,
    const ushort_t* __restrict__ wqkvT, const float* __restrict__ bqkv,
    float* __restrict__ x, ushort_t* __restrict__ q, ushort_t* __restrict__ kv,
    ushort_t* __restrict__ attbf) {
  int tid = threadIdx.x;
  int wv = tid >> 6, lane = tid & 63;
  int r = lane & 15, g = lane >> 4;
  int bm = blockIdx.x * 16;
  __shared__ ushort_t hnsh[16][KP_];

  if (tid < 256) {
    int row = tid >> 4, j = tid & 15;
    int grow = bm + row;
    int b = grow / L_, i = grow % L_;
    int srow = (i < RCT_) ? ((i >> 3) + 1)*SEG_ + (i & 7) : i - RCT_;
    float v[5], s = 0.f, ss = 0.f;
    #pragma unroll
    for (int c = 0; c < 5; ++c) {
      int col = j*5 + c;
      v[c] = mel[((size_t)b*(TU_+RC_) + srow)*D_ + col];
      x[(size_t)grow*D_ + col] = v[c];
      s += v[c]; ss += v[c]*v[c];
    }
    s  += __shfl_xor(s, 1, 16);  ss += __shfl_xor(ss, 1, 16);
    s  += __shfl_xor(s, 2, 16);  ss += __shfl_xor(ss, 2, 16);
    s  += __shfl_xor(s, 4, 16);  ss += __shfl_xor(ss, 4, 16);
    s  += __shfl_xor(s, 8, 16);  ss += __shfl_xor(ss, 8, 16);
    float mean = s * (1.f/D_);
    float var  = ss * (1.f/D_) - mean*mean;
    float inv  = rsqrtf(var + EPS_);
    #pragma unroll
    for (int c = 0; c < 5; ++c) {
      int col = j*5 + c;
      hnsh[row][col] = f2bf((v[c] - mean) * inv * lw[col] + lb[col]);
    }
    hnsh[row][D_ + j] = 0;
    attbf[(size_t)grow*KP_ + D_ + j] = 0;    // zero pad cols once for all layers
  }
  __syncthreads();

  for (int t = wv; t < 15; t += 8) {
    f32x4 acc = {};
    #pragma unroll
    for (int kt = 0; kt < 3; ++kt) {
      bf16x8 a  = *(const bf16x8*)(&hnsh[r][kt*32 + g*8]);
      bf16x8 bb = *(const bf16x8*)(wqkvT + ((size_t)t*3 + kt)*512 + lane*8);
      acc = __builtin_amdgcn_mfma_f32_16x16x32_bf16(a, bb, acc, 0, 0, 0);
    }
    int col = t*16 + r;
    float bc = bqkv[col];
    #pragma unroll
    for (int rr = 0; rr < 4; ++rr) {
      int row = bm + g*4 + rr;
      float v = acc[rr] + bc;
      if (col < D_) q[(size_t)row*D_ + col] = f2bf(v);
      else          kv[(size_t)row*2*D_ + (col - D_)] = f2bf(v);
    }
  }
}

// ============ block-sparse attention (bf16 q/kv in) -> attbf bf16 [2560][96] ============
__global__ __launch_bounds__(256) void k_attn(const ushort_t* __restrict__ q,
    const ushort_t* __restrict__ kv, ushort_t* __restrict__ att) {
  int seg = blockIdx.x, b = blockIdx.y, h = blockIdx.z;
  int tid = threadIdx.x;
  int seg_start = seg*SEG_ - LC_; if (seg_start < 0) seg_start = 0;
  int kc = RC_ + (seg+1)*SEG_ - seg_start;       // <= 90
  __shared__ float Ksh[90][DH_];
  __shared__ float Vsh[90][DH_];
  __shared__ float Qsh[40][DH_];
  __shared__ float Ssh[40][90];
  __shared__ float inv_sh[40];
  for (int idx = tid; idx < kc*5; idx += 256) {
    int kk = idx / 5, dd = (idx % 5) * 2;
    int krow = (kk < RC_) ? seg*RC_ + kk : RCT_ + seg_start + (kk - RC_);
    const ushort_t* base = kv + ((size_t)b*L_ + krow)*2*D_ + h*DH_ + dd;
    ushort2 kf = *(const ushort2*)base;
    ushort2 vf = *(const ushort2*)(base + D_);
    Ksh[kk][dd] = bf2f(kf.x); Ksh[kk][dd+1] = bf2f(kf.y);
    Vsh[kk][dd] = bf2f(vf.x); Vsh[kk][dd+1] = bf2f(vf.y);
  }
  if (tid < 200) {
    int qi = tid / 5, dd = (tid % 5) * 2;
    int qrow = (qi < RC_) ? seg*RC_ + qi : RCT_ + seg*SEG_ + (qi - RC_);
    ushort2 qf = *(const ushort2*)(q + ((size_t)b*L_ + qrow)*D_ + h*DH_ + dd);
    Qsh[qi][dd] = bf2f(qf.x); Qsh[qi][dd+1] = bf2f(qf.y);
  }
  __syncthreads();
  if (tid < 240) {
    int qi = tid / 6, j = tid % 6;
    float qv[DH_];
    #pragma unroll
    for (int d = 0; d < DH_; ++d) qv[d] = Qsh[qi][d];
    for (int kk = j; kk < kc; kk += 6) {
      float s = 0.f;
      #pragma unroll
      for (int d = 0; d < DH_; ++d) s += qv[d] * Ksh[kk][d];
      Ssh[qi][kk] = s;
    }
  }
  __syncthreads();
  if (tid < 160) {
    int row = tid >> 2, j = tid & 3;
    float pm = -INFINITY;
    for (int kk = j; kk < kc; kk += 4) pm = fmaxf(pm, Ssh[row][kk]);
    pm = fmaxf(pm, __shfl_xor(pm, 1, 4));
    pm = fmaxf(pm, __shfl_xor(pm, 2, 4));
    float ps = 0.f;
    for (int kk = j; kk < kc; kk += 4) {
      float e = __expf(Ssh[row][kk] - pm);
      Ssh[row][kk] = e;
      ps += e;
    }
    ps += __shfl_xor(ps, 1, 4);
    ps += __shfl_xor(ps, 2, 4);
    if (j == 0) inv_sh[row] = 1.f / ps;
  }
  __syncthreads();
  if (tid < 200) {
    int qi = tid / 5, dp = tid % 5;
    int d0 = dp*2;
    float a0 = 0.f, a1 = 0.f;
    for (int kk = 0; kk < kc; ++kk) {
      float p = Ssh[qi][kk];
      a0 += p * Vsh[kk][d0];
      a1 += p * Vsh[kk][d0+1];
    }
    float invl = inv_sh[qi];
    int qrow = (qi < RC_) ? seg*RC_ + qi : RCT_ + seg*SEG_ + (qi - RC_);
    ushort2 o;
    o.x = f2bf(a0 * invl);
    o.y = f2bf(a1 * invl);
    *(ushort2*)(att + ((size_t)b*L_ + qrow)*KP_ + h*DH_ + d0) = o;
  }
}

// ============ fused per-layer tail (16 waves), fragment-tiled weights,
//              mode0: +QKV(next); mode1: +final projection ============
__global__ __launch_bounds__(1024) void k_ffn_fused(const ushort_t* __restrict__ attbf,
    const ushort_t* __restrict__ woT, const float* __restrict__ bo,
    const uchar_t* __restrict__ w18, const float* __restrict__ b1,
    const uchar_t* __restrict__ w28, const float* __restrict__ b2,
    const float* __restrict__ lfw, const float* __restrict__ lfb,
    const float* __restrict__ low, const float* __restrict__ lob,
    const float* __restrict__ liw, const float* __restrict__ lib, int mode,
    float* __restrict__ x,
    const ushort_t* __restrict__ wqkvT_n, const float* __restrict__ bqkv_n,
    ushort_t* __restrict__ q, ushort_t* __restrict__ kv,
    const ushort_t* __restrict__ pwT, const float* __restrict__ pb,
    float* __restrict__ out) {
  int tid = threadIdx.x;
  int wv = tid >> 6, lane = tid & 63;
  int r = lane & 15, g = lane >> 4;
  int bm = blockIdx.x * 16;
  __shared__ ushort_t attsh[16][KP_];
  __shared__ ushort_t hnsh[16][KP_];
  __shared__ uchar_t  hn8[16][104];
  __shared__ uchar_t  ff18[16][16][136];
  __shared__ ushort_t redb[16][16][D_];
  __shared__ float    vsh[16][D_];

  if (tid < 192) {
    int row = tid / 12, c = (tid % 12) * 8;
    *(bf16x8*)&attsh[row][c] = *(const bf16x8*)(attbf + (size_t)(bm+row)*KP_ + c);
  }
  __syncthreads();

  // ---- WO split over 15 waves: wave = (nf, kt) pair, bf16 partials in redb ----
  if (wv < 15) {
    int nf = wv / 3, kt = wv % 3;
    f32x4 acc = {};
    bf16x8 a  = *(const bf16x8*)(&attsh[r][kt*32 + g*8]);
    bf16x8 bb = *(const bf16x8*)(woT + ((size_t)nf*3 + kt)*512 + lane*8);
    acc = __builtin_amdgcn_mfma_f32_16x16x32_bf16(a, bb, acc, 0, 0, 0);
    #pragma unroll
    for (int rr = 0; rr < 4; ++rr)
      redb[wv][g*4 + rr][nf*16 + r] = f2bf(acc[rr]);
  }
  __syncthreads();

  // ---- sum 3 kt-partials + bias + residual + LN_ff -> hn8 (res kept in vsh) ----
  if (tid < 256) {
    int row = tid >> 4, j = tid & 15;
    int grow = bm + row;
    float v[5], s = 0.f, ss = 0.f;
    #pragma unroll
    for (int c = 0; c < 5; ++c) {
      int col = j*5 + c;
      int nf3 = (col >> 4) * 3;
      float wo3 = bf2f(redb[nf3][row][col]) + bf2f(redb[nf3+1][row][col])
                + bf2f(redb[nf3+2][row][col]);
      v[c] = wo3 + bo[col] + x[(size_t)grow*D_ + col];
      vsh[row][col] = v[c];
      s += v[c]; ss += v[c]*v[c];
    }
    s  += __shfl_xor(s, 1, 16);  ss += __shfl_xor(ss, 1, 16);
    s  += __shfl_xor(s, 2, 16);  ss += __shfl_xor(ss, 2, 16);
    s  += __shfl_xor(s, 4, 16);  ss += __shfl_xor(ss, 4, 16);
    s  += __shfl_xor(s, 8, 16);  ss += __shfl_xor(ss, 8, 16);
    float mean = s * (1.f/D_);
    float var  = ss * (1.f/D_) - mean*mean;
    float inv  = rsqrtf(var + EPS_);
    #pragma unroll
    for (int c = 0; c < 5; ++c) {
      int col = j*5 + c;
      hn8[row][col] = f2fp8((v[c] - mean) * inv * lfw[col] + lfb[col]);
    }
    hn8[row][D_ + j] = 0;
  }
  __syncthreads();

  // ---- FFN1 fp8 ----
  f32x4 acc1[8];
  #pragma unroll
  for (int ni = 0; ni < 8; ++ni) acc1[ni] = (f32x4){0.f,0.f,0.f,0.f};
  #pragma unroll
  for (int kt = 0; kt < 3; ++kt) {
    i64_t a = *(const i64_t*)(&hn8[r][kt*32 + g*8]);
    #pragma unroll
    for (int ni = 0; ni < 8; ++ni) {
      i64_t bb = *(const i64_t*)(w18 + (((size_t)(wv*8 + ni))*3 + kt)*512 + lane*8);
      acc1[ni] = __builtin_amdgcn_mfma_f32_16x16x32_fp8_fp8(a, bb, acc1[ni], 0, 0, 0);
    }
  }
  int nbase = wv*128;
  #pragma unroll
  for (int ni = 0; ni < 8; ++ni) {
    int col = nbase + ni*16 + r;
    float bc = b1[col];
    #pragma unroll
    for (int rr = 0; rr < 4; ++rr) {
      float v = acc1[ni][rr] * 0.0625f + bc;
      ff18[wv][g*4 + rr][ni*16 + r] = f2fp8(fmaxf(v, 0.f) * 8.f);
    }
  }

  // ---- FFN2 fp8 ----
  f32x4 acc2[5] = {};
  #pragma unroll
  for (int ks = 0; ks < 4; ++ks) {
    i64_t a = *(const i64_t*)(&ff18[wv][r][ks*32 + g*8]);
    #pragma unroll
    for (int nf = 0; nf < 5; ++nf) {
      i64_t bb = *(const i64_t*)(w28 + (((size_t)nf*64) + wv*4 + ks)*512 + lane*8);
      acc2[nf] = __builtin_amdgcn_mfma_f32_16x16x32_fp8_fp8(a, bb, acc2[nf], 0, 0, 0);
    }
  }
  #pragma unroll
  for (int nf = 0; nf < 5; ++nf)
    #pragma unroll
    for (int rr = 0; rr < 4; ++rr)
      redb[wv][g*4 + rr][nf*16 + r] = f2bf(acc2[nf][rr]);
  __syncthreads();

  for (int e = tid; e < 16*D_; e += 1024) {
    int row = e / D_, col = e % D_;
    float s0 = 0.f, s1 = 0.f, s2 = 0.f, s3 = 0.f;
    #pragma unroll
    for (int w = 0; w < 16; w += 4) {
      s0 += bf2f(redb[w+0][row][col]);
      s1 += bf2f(redb[w+1][row][col]);
      s2 += bf2f(redb[w+2][row][col]);
      s3 += bf2f(redb[w+3][row][col]);
    }
    vsh[row][col] = ((s0+s1)+(s2+s3)) * (1.f/128.f) + b2[col] + vsh[row][col];
  }
  __syncthreads();
  if (tid < 256) {
    int row = tid >> 4, j = tid & 15;
    float v[5], s = 0.f, ss = 0.f;
    #pragma unroll
    for (int c = 0; c < 5; ++c) {
      v[c] = vsh[row][j*5 + c];
      s += v[c]; ss += v[c]*v[c];
    }
    s  += __shfl_xor(s, 1, 16);  ss += __shfl_xor(ss, 1, 16);
    s  += __shfl_xor(s, 2, 16);  ss += __shfl_xor(ss, 2, 16);
    s  += __shfl_xor(s, 4, 16);  ss += __shfl_xor(ss, 4, 16);
    s  += __shfl_xor(s, 8, 16);  ss += __shfl_xor(ss, 8, 16);
    float mean = s * (1.f/D_);
    float var  = ss * (1.f/D_) - mean*mean;
    float inv  = rsqrtf(var + EPS_);
    int grow = bm + row;
    float xs[5];
    float s2 = 0.f, ss2 = 0.f;
    #pragma unroll
    for (int c = 0; c < 5; ++c) {
      int col = j*5 + c;
      xs[c] = (v[c] - mean) * inv * low[col] + lob[col];
      x[(size_t)grow*D_ + col] = xs[c];
      s2 += xs[c]; ss2 += xs[c]*xs[c];
    }
    if (mode == 0) {
      s2  += __shfl_xor(s2, 1, 16);  ss2 += __shfl_xor(ss2, 1, 16);
      s2  += __shfl_xor(s2, 2, 16);  ss2 += __shfl_xor(ss2, 2, 16);
      s2  += __shfl_xor(s2, 4, 16);  ss2 += __shfl_xor(ss2, 4, 16);
      s2  += __shfl_xor(s2, 8, 16);  ss2 += __shfl_xor(ss2, 8, 16);
      float m2 = s2 * (1.f/D_);
      float v2 = ss2 * (1.f/D_) - m2*m2;
      float i2 = rsqrtf(v2 + EPS_);
      #pragma unroll
      for (int c = 0; c < 5; ++c) {
        int col = j*5 + c;
        hnsh[row][col] = f2bf((xs[c] - m2) * i2 * liw[col] + lib[col]);
      }
    } else {
      #pragma unroll
      for (int c = 0; c < 5; ++c)
        hnsh[row][j*5 + c] = f2bf(xs[c]);       // stage for fused projection
    }
    hnsh[row][D_ + j] = 0;
  }

  if (mode == 0) {
    // ---- fused next-layer QKV -> bf16 q/kv ----
    __syncthreads();
    if (wv < 15) {
      int t = wv;
      f32x4 acc = {};
      #pragma unroll
      for (int kt = 0; kt < 3; ++kt) {
        bf16x8 a  = *(const bf16x8*)(&hnsh[r][kt*32 + g*8]);
        bf16x8 bb = *(const bf16x8*)(wqkvT_n + ((size_t)t*3 + kt)*512 + lane*8);
        acc = __builtin_amdgcn_mfma_f32_16x16x32_bf16(a, bb, acc, 0, 0, 0);
      }
      int col = t*16 + r;
      float bc = bqkv_n[col];
      #pragma unroll
      for (int rr = 0; rr < 4; ++rr) {
        int row = bm + g*4 + rr;
        float v = acc[rr] + bc;
        if (col < D_) q[(size_t)row*D_ + col] = f2bf(v);
        else          kv[(size_t)row*2*D_ + (col - D_)] = f2bf(v);
      }
    }
  } else {
    // ---- fused final projection: u-rows only, [16x96] @ pwT -> out[16x768] ----
    int i0 = bm % L_;
    if (i0 >= RCT_) {
      __syncthreads();
      int b = bm / L_;
      int urow0 = i0 - RCT_;
      for (int t = wv; t < 48; t += 16) {
        f32x4 acc = {};
        #pragma unroll
        for (int kt = 0; kt < 3; ++kt) {
          bf16x8 a  = *(const bf16x8*)(&hnsh[r][kt*32 + g*8]);
          bf16x8 bb = *(const bf16x8*)(pwT + ((size_t)t*3 + kt)*512 + lane*8);
          acc = __builtin_amdgcn_mfma_f32_16x16x32_bf16(a, bb, acc, 0, 0, 0);
        }
        int col = t*16 + r;
        float bc = pb[col];
        #pragma unroll
        for (int rr = 0; rr < 4; ++rr) {
          int row = urow0 + g*4 + rr;
          out[((size_t)b*TU_ + row)*OUTD_ + col] = acc[rr] + bc;
        }
      }
    }
  }
}

extern "C" void kernel_launch(void* const* d_in, const int* in_sizes, int n_in,
                              void* d_out, int out_size, void* d_ws, size_t ws_size,
                              hipStream_t stream) {
  const float* mel     = (const float*)d_in[0];
  const int*   lengths = (const int*)  d_in[1];
  const float* ln_in_w = (const float*)d_in[2];
  const float* ln_in_b = (const float*)d_in[3];
  const float* wq      = (const float*)d_in[4];
  const float* bq      = (const float*)d_in[5];
  const float* wkv     = (const float*)d_in[6];
  const float* bkv     = (const float*)d_in[7];
  const float* wo      = (const float*)d_in[8];
  const float* bo      = (const float*)d_in[9];
  const float* ln_ff_w = (const float*)d_in[10];
  const float* ln_ff_b = (const float*)d_in[11];
  const float* w1      = (const float*)d_in[12];
  const float* b1      = (const float*)d_in[13];
  const float* w2      = (const float*)d_in[14];
  const float* b2      = (const float*)d_in[15];
  const float* ln_o_w  = (const float*)d_in[16];
  const float* ln_o_b  = (const float*)d_in[17];
  const float* pw      = (const float*)d_in[18];
  const float* pb      = (const float*)d_in[19];
  float* out = (float*)d_out;

  float* ws = (float*)d_ws;
  float* x     = ws; ws += NR_*D_;
  float* bqkv  = ws; ws += NLAYERS_*240;
  ushort_t* us = (ushort_t*)ws;
  ushort_t* qb    = us; us += NR_*D_;
  ushort_t* kvb   = us; us += NR_*2*D_;
  ushort_t* attbf = us; us += NR_*KP_;
  ushort_t* wqkvT = us; us += S3_;
  ushort_t* woT   = us; us += S4_;
  ushort_t* pwT   = us; us += S5_;
  uchar_t* ub = (uchar_t*)us;
  uchar_t* w18 = ub; ub += S1_;
  uchar_t* w28 = ub; ub += S2_;

  k_wprep_all<<<WSM_BLK_ + W1_BLK_ + W2_BLK_, 256, 0, stream>>>(
      wq, wkv, wo, pw, bq, bkv, w1, w2, wqkvT, woT, pwT, bqkv, w18, w28,
      lengths, out);
  k_build_qkv<<<NR_/16, 512, 0, stream>>>(mel, ln_in_w, ln_in_b, wqkvT, bqkv,
                                          x, qb, kvb, attbf);

  for (int l = 0; l < NLAYERS_; ++l) {
    int last = (l == NLAYERS_-1);
    k_attn<<<dim3(NSEG_, B_, H_), 256, 0, stream>>>(qb, kvb, attbf);
    k_ffn_fused<<<NR_/16, 1024, 0, stream>>>(attbf,
        woT + l*15*512, bo + l*D_,
        w18 + (size_t)l*FFN_*KP_, b1 + l*FFN_,
        w28 + (size_t)l*D_*FFN_, b2 + l*D_,
        ln_ff_w + l*D_, ln_ff_b + l*D_,
        ln_o_w + l*D_, ln_o_b + l*D_,
        ln_in_w + (last ? 0 : (l+1)*D_), ln_in_b + (last ? 0 : (l+1)*D_),
        last, x,
        wqkvT + (last ? 0 : (l+1)*45*512), bqkv + (last ? 0 : (l+1)*240),
        qb, kvb, pwT, pb, out);
  }
}

// Round 18
// 95.778 us; speedup vs baseline: 1.5537x; 1.0119x over previous
//
#include <hip/hip_runtime.h>
#include <math.h>

#define B_    2
#define TU_   1024
#define D_    80
#define H_    8
#define DH_   10
#define FFN_  2048
#define SEG_  32
#define RC_   8
#define LC_   50
#define NSEG_ 32
#define RCT_  256
#define L_    1280
#define NLAYERS_ 4
#define OUTD_ 768
#define EPS_  1e-5f
#define SCALE_ 0.31622776601683794f
#define NR_   (B_*L_)                 // 2560
#define KP_   96                      // K pad 80->96

typedef __attribute__((ext_vector_type(8))) short bf16x8;
typedef __attribute__((ext_vector_type(4))) float f32x4;
typedef unsigned short ushort_t;
typedef unsigned char uchar_t;
typedef long i64_t;

__device__ inline ushort_t f2bf(float f) {
  union { float f; unsigned u; } x; x.f = f;
  unsigned r = x.u + 0x7fffu + ((x.u >> 16) & 1u);   // RNE
  return (ushort_t)(r >> 16);
}
__device__ inline float bf2f(ushort_t u) {
  union { unsigned u; float f; } x; x.u = ((unsigned)u) << 16; return x.f;
}
__device__ inline uchar_t f2fp8(float f) {
  return (uchar_t)(__builtin_amdgcn_cvt_pk_fp8_f32(f, f, 0, false) & 0xff);
}
__device__ inline unsigned pk4fp8(float f0, float f1, float f2, float f3) {
  unsigned w = (unsigned)__builtin_amdgcn_cvt_pk_fp8_f32(f0, f1, 0, false);
  w = (unsigned)__builtin_amdgcn_cvt_pk_fp8_f32(f2, f3, (int)w, true);
  return w;
}

// ---- fragment-tiled sizes (tile = 512 elements = 64 lanes x 8) ----
#define S1_  (NLAYERS_*FFN_*KP_)       // w18 fp8 tiled [l][128 ntile][3 ktile][512]
#define S2_  (NLAYERS_*D_*FFN_)        // w28 fp8 tiled [l][5 ntile][64 ktile][512]
#define S3_  (NLAYERS_*45*512)         // wqkvT bf16 tiled [l][15][3][512]
#define S4_  (NLAYERS_*15*512)         // woT bf16 tiled [l][5][3][512]
#define S5_  (144*512)                 // pwT bf16 tiled [48][3][512]
#define S6_  (NLAYERS_*240)            // bqkv fp32
#define WSM_N_ (S3_+S4_+S5_+S6_)
#define WSM_BLK_ ((WSM_N_ + 255)/256)          // 772
#define W1_BLK_  (32*NLAYERS_)                 // 128
#define W2_BLK_  (32*NLAYERS_)                 // 128

// ============ unified weight prep (+ lengths tail) ============
__global__ __launch_bounds__(256) void k_wprep_all(
    const float* __restrict__ wq, const float* __restrict__ wkv,
    const float* __restrict__ wo, const float* __restrict__ pw,
    const float* __restrict__ bq, const float* __restrict__ bkv,
    const float* __restrict__ w1, const float* __restrict__ w2,
    ushort_t* __restrict__ wqkvT, ushort_t* __restrict__ woT,
    ushort_t* __restrict__ pwT, float* __restrict__ bqkv,
    uchar_t* __restrict__ w18, uchar_t* __restrict__ w28,
    const int* __restrict__ len, float* __restrict__ out) {
  int bx = blockIdx.x;
  int tid = threadIdx.x;
  __shared__ float t[5120];

  if (bx == 0 && tid < B_)
    out[(size_t)B_*TU_*OUTD_ + tid] = (float)len[tid];

  if (bx < WSM_BLK_) {
    int idx = bx * 256 + tid;
    if (idx < S3_) {
      int l = idx / (45*512); int rem = idx % (45*512);
      int tile = rem / 512, off = rem % 512;
      int tt = tile / 3, kt = tile % 3;
      int lane = off >> 3, j = off & 7;
      int n = tt*16 + (lane & 15);
      int k = kt*32 + (lane >> 4)*8 + j;
      float v = 0.f;
      if (k < D_) {
        if (n < D_)       v = wq[(l*D_ + k)*D_ + n] * SCALE_;
        else if (n < 240) v = wkv[(l*D_ + k)*2*D_ + (n - D_)];
      }
      wqkvT[idx] = f2bf(v);
      return;
    }
    idx -= S3_;
    if (idx < S4_) {
      int l = idx / (15*512); int rem = idx % (15*512);
      int tile = rem / 512, off = rem % 512;
      int nf = tile / 3, kt = tile % 3;
      int lane = off >> 3, j = off & 7;
      int n = nf*16 + (lane & 15);
      int k = kt*32 + (lane >> 4)*8 + j;
      woT[idx] = (k < D_) ? f2bf(wo[(l*D_ + k)*D_ + n]) : 0;
      return;
    }
    idx -= S4_;
    if (idx < S5_) {
      int tile = idx / 512, off = idx % 512;
      int tt = tile / 3, kt = tile % 3;
      int lane = off >> 3, j = off & 7;
      int n = tt*16 + (lane & 15);
      int k = kt*32 + (lane >> 4)*8 + j;
      pwT[idx] = (k < D_) ? f2bf(pw[k*OUTD_ + n]) : 0;
      return;
    }
    idx -= S5_;
    if (idx < S6_) {
      int c = idx % 240, l = idx / 240;
      bqkv[idx] = (c < D_) ? bq[l*D_ + c] * SCALE_ : bkv[l*2*D_ + (c - D_)];
    }
    return;
  }
  bx -= WSM_BLK_;
  if (bx < W1_BLK_) {
    int n0 = (bx & 31) * 64, l = bx >> 5;
    for (int idx = tid; idx < D_*64; idx += 256) {
      int k = idx >> 6, n = idx & 63;
      t[k*64 + n] = w1[((size_t)(l*D_ + k))*FFN_ + n0 + n];
    }
    __syncthreads();
    for (int idx = tid; idx < 4*3*64; idx += 256) {
      int nis = idx / 192, rem = idx % 192;
      int kt = rem / 64, lane = rem % 64;
      int r = lane & 15, g = lane >> 4;
      int nl = nis*16 + r;
      int kb = kt*32 + g*8;
      float v[8];
      #pragma unroll
      for (int j = 0; j < 8; ++j) {
        int k = kb + j;
        v[j] = (k < D_) ? t[k*64 + nl]*16.f : 0.f;
      }
      uint2 o;
      o.x = pk4fp8(v[0], v[1], v[2], v[3]);
      o.y = pk4fp8(v[4], v[5], v[6], v[7]);
      size_t ni = (size_t)(n0 >> 4) + nis;
      *(uint2*)(w18 + (((size_t)l*128 + ni)*3 + kt)*512 + lane*8) = o;
    }
    return;
  }
  bx -= W1_BLK_;
  {
    int k0 = (bx & 31) * 64, l = bx >> 5;
    for (int idx = tid; idx < 64*D_; idx += 256) {
      int k = idx / D_, n = idx % D_;
      t[k*D_ + n] = w2[((size_t)(l*FFN_ + k0 + k))*D_ + n];
    }
    __syncthreads();
    for (int idx = tid; idx < 5*2*64; idx += 256) {
      int nf = idx / 128, rem = idx % 128;
      int ktl = rem / 64, lane = rem % 64;
      int r = lane & 15, g = lane >> 4;
      int n = nf*16 + r;
      int kb = ktl*32 + g*8;
      uint2 o;
      o.x = pk4fp8(t[(kb+0)*D_+n]*16.f, t[(kb+1)*D_+n]*16.f, t[(kb+2)*D_+n]*16.f, t[(kb+3)*D_+n]*16.f);
      o.y = pk4fp8(t[(kb+4)*D_+n]*16.f, t[(kb+5)*D_+n]*16.f, t[(kb+6)*D_+n]*16.f, t[(kb+7)*D_+n]*16.f);
      size_t kt = (size_t)(k0 >> 5) + ktl;
      *(uint2*)(w28 + (((size_t)l*5 + nf)*64 + kt)*512 + lane*8) = o;
    }
  }
}

// ============ merged: gather mel -> x + layer-0 LN_in + QKV MFMA -> q/kv (bf16) ============
__global__ __launch_bounds__(512) void k_build_qkv(const float* __restrict__ mel,
    const float* __restrict__ lw, const float* __restrict__ lb,
    const ushort_t* __restrict__ wqkvT, const float* __restrict__ bqkv,
    float* __restrict__ x, ushort_t* __restrict__ q, ushort_t* __restrict__ kv) {
  int tid = threadIdx.x;
  int wv = tid >> 6, lane = tid & 63;
  int r = lane & 15, g = lane >> 4;
  int bm = blockIdx.x * 16;
  __shared__ ushort_t hnsh[16][KP_];

  if (tid < 256) {
    int row = tid >> 4, j = tid & 15;
    int grow = bm + row;
    int b = grow / L_, i = grow % L_;
    int srow = (i < RCT_) ? ((i >> 3) + 1)*SEG_ + (i & 7) : i - RCT_;
    float v[5], s = 0.f, ss = 0.f;
    #pragma unroll
    for (int c = 0; c < 5; ++c) {
      int col = j*5 + c;
      v[c] = mel[((size_t)b*(TU_+RC_) + srow)*D_ + col];
      x[(size_t)grow*D_ + col] = v[c];
      s += v[c]; ss += v[c]*v[c];
    }
    s  += __shfl_xor(s, 1, 16);  ss += __shfl_xor(ss, 1, 16);
    s  += __shfl_xor(s, 2, 16);  ss += __shfl_xor(ss, 2, 16);
    s  += __shfl_xor(s, 4, 16);  ss += __shfl_xor(ss, 4, 16);
    s  += __shfl_xor(s, 8, 16);  ss += __shfl_xor(ss, 8, 16);
    float mean = s * (1.f/D_);
    float var  = ss * (1.f/D_) - mean*mean;
    float inv  = rsqrtf(var + EPS_);
    #pragma unroll
    for (int c = 0; c < 5; ++c) {
      int col = j*5 + c;
      hnsh[row][col] = f2bf((v[c] - mean) * inv * lw[col] + lb[col]);
    }
    hnsh[row][D_ + j] = 0;
  }
  __syncthreads();

  for (int t = wv; t < 15; t += 8) {
    f32x4 acc = {};
    #pragma unroll
    for (int kt = 0; kt < 3; ++kt) {
      bf16x8 a  = *(const bf16x8*)(&hnsh[r][kt*32 + g*8]);
      bf16x8 bb = *(const bf16x8*)(wqkvT + ((size_t)t*3 + kt)*512 + lane*8);
      acc = __builtin_amdgcn_mfma_f32_16x16x32_bf16(a, bb, acc, 0, 0, 0);
    }
    int col = t*16 + r;
    float bc = bqkv[col];
    #pragma unroll
    for (int rr = 0; rr < 4; ++rr) {
      int row = bm + g*4 + rr;
      float v = acc[rr] + bc;
      if (col < D_) q[(size_t)row*D_ + col] = f2bf(v);
      else          kv[(size_t)row*2*D_ + (col - D_)] = f2bf(v);
    }
  }
}

// ============ per-layer mega kernel: attention(own 16 rows, 1 pass, bf16 staging)
//              + WO + LN_ff + FFN1(fp8) + FFN2(fp8) + LN_out
//              + (mode0: QKV(next) -> qout/kvout | mode1: final projection) ============
// grid 160, 1024 thr. Attn pools union with FFN pools (disjoint lifetimes).
#define POOLB_ 106240
__global__ __launch_bounds__(1024) void k_layer(
    const ushort_t* __restrict__ qin, const ushort_t* __restrict__ kvin,
    const ushort_t* __restrict__ woT, const float* __restrict__ bo,
    const uchar_t* __restrict__ w18, const float* __restrict__ b1,
    const uchar_t* __restrict__ w28, const float* __restrict__ b2,
    const float* __restrict__ lfw, const float* __restrict__ lfb,
    const float* __restrict__ low, const float* __restrict__ lob,
    const float* __restrict__ liw, const float* __restrict__ lib, int mode,
    float* __restrict__ x,
    const ushort_t* __restrict__ wqkvT_n, const float* __restrict__ bqkv_n,
    ushort_t* __restrict__ qout, ushort_t* __restrict__ kvout,
    const ushort_t* __restrict__ pwT, const float* __restrict__ pb,
    float* __restrict__ out) {
  int tid = threadIdx.x;
  int wv = tid >> 6, lane = tid & 63;
  int r = lane & 15, g = lane >> 4;
  int bm = blockIdx.x * 16;
  int b = bm / L_, i0 = bm % L_;

  __shared__ __align__(16) char pool[POOLB_];
  __shared__ ushort_t attsh[16][KP_];
  __shared__ ushort_t hnsh[16][KP_];
  __shared__ uchar_t  hn8[16][104];
  __shared__ float    resf[16][D_];
  __shared__ float    inv_sh[8][16];

  // attn-phase pool views
  ushort_t (*ksh)[90][D_] = (ushort_t(*)[90][D_])(pool);             // [2][90][80]
  ushort_t (*vsh)[90][D_] = (ushort_t(*)[90][D_])(pool + 28800);
  ushort_t (*qsh)[D_]     = (ushort_t(*)[D_])(pool + 57600);         // [16][80]
  float    (*Ssh)[16][90] = (float(*)[16][90])(pool + 60160);        // [8][16][90]
  // ffn-phase pool views (after attention completes)
  uchar_t  (*ff18)[16][136] = (uchar_t(*)[16][136])(pool);           // [16][16][136]
  ushort_t (*redb)[16][D_]  = (ushort_t(*)[16][D_])(pool + 34816);   // [16][16][80]

  // ---- window setup ----
  int isR = (i0 < RCT_);
  int nw  = isR ? 2 : 1;
  int ws0 = isR ? (i0 >> 3) : ((i0 - RCT_) >> 5);
  int kcs[2], s0s[2];
  #pragma unroll
  for (int w = 0; w < 2; ++w) {
    int seg = ws0 + w;
    int s0 = seg*SEG_ - LC_; if (s0 < 0) s0 = 0;
    s0s[w] = s0;
    kcs[w] = RC_ + (seg+1)*SEG_ - s0;    // 40..90
  }

  // ---- stage K/V windows (bf16, ushort2) + Q + zero attsh pads ----
  for (int e = tid; e < nw*90*40; e += 1024) {
    int dd = (e % 40) * 2;
    int t2 = e / 40;
    int kk = t2 % 90, w = t2 / 90;
    if (kk < kcs[w]) {
      int seg = ws0 + w;
      int krow = (kk < RC_) ? seg*RC_ + kk : RCT_ + s0s[w] + (kk - RC_);
      const ushort_t* base = kvin + ((size_t)b*L_ + krow)*2*D_ + dd;
      *(ushort2*)&ksh[w][kk][dd] = *(const ushort2*)base;
      *(ushort2*)&vsh[w][kk][dd] = *(const ushort2*)(base + D_);
    }
  }
  if (tid < 640) {
    int row = tid / 40, dd = (tid % 40)*2;
    *(ushort2*)&qsh[row][dd] = *(const ushort2*)(qin + ((size_t)(bm+row))*D_ + dd);
  }
  if (tid < 256) attsh[tid >> 4][D_ + (tid & 15)] = 0;
  __syncthreads();

  // ---- scores + softmax: 128 (row,head) units x 8 lanes (all 1024 thr) ----
  {
    int j = tid & 7, unit = tid >> 3;
    int row = unit & 15, h = unit >> 4;
    int w = isR ? (row >> 3) : 0;
    int kc = kcs[w];
    float qv[DH_];
    #pragma unroll
    for (int d = 0; d < DH_; ++d) qv[d] = bf2f(qsh[row][h*DH_ + d]);
    float pm = -INFINITY;
    for (int kk = j; kk < kc; kk += 8) {
      float s = 0.f;
      #pragma unroll
      for (int d = 0; d < DH_; ++d) s += qv[d] * bf2f(ksh[w][kk][h*DH_ + d]);
      Ssh[h][row][kk] = s;
      pm = fmaxf(pm, s);
    }
    pm = fmaxf(pm, __shfl_xor(pm, 1, 8));
    pm = fmaxf(pm, __shfl_xor(pm, 2, 8));
    pm = fmaxf(pm, __shfl_xor(pm, 4, 8));
    float ps = 0.f;
    for (int kk = j; kk < kc; kk += 8) {
      float e = __expf(Ssh[h][row][kk] - pm);
      Ssh[h][row][kk] = e;
      ps += e;
    }
    ps += __shfl_xor(ps, 1, 8);
    ps += __shfl_xor(ps, 2, 8);
    ps += __shfl_xor(ps, 4, 8);
    if (j == 0) inv_sh[h][row] = 1.f / ps;
  }
  __syncthreads();

  // ---- PV: 640 threads (row, head, d-pair) -> attsh bf16 ----
  if (tid < 640) {
    int dp = tid % 5, u = tid / 5;
    int row = u & 15, h = u >> 4;
    int w = isR ? (row >> 3) : 0;
    int kc = kcs[w];
    int d0 = dp*2;
    float a0 = 0.f, a1 = 0.f;
    for (int kk = 0; kk < kc; ++kk) {
      float p = Ssh[h][row][kk];
      a0 += p * bf2f(vsh[w][kk][h*DH_ + d0]);
      a1 += p * bf2f(vsh[w][kk][h*DH_ + d0 + 1]);
    }
    float invl = inv_sh[h][row];
    attsh[row][h*DH_ + d0]     = f2bf(a0 * invl);
    attsh[row][h*DH_ + d0 + 1] = f2bf(a1 * invl);
  }
  __syncthreads();

  // ---- WO split over 15 waves: wave = (nf, kt), bf16 partials in redb ----
  if (wv < 15) {
    int nf = wv / 3, kt = wv % 3;
    f32x4 acc = {};
    bf16x8 a  = *(const bf16x8*)(&attsh[r][kt*32 + g*8]);
    bf16x8 bb = *(const bf16x8*)(woT + ((size_t)nf*3 + kt)*512 + lane*8);
    acc = __builtin_amdgcn_mfma_f32_16x16x32_bf16(a, bb, acc, 0, 0, 0);
    #pragma unroll
    for (int rr = 0; rr < 4; ++rr)
      redb[wv][g*4 + rr][nf*16 + r] = f2bf(acc[rr]);
  }
  __syncthreads();

  // ---- sum 3 kt-partials + bias + residual + LN_ff -> hn8 (res kept in resf) ----
  if (tid < 256) {
    int row = tid >> 4, j = tid & 15;
    int grow = bm + row;
    float v[5], s = 0.f, ss = 0.f;
    #pragma unroll
    for (int c = 0; c < 5; ++c) {
      int col = j*5 + c;
      int nf3 = (col >> 4) * 3;
      float wo3 = bf2f(redb[nf3][row][col]) + bf2f(redb[nf3+1][row][col])
                + bf2f(redb[nf3+2][row][col]);
      v[c] = wo3 + bo[col] + x[(size_t)grow*D_ + col];
      resf[row][col] = v[c];
      s += v[c]; ss += v[c]*v[c];
    }
    s  += __shfl_xor(s, 1, 16);  ss += __shfl_xor(ss, 1, 16);
    s  += __shfl_xor(s, 2, 16);  ss += __shfl_xor(ss, 2, 16);
    s  += __shfl_xor(s, 4, 16);  ss += __shfl_xor(ss, 4, 16);
    s  += __shfl_xor(s, 8, 16);  ss += __shfl_xor(ss, 8, 16);
    float mean = s * (1.f/D_);
    float var  = ss * (1.f/D_) - mean*mean;
    float inv  = rsqrtf(var + EPS_);
    #pragma unroll
    for (int c = 0; c < 5; ++c) {
      int col = j*5 + c;
      hn8[row][col] = f2fp8((v[c] - mean) * inv * lfw[col] + lfb[col]);
    }
    hn8[row][D_ + j] = 0;
  }
  __syncthreads();

  // ---- FFN1 fp8: fragment-tiled w18 ----
  f32x4 acc1[8];
  #pragma unroll
  for (int ni = 0; ni < 8; ++ni) acc1[ni] = (f32x4){0.f,0.f,0.f,0.f};
  #pragma unroll
  for (int kt = 0; kt < 3; ++kt) {
    i64_t a = *(const i64_t*)(&hn8[r][kt*32 + g*8]);
    #pragma unroll
    for (int ni = 0; ni < 8; ++ni) {
      i64_t bb = *(const i64_t*)(w18 + (((size_t)(wv*8 + ni))*3 + kt)*512 + lane*8);
      acc1[ni] = __builtin_amdgcn_mfma_f32_16x16x32_fp8_fp8(a, bb, acc1[ni], 0, 0, 0);
    }
  }
  int nbase = wv*128;
  #pragma unroll
  for (int ni = 0; ni < 8; ++ni) {
    int col = nbase + ni*16 + r;
    float bc = b1[col];
    #pragma unroll
    for (int rr = 0; rr < 4; ++rr) {
      float v = acc1[ni][rr] * 0.0625f + bc;
      ff18[wv][g*4 + rr][ni*16 + r] = f2fp8(fmaxf(v, 0.f) * 8.f);
    }
  }
  // same-wave write->read of ff18[wv]: compiler-ordered

  // ---- FFN2 fp8 ----
  f32x4 acc2[5] = {};
  #pragma unroll
  for (int ks = 0; ks < 4; ++ks) {
    i64_t a = *(const i64_t*)(&ff18[wv][r][ks*32 + g*8]);
    #pragma unroll
    for (int nf = 0; nf < 5; ++nf) {
      i64_t bb = *(const i64_t*)(w28 + (((size_t)nf*64) + wv*4 + ks)*512 + lane*8);
      acc2[nf] = __builtin_amdgcn_mfma_f32_16x16x32_fp8_fp8(a, bb, acc2[nf], 0, 0, 0);
    }
  }
  __syncthreads();   // all ff18 reads done before redb (overlapping pool) is rewritten
  #pragma unroll
  for (int nf = 0; nf < 5; ++nf)
    #pragma unroll
    for (int rr = 0; rr < 4; ++rr)
      redb[wv][g*4 + rr][nf*16 + r] = f2bf(acc2[nf][rr]);
  __syncthreads();

  for (int e = tid; e < 16*D_; e += 1024) {
    int row = e / D_, col = e % D_;
    float s0 = 0.f, s1 = 0.f, s2 = 0.f, s3 = 0.f;
    #pragma unroll
    for (int w = 0; w < 16; w += 4) {
      s0 += bf2f(redb[w+0][row][col]);
      s1 += bf2f(redb[w+1][row][col]);
      s2 += bf2f(redb[w+2][row][col]);
      s3 += bf2f(redb[w+3][row][col]);
    }
    resf[row][col] = ((s0+s1)+(s2+s3)) * (1.f/128.f) + b2[col] + resf[row][col];
  }
  __syncthreads();
  if (tid < 256) {
    int row = tid >> 4, j = tid & 15;
    float v[5], s = 0.f, ss = 0.f;
    #pragma unroll
    for (int c = 0; c < 5; ++c) {
      v[c] = resf[row][j*5 + c];
      s += v[c]; ss += v[c]*v[c];
    }
    s  += __shfl_xor(s, 1, 16);  ss += __shfl_xor(ss, 1, 16);
    s  += __shfl_xor(s, 2, 16);  ss += __shfl_xor(ss, 2, 16);
    s  += __shfl_xor(s, 4, 16);  ss += __shfl_xor(ss, 4, 16);
    s  += __shfl_xor(s, 8, 16);  ss += __shfl_xor(ss, 8, 16);
    float mean = s * (1.f/D_);
    float var  = ss * (1.f/D_) - mean*mean;
    float inv  = rsqrtf(var + EPS_);
    int grow = bm + row;
    float xs[5];
    float s2 = 0.f, ss2 = 0.f;
    #pragma unroll
    for (int c = 0; c < 5; ++c) {
      int col = j*5 + c;
      xs[c] = (v[c] - mean) * inv * low[col] + lob[col];
      x[(size_t)grow*D_ + col] = xs[c];
      s2 += xs[c]; ss2 += xs[c]*xs[c];
    }
    if (mode == 0) {
      s2  += __shfl_xor(s2, 1, 16);  ss2 += __shfl_xor(ss2, 1, 16);
      s2  += __shfl_xor(s2, 2, 16);  ss2 += __shfl_xor(ss2, 2, 16);
      s2  += __shfl_xor(s2, 4, 16);  ss2 += __shfl_xor(ss2, 4, 16);
      s2  += __shfl_xor(s2, 8, 16);  ss2 += __shfl_xor(ss2, 8, 16);
      float m2 = s2 * (1.f/D_);
      float v2 = ss2 * (1.f/D_) - m2*m2;
      float i2 = rsqrtf(v2 + EPS_);
      #pragma unroll
      for (int c = 0; c < 5; ++c) {
        int col = j*5 + c;
        hnsh[row][col] = f2bf((xs[c] - m2) * i2 * liw[col] + lib[col]);
      }
    } else {
      #pragma unroll
      for (int c = 0; c < 5; ++c)
        hnsh[row][j*5 + c] = f2bf(xs[c]);
    }
    hnsh[row][D_ + j] = 0;
  }

  if (mode == 0) {
    // ---- fused next-layer QKV -> qout/kvout (double-buffered; no race) ----
    __syncthreads();
    if (wv < 15) {
      int t = wv;
      f32x4 acc = {};
      #pragma unroll
      for (int kt = 0; kt < 3; ++kt) {
        bf16x8 a  = *(const bf16x8*)(&hnsh[r][kt*32 + g*8]);
        bf16x8 bb = *(const bf16x8*)(wqkvT_n + ((size_t)t*3 + kt)*512 + lane*8);
        acc = __builtin_amdgcn_mfma_f32_16x16x32_bf16(a, bb, acc, 0, 0, 0);
      }
      int col = t*16 + r;
      float bc = bqkv_n[col];
      #pragma unroll
      for (int rr = 0; rr < 4; ++rr) {
        int row = bm + g*4 + rr;
        float v = acc[rr] + bc;
        if (col < D_) qout[(size_t)row*D_ + col] = f2bf(v);
        else          kvout[(size_t)row*2*D_ + (col - D_)] = f2bf(v);
      }
    }
  } else {
    // ---- fused final projection: u-rows only ----
    int iu = bm % L_;
    if (iu >= RCT_) {
      __syncthreads();
      int bb2 = bm / L_;
      int urow0 = iu - RCT_;
      for (int t = wv; t < 48; t += 16) {
        f32x4 acc = {};
        #pragma unroll
        for (int kt = 0; kt < 3; ++kt) {
          bf16x8 a  = *(const bf16x8*)(&hnsh[r][kt*32 + g*8]);
          bf16x8 bb = *(const bf16x8*)(pwT + ((size_t)t*3 + kt)*512 + lane*8);
          acc = __builtin_amdgcn_mfma_f32_16x16x32_bf16(a, bb, acc, 0, 0, 0);
        }
        int col = t*16 + r;
        float bc = pb[col];
        #pragma unroll
        for (int rr = 0; rr < 4; ++rr) {
          int row = urow0 + g*4 + rr;
          out[((size_t)bb2*TU_ + row)*OUTD_ + col] = acc[rr] + bc;
        }
      }
    }
  }
}

extern "C" void kernel_launch(void* const* d_in, const int* in_sizes, int n_in,
                              void* d_out, int out_size, void* d_ws, size_t ws_size,
                              hipStream_t stream) {
  const float* mel     = (const float*)d_in[0];
  const int*   lengths = (const int*)  d_in[1];
  const float* ln_in_w = (const float*)d_in[2];
  const float* ln_in_b = (const float*)d_in[3];
  const float* wq      = (const float*)d_in[4];
  const float* bq      = (const float*)d_in[5];
  const float* wkv     = (const float*)d_in[6];
  const float* bkv     = (const float*)d_in[7];
  const float* wo      = (const float*)d_in[8];
  const float* bo      = (const float*)d_in[9];
  const float* ln_ff_w = (const float*)d_in[10];
  const float* ln_ff_b = (const float*)d_in[11];
  const float* w1      = (const float*)d_in[12];
  const float* b1      = (const float*)d_in[13];
  const float* w2      = (const float*)d_in[14];
  const float* b2      = (const float*)d_in[15];
  const float* ln_o_w  = (const float*)d_in[16];
  const float* ln_o_b  = (const float*)d_in[17];
  const float* pw      = (const float*)d_in[18];
  const float* pb      = (const float*)d_in[19];
  float* out = (float*)d_out;

  float* ws = (float*)d_ws;
  float* x     = ws; ws += NR_*D_;
  float* bqkv  = ws; ws += NLAYERS_*240;
  ushort_t* us = (ushort_t*)ws;
  ushort_t* qb0   = us; us += NR_*D_;
  ushort_t* kvb0  = us; us += NR_*2*D_;
  ushort_t* qb1   = us; us += NR_*D_;
  ushort_t* kvb1  = us; us += NR_*2*D_;
  ushort_t* wqkvT = us; us += S3_;
  ushort_t* woT   = us; us += S4_;
  ushort_t* pwT   = us; us += S5_;
  uchar_t* ub = (uchar_t*)us;
  uchar_t* w18 = ub; ub += S1_;
  uchar_t* w28 = ub; ub += S2_;

  k_wprep_all<<<WSM_BLK_ + W1_BLK_ + W2_BLK_, 256, 0, stream>>>(
      wq, wkv, wo, pw, bq, bkv, w1, w2, wqkvT, woT, pwT, bqkv, w18, w28,
      lengths, out);
  k_build_qkv<<<NR_/16, 512, 0, stream>>>(mel, ln_in_w, ln_in_b, wqkvT, bqkv,
                                          x, qb0, kvb0);

  for (int l = 0; l < NLAYERS_; ++l) {
    int last = (l == NLAYERS_-1);
    ushort_t* qi  = (l & 1) ? qb1  : qb0;
    ushort_t* kvi = (l & 1) ? kvb1 : kvb0;
    ushort_t* qo  = (l & 1) ? qb0  : qb1;
    ushort_t* kvo = (l & 1) ? kvb0 : kvb1;
    k_layer<<<NR_/16, 1024, 0, stream>>>(qi, kvi,
        woT + l*15*512, bo + l*D_,
        w18 + (size_t)l*FFN_*KP_, b1 + l*FFN_,
        w28 + (size_t)l*D_*FFN_, b2 + l*D_,
        ln_ff_w + l*D_, ln_ff_b + l*D_,
        ln_o_w + l*D_, ln_o_b + l*D_,
        ln_in_w + (last ? 0 : (l+1)*D_), ln_in_b + (last ? 0 : (l+1)*D_),
        last, x,
        wqkvT + (last ? 0 : (l+1)*45*512), bqkv + (last ? 0 : (l+1)*240),
        qo, kvo, pwT, pb, out);
  }
}